// Round 1
// baseline (2419.533 us; speedup 1.0000x reference)
//
#include <hip/hip_runtime.h>
#include <hip/hip_bf16.h>

#define NB 4
#define C 96
#define HH 256
#define WW 256
#define NPIX (HH*WW)
#define HEADS 4
#define CH 24
#define TI 14            // interior tile side
#define THALO 16         // halo tile side (=256 px = blockDim)
#define NTX 19           // ceil(256/14)
#define NTY 19
#define TP (TI*TI)       // 196 interior pixels

// ws layout (float offsets). Accumulator region [0, WS_MS) is zeroed each call.
#define WS_SUMSQ_Q 0
#define WS_SUMSQ_K (WS_SUMSQ_Q + NB*C)
#define WS_GRAM    (WS_SUMSQ_K + NB*C)
#define WS_MS      (WS_GRAM + NB*HEADS*CH*CH)   // M_scale transposed: [b][d][o]
#define WS_MSH     (WS_MS + NB*C*C)
#define WS_TOTAL   (WS_MSH + NB*C*C)            // ~84K floats = 335 KB

__device__ __forceinline__ unsigned short f2b(float f){
  unsigned u = __float_as_uint(f);
  unsigned r = u + 0x7FFFu + ((u >> 16) & 1u);
  return (unsigned short)(r >> 16);
}
__device__ __forceinline__ float b2f(unsigned short s){
  return __uint_as_float(((unsigned)s) << 16);
}

// conv1x1 for 24 output channels at this thread's halo pixel -> LDS Y
__device__ __forceinline__ void conv_group(
    const float* __restrict__ inb,   // input batch base [C][NPIX]
    const float* __restrict__ wmat,  // [rows][C]
    const float* __restrict__ bias,
    int row0, int poff, bool inimg, int t, float* __restrict__ Ysh)
{
  float acc[CH];
  #pragma unroll
  for (int o = 0; o < CH; ++o) acc[o] = bias[row0 + o];
  #pragma unroll 2
  for (int k = 0; k < C; k += 4){
    const float* xp = inb + (size_t)k * NPIX + poff;
    float x0 = xp[0];
    float x1 = xp[NPIX];
    float x2 = xp[2 * NPIX];
    float x3 = xp[3 * NPIX];
    #pragma unroll
    for (int o = 0; o < CH; ++o){
      float4 w = *reinterpret_cast<const float4*>(wmat + (size_t)(row0 + o) * C + k);
      acc[o] = fmaf(w.x, x0, acc[o]);
      acc[o] = fmaf(w.y, x1, acc[o]);
      acc[o] = fmaf(w.z, x2, acc[o]);
      acc[o] = fmaf(w.w, x3, acc[o]);
    }
  }
  #pragma unroll
  for (int o = 0; o < CH; ++o) Ysh[o * (THALO*THALO) + t] = inimg ? acc[o] : 0.0f;
}

// depthwise 3x3 at interior pixel (hx,hy) for channel row0+o, reading LDS Y
__device__ __forceinline__ float dw_at(const float* __restrict__ Ysh,
    const float* __restrict__ dww, const float* __restrict__ dwb,
    int row0, int o, int hx, int hy)
{
  const float* wd = dww + (size_t)(row0 + o) * 9;
  const float* yb = Ysh + o * (THALO*THALO) + (hy - 1) * THALO + (hx - 1);
  float s = dwb[row0 + o];
  #pragma unroll
  for (int dy = 0; dy < 3; ++dy){
    #pragma unroll
    for (int dx = 0; dx < 3; ++dx)
      s = fmaf(wd[dy * 3 + dx], yb[dy * THALO + dx], s);
  }
  return s;
}

__global__ __launch_bounds__(256, 2) void k1_fused(
  const float* __restrict__ content, const float* __restrict__ style,
  const float* __restrict__ q_w, const float* __restrict__ q_b,
  const float* __restrict__ qd_w, const float* __restrict__ qd_b,
  const float* __restrict__ kv_w, const float* __restrict__ kv_b,
  const float* __restrict__ kvd_w, const float* __restrict__ kvd_b,
  float* __restrict__ out, float* __restrict__ ws)
{
  __shared__ float Ysh[CH * THALO * THALO];        // 24.6 KB
  __shared__ unsigned short qS[HEADS * CH * TP];   // 37.6 KB (bf16)
  __shared__ unsigned short kS[CH * TP];           // 9.4 KB (bf16)
  __shared__ float redbuf[CH];

  const int t = threadIdx.x;
  const int b = blockIdx.y;
  const int tile = blockIdx.x;
  const int tx = tile % NTX, ty = tile / NTX;
  const int hx = t & (THALO - 1), hy = t >> 4;
  const int gx = tx * TI - 1 + hx, gy = ty * TI - 1 + hy;
  const bool inimg = (gx >= 0) && (gx < WW) && (gy >= 0) && (gy < HH);
  const bool irange = (hx >= 1) && (hx <= TI) && (hy >= 1) && (hy <= TI);
  const bool interior = irange && inimg;
  const int ip = (hy - 1) * TI + (hx - 1);
  const int poff = inimg ? (gy * WW + gx) : 0;

  const float* cb = content + (size_t)b * C * NPIX;
  const float* sb = style   + (size_t)b * C * NPIX;

  // ---- Phase A: q heads (content) ----
  for (int h = 0; h < HEADS; ++h){
    conv_group(cb, q_w, q_b, h * CH, poff, inimg, t, Ysh);
    __syncthreads();
    if (t < CH) redbuf[t] = 0.f;
    if (irange){
      for (int o = 0; o < CH; ++o){
        float v = interior ? dw_at(Ysh, qd_w, qd_b, h * CH, o, hx, hy) : 0.f;
        qS[(h * CH + o) * TP + ip] = f2b(v);
      }
    }
    __syncthreads();
    if (t < 240){
      int c = t % CH, st = t / CH;
      float s = 0.f;
      for (int p = st; p < TP; p += 10){
        float v = b2f(qS[(h * CH + c) * TP + p]);
        s = fmaf(v, v, s);
      }
      atomicAdd(&redbuf[c], s);
    }
    __syncthreads();
    if (t < CH) atomicAdd(&ws[WS_SUMSQ_Q + b * C + h * CH + t], redbuf[t]);
  }

  // ---- Phase B/C: kv groups (style): kg<4 = k heads, kg>=4 = v_scale/v_shift ----
  for (int kg = 0; kg < 12; ++kg){
    conv_group(sb, kv_w, kv_b, kg * CH, poff, inimg, t, Ysh);
    __syncthreads();
    if (kg < HEADS){
      if (t < CH) redbuf[t] = 0.f;
      if (irange){
        for (int o = 0; o < CH; ++o){
          float v = interior ? dw_at(Ysh, kvd_w, kvd_b, kg * CH, o, hx, hy) : 0.f;
          kS[o * TP + ip] = f2b(v);
        }
      }
      __syncthreads();
      if (t < 240){
        int c = t % CH, st = t / CH;
        float s = 0.f;
        for (int p = st; p < TP; p += 10){
          float v = b2f(kS[c * TP + p]);
          s = fmaf(v, v, s);
        }
        atomicAdd(&redbuf[c], s);
      }
      __syncthreads();
      if (t < CH) atomicAdd(&ws[WS_SUMSQ_K + b * C + kg * CH + t], redbuf[t]);
      // Gram: 576 entries, up to 3 per thread, each summed over 196 px (bf16 pairs)
      #pragma unroll
      for (int j = 0; j < 3; ++j){
        int idx = t + 256 * j;
        if (idx < CH * CH){
          int cc = idx / CH, dd = idx - cc * CH;
          const unsigned* qp = reinterpret_cast<const unsigned*>(qS + (kg * CH + cc) * TP);
          const unsigned* kp = reinterpret_cast<const unsigned*>(kS + dd * TP);
          float g = 0.f;
          for (int p = 0; p < TP / 2; ++p){
            unsigned uq = qp[p], uk = kp[p];
            g = fmaf(b2f((unsigned short)(uq & 0xffffu)), b2f((unsigned short)(uk & 0xffffu)), g);
            g = fmaf(b2f((unsigned short)(uq >> 16)),     b2f((unsigned short)(uk >> 16)),     g);
          }
          atomicAdd(&ws[WS_GRAM + ((b * HEADS + kg) * CH + cc) * CH + dd], g);
        }
      }
    } else {
      const int gg = kg - HEADS;   // 0..7: 0..3 v_scale, 4..7 v_shift
      float* obase = out + (gg < 4 ? (size_t)0 : (size_t)NB * C * NPIX)
                   + ((size_t)b * C + (gg & 3) * CH) * (size_t)NPIX;
      if (interior){
        for (int o = 0; o < CH; ++o){
          float v = dw_at(Ysh, kvd_w, kvd_b, kg * CH, o, hx, hy);
          obase[(size_t)o * NPIX + poff] = v;
        }
      }
      __syncthreads();   // guard Ysh reuse by next conv
    }
  }
}

__global__ void k2_attn(
  const float* __restrict__ temp,
  const float* __restrict__ ps_w, const float* __restrict__ psh_w,
  float* __restrict__ ws)
{
  const int b = blockIdx.x;
  const int t = threadIdx.x;
  __shared__ float attn[C * CH];   // [global c][d]
  __shared__ float nq[C], nk[C];
  if (t < C){
    nq[t] = fmaxf(sqrtf(ws[WS_SUMSQ_Q + b * C + t]), 1e-12f);
    nk[t] = fmaxf(sqrtf(ws[WS_SUMSQ_K + b * C + t]), 1e-12f);
  }
  __syncthreads();
  if (t < C){
    int h = t / CH;
    const float* g = ws + WS_GRAM + (((size_t)b * HEADS + h) * CH + (t % CH)) * CH;
    float tp = temp[h];
    float row[CH];
    float mx = -3.4e38f;
    #pragma unroll
    for (int d = 0; d < CH; ++d){
      row[d] = g[d] / (nq[t] * nk[h * CH + d]) * tp;
      mx = fmaxf(mx, row[d]);
    }
    float s = 0.f;
    #pragma unroll
    for (int d = 0; d < CH; ++d){ row[d] = expf(row[d] - mx); s += row[d]; }
    float inv = 1.f / s;
    #pragma unroll
    for (int d = 0; d < CH; ++d) attn[t * CH + d] = row[d] * inv;
  }
  __syncthreads();
  // M matrices, stored transposed: Mt[dg][o] = sum_c ps_w[o][h*24+c]*attn[h*24+c][d]
  for (int idx = t; idx < C * C; idx += 256){
    int dg = idx / C, o = idx - dg * C;
    int h = dg / CH, d = dg - h * CH;
    float s1 = 0.f, s2 = 0.f;
    #pragma unroll
    for (int c2 = 0; c2 < CH; ++c2){
      float a = attn[(h * CH + c2) * CH + d];
      s1 = fmaf(ps_w [(size_t)o * C + h * CH + c2], a, s1);
      s2 = fmaf(psh_w[(size_t)o * C + h * CH + c2], a, s2);
    }
    ws[WS_MS  + (size_t)b * C * C + idx] = s1;
    ws[WS_MSH + (size_t)b * C * C + idx] = s2;
  }
}

__global__ __launch_bounds__(256, 2) void k3_out(
  const float* __restrict__ ps_b, const float* __restrict__ psh_b,
  float* out, const float* __restrict__ ws)
{
  const int b = blockIdx.z;
  const int which = blockIdx.y;   // 0 = scale, 1 = shift
  const int n = blockIdx.x * 256 + threadIdx.x;
  float* base = out + (size_t)which * NB * C * NPIX + (size_t)b * C * NPIX + n;
  const float* Mt = ws + (which ? WS_MSH : WS_MS) + (size_t)b * C * C;
  const float* bias = which ? psh_b : ps_b;
  float acc[C];
  #pragma unroll
  for (int o = 0; o < C; ++o) acc[o] = bias[o];
  for (int d = 0; d < C; ++d){
    float x = base[(size_t)d * NPIX];
    const float* mr = Mt + d * C;
    #pragma unroll
    for (int o = 0; o < C; ++o) acc[o] = fmaf(mr[o], x, acc[o]);
  }
  #pragma unroll
  for (int o = 0; o < C; ++o) base[(size_t)o * NPIX] = acc[o];
}

extern "C" void kernel_launch(void* const* d_in, const int* in_sizes, int n_in,
                              void* d_out, int out_size, void* d_ws, size_t ws_size,
                              hipStream_t stream)
{
  const float* content = (const float*)d_in[0];
  const float* style   = (const float*)d_in[1];
  const float* temp    = (const float*)d_in[2];
  const float* q_w   = (const float*)d_in[3];
  const float* q_b   = (const float*)d_in[4];
  const float* qd_w  = (const float*)d_in[5];
  const float* qd_b  = (const float*)d_in[6];
  const float* kv_w  = (const float*)d_in[7];
  const float* kv_b  = (const float*)d_in[8];
  const float* kvd_w = (const float*)d_in[9];
  const float* kvd_b = (const float*)d_in[10];
  const float* ps_w  = (const float*)d_in[11];
  const float* ps_b  = (const float*)d_in[12];
  const float* psh_w = (const float*)d_in[13];
  const float* psh_b = (const float*)d_in[14];
  float* out = (float*)d_out;
  float* ws  = (float*)d_ws;

  // zero reduction accumulators (sumsq + Gram) each call
  hipMemsetAsync(ws, 0, (size_t)WS_MS * sizeof(float), stream);

  dim3 g1(NTX * NTY, NB);
  k1_fused<<<g1, dim3(256), 0, stream>>>(content, style, q_w, q_b, qd_w, qd_b,
                                         kv_w, kv_b, kvd_w, kvd_b, out, ws);
  k2_attn<<<dim3(NB), dim3(256), 0, stream>>>(temp, ps_w, psh_w, ws);
  dim3 g3(NPIX / 256, 2, NB);
  k3_out<<<g3, dim3(256), 0, stream>>>(ps_b, psh_b, out, ws);
}

// Round 2
// 756.754 us; speedup vs baseline: 3.1973x; 3.1973x over previous
//
#include <hip/hip_runtime.h>

#define NB 4
#define C 96
#define HH 256
#define WW 256
#define NPIX (HH*WW)
#define HEADS 4
#define CH 24
#define TI 14
#define NT 19
#define XP 104      // Xs/vS pitch in bf16 elems (208B: 2-way-free b128 reads)
#define SP 264      // qS/kT/Ysh pitch in bf16 elems (528B)

#define WS_SUMSQ_Q 0
#define WS_SUMSQ_K (WS_SUMSQ_Q + NB*C)
#define WS_GRAM    (WS_SUMSQ_K + NB*C)
#define WS_MS      (WS_GRAM + NB*HEADS*CH*CH)
#define WS_MSH     (WS_MS + NB*C*C)

typedef short short8 __attribute__((ext_vector_type(8)));
typedef float f32x4 __attribute__((ext_vector_type(4)));
typedef float f32x16 __attribute__((ext_vector_type(16)));

__device__ __forceinline__ unsigned short f2b(float f){
  unsigned u = __float_as_uint(f);
  unsigned r = u + 0x7FFFu + ((u >> 16) & 1u);
  return (unsigned short)(r >> 16);
}
__device__ __forceinline__ float b2f(unsigned short s){
  return __uint_as_float(((unsigned)s) << 16);
}
__device__ __forceinline__ short8 pack8(float4 a, float4 b){
  short8 r;
  r[0]=(short)f2b(a.x); r[1]=(short)f2b(a.y); r[2]=(short)f2b(a.z); r[3]=(short)f2b(a.w);
  r[4]=(short)f2b(b.x); r[5]=(short)f2b(b.y); r[6]=(short)f2b(b.z); r[7]=(short)f2b(b.w);
  return r;
}

__global__ __launch_bounds__(512, 1) void k1_fused(
  const float* __restrict__ content, const float* __restrict__ style,
  const float* __restrict__ q_w, const float* __restrict__ q_b,
  const float* __restrict__ qd_w, const float* __restrict__ qd_b,
  const float* __restrict__ kv_w, const float* __restrict__ kv_b,
  const float* __restrict__ kvd_w, const float* __restrict__ kvd_b,
  float* __restrict__ out, float* __restrict__ ws)
{
  __shared__ unsigned short Xs[256*XP];   // 53248 B  [px][ch] bf16
  __shared__ unsigned short qS[C*SP];     // 50688 B  q tile (halo px, border zero)
  __shared__ unsigned short Ysh[48*SP];   // 25344 B  conv1x1 chunk output
  __shared__ unsigned short kT[48*SP];    // 25344 B  k chunk tile
  __shared__ float redq[C], redk[C];

  const int t = threadIdx.x;
  const int lane = t & 63;
  const int w = t >> 6;
  const int b = blockIdx.y;
  const int tile = blockIdx.x;
  const int tx = tile % NT, ty = tile / NT;

  { // zero qS, kT, red
    unsigned* q32 = (unsigned*)qS;
    for (int i = t; i < C*SP/2; i += 512) q32[i] = 0u;
    unsigned* k32 = (unsigned*)kT;
    for (int i = t; i < 48*SP/2; i += 512) k32[i] = 0u;
    if (t < C){ redq[t] = 0.f; redk[t] = 0.f; }
  }
  __syncthreads();

  auto stageX = [&](const float* inb){
    for (int i = 0; i < 12; ++i){
      int s = i*512 + t;
      int px = s & 255, chg = s >> 8;     // chg: 0..23 -> 4 channels each
      int hx = px & 15, hy = px >> 4;
      int gx = tx*TI - 1 + hx, gy = ty*TI - 1 + hy;
      bool im = (gx>=0) && (gx<WW) && (gy>=0) && (gy<HH);
      const float* p = inb + (size_t)(chg*4)*NPIX + (im ? (gy*WW+gx) : 0);
      float v0 = im ? p[0] : 0.f;
      float v1 = im ? p[NPIX] : 0.f;
      float v2 = im ? p[2*NPIX] : 0.f;
      float v3 = im ? p[3*NPIX] : 0.f;
      unsigned lo = ((unsigned)f2b(v1) << 16) | (unsigned)f2b(v0);
      unsigned hi = ((unsigned)f2b(v3) << 16) | (unsigned)f2b(v2);
      *(uint2*)&Xs[px*XP + chg*4] = make_uint2(lo, hi);
    }
  };

  // conv1x1 for 48 output rows [row0..row0+47] over all 256 halo px -> Ysh
  auto convChunk = [&](const float* wmat, const float* bias, int row0){
    for (int mi = 0; mi < 3; ++mi){
      int m0 = mi*16;
      int orow = row0 + m0 + (lane & 15);
      const float* wp = wmat + (size_t)orow*96 + ((lane>>4)*8);
      short8 a0 = pack8(*(const float4*)(wp),    *(const float4*)(wp+4));
      short8 a1 = pack8(*(const float4*)(wp+32), *(const float4*)(wp+36));
      short8 a2 = pack8(*(const float4*)(wp+64), *(const float4*)(wp+68));
      float4 bv = *(const float4*)&bias[row0 + m0 + (lane>>4)*4];
      for (int ni = 0; ni < 2; ++ni){
        int px = (w*2 + ni)*16 + (lane & 15);
        f32x4 acc = {bv.x, bv.y, bv.z, bv.w};
        const unsigned short* xb = &Xs[px*XP + ((lane>>4)*8)];
        acc = __builtin_amdgcn_mfma_f32_16x16x32_bf16(a0, *(const short8*)(xb),    acc, 0,0,0);
        acc = __builtin_amdgcn_mfma_f32_16x16x32_bf16(a1, *(const short8*)(xb+32), acc, 0,0,0);
        acc = __builtin_amdgcn_mfma_f32_16x16x32_bf16(a2, *(const short8*)(xb+64), acc, 0,0,0);
        int hx = px & 15, hy = px >> 4;
        int gx = tx*TI - 1 + hx, gy = ty*TI - 1 + hy;
        bool im = (gx>=0) && (gx<WW) && (gy>=0) && (gy<HH);
        int chb = m0 + (lane>>4)*4;
        #pragma unroll
        for (int r = 0; r < 4; ++r)
          Ysh[(chb + r)*SP + px] = im ? f2b(acc[r]) : (unsigned short)0;
      }
    }
  };

  // depthwise 3x3 over Ysh. mode 0: ->qS(+redq), 1: ->kT(+redk), 2: ->global v
  auto dwChunk = [&](const float* dww, const float* dwb, int wrow0, int mode,
                     unsigned short* dst, int dstRow0, float* gout){
    for (int slot = t; slot < 48*16; slot += 512){
      int c = slot >> 4, py = slot & 15;
      if (py >= TI){
        if (mode < 2){  // zero border rows 0 and 15
          int hr = (py == TI) ? 0 : 15;
          short8 z = {};
          *(short8*)&dst[(dstRow0 + c)*SP + hr*16]     = z;
          *(short8*)&dst[(dstRow0 + c)*SP + hr*16 + 8] = z;
        }
        continue;
      }
      const unsigned short* yb = &Ysh[c*SP + py*16];
      float u0[16], u1[16], u2[16];
      {
        short8 s0 = *(const short8*)(yb),    s1 = *(const short8*)(yb+8);
        short8 s2 = *(const short8*)(yb+16), s3 = *(const short8*)(yb+24);
        short8 s4 = *(const short8*)(yb+32), s5 = *(const short8*)(yb+40);
        #pragma unroll
        for (int j = 0; j < 8; ++j){
          u0[j]=b2f((unsigned short)s0[j]); u0[j+8]=b2f((unsigned short)s1[j]);
          u1[j]=b2f((unsigned short)s2[j]); u1[j+8]=b2f((unsigned short)s3[j]);
          u2[j]=b2f((unsigned short)s4[j]); u2[j+8]=b2f((unsigned short)s5[j]);
        }
      }
      const float* wd = dww + (size_t)(wrow0 + c)*9;
      float w00=wd[0],w01=wd[1],w02=wd[2],w10=wd[3],w11=wd[4],w12=wd[5],w20=wd[6],w21=wd[7],w22=wd[8];
      float bb = dwb[wrow0 + c];
      int gy = ty*TI + py;
      float o[TI];
      #pragma unroll
      for (int j = 0; j < TI; ++j){
        float s = bb;
        s = fmaf(w00,u0[j],s); s = fmaf(w01,u0[j+1],s); s = fmaf(w02,u0[j+2],s);
        s = fmaf(w10,u1[j],s); s = fmaf(w11,u1[j+1],s); s = fmaf(w12,u1[j+2],s);
        s = fmaf(w20,u2[j],s); s = fmaf(w21,u2[j+1],s); s = fmaf(w22,u2[j+2],s);
        int gx = tx*TI + j;
        bool ok = (gx < WW) && (gy < HH);
        o[j] = ok ? s : 0.f;
      }
      if (mode < 2){
        float sq = 0.f;
        #pragma unroll
        for (int j = 0; j < TI; ++j) sq = fmaf(o[j], o[j], sq);
        atomicAdd((mode==0 ? redq : redk) + wrow0 + c, sq);
        unsigned short vv[16];
        vv[0] = 0; vv[15] = 0;
        #pragma unroll
        for (int j = 0; j < TI; ++j) vv[j+1] = f2b(o[j]);
        *(short8*)&dst[(dstRow0 + c)*SP + (py+1)*16]     = *(short8*)&vv[0];
        *(short8*)&dst[(dstRow0 + c)*SP + (py+1)*16 + 8] = *(short8*)&vv[8];
      } else {
        if (gy < HH){
          float* op = gout + (size_t)c*NPIX + (size_t)gy*WW + tx*TI;
          #pragma unroll
          for (int j = 0; j < TI; ++j){
            if (tx*TI + j < WW) op[j] = o[j];
          }
        }
      }
    }
  };

  // Gram for heads {2cc, 2cc+1}: G[c][d] += sum_px q_c * k_d (MFMA 32x32x16)
  auto gram = [&](int cc){
    int h = cc*2 + (w & 1);
    int cl = lane & 31;
    bool cvld = cl < CH;
    int qrow = h*CH + (cvld ? cl : 0);
    int krow = (w & 1)*CH + (cvld ? cl : 0);
    f32x16 g;
    #pragma unroll
    for (int r = 0; r < 16; ++r) g[r] = 0.f;
    short8 z = {};
    #pragma unroll
    for (int ki = 0; ki < 4; ++ki){
      int k0 = ((w>>1)*4 + ki)*16 + (lane>>5)*8;
      short8 qa = *(const short8*)&qS[qrow*SP + k0];
      short8 kb = *(const short8*)&kT[krow*SP + k0];
      if (!cvld){ qa = z; kb = z; }
      g = __builtin_amdgcn_mfma_f32_32x32x16_bf16(qa, kb, g, 0,0,0);
    }
    float* gdst = ws + WS_GRAM + (size_t)(b*HEADS + h)*CH*CH;
    #pragma unroll
    for (int r = 0; r < 16; ++r){
      int row = (r&3) + 8*(r>>2) + 4*(lane>>5);
      int col = lane & 31;
      if (row < CH && col < CH) atomicAdd(&gdst[row*CH + col], g[r]);
    }
  };

  // ---- Phase A: q from content ----
  stageX(content + (size_t)b*C*NPIX);
  __syncthreads();
  for (int qc = 0; qc < 2; ++qc){
    convChunk(q_w, q_b, qc*48);
    __syncthreads();
    dwChunk(qd_w, qd_b, qc*48, 0, qS, qc*48, nullptr);
    __syncthreads();
  }
  if (t < C) atomicAdd(&ws[WS_SUMSQ_Q + b*C + t], redq[t]);

  // ---- Phase B: kv from style ----
  stageX(style + (size_t)b*C*NPIX);
  __syncthreads();
  for (int cc = 0; cc < 2; ++cc){           // k chunks + Gram
    convChunk(kv_w, kv_b, cc*48);
    __syncthreads();
    dwChunk(kvd_w, kvd_b, cc*48, 1, kT, 0, nullptr);
    __syncthreads();
    gram(cc);
    __syncthreads();
  }
  if (t < C) atomicAdd(&ws[WS_SUMSQ_K + b*C + t], redk[t]);
  for (int cv = 0; cv < 4; ++cv){           // v chunks -> global fp32
    convChunk(kv_w, kv_b, 96 + cv*48);
    __syncthreads();
    float* gout = out + (size_t)(cv>>1)*NB*C*NPIX + ((size_t)b*C + (cv&1)*48)*NPIX;
    dwChunk(kvd_w, kvd_b, 96 + cv*48, 2, nullptr, 0, gout);
    __syncthreads();
  }
}

__global__ void k2_attn(
  const float* __restrict__ temp,
  const float* __restrict__ ps_w, const float* __restrict__ psh_w,
  float* __restrict__ ws)
{
  const int b = blockIdx.x;
  const int t = threadIdx.x;
  __shared__ float attn[C * CH];   // [global c][d]
  __shared__ float nq[C], nk[C];
  if (t < C){
    nq[t] = fmaxf(sqrtf(ws[WS_SUMSQ_Q + b * C + t]), 1e-12f);
    nk[t] = fmaxf(sqrtf(ws[WS_SUMSQ_K + b * C + t]), 1e-12f);
  }
  __syncthreads();
  if (t < C){
    int h = t / CH;
    const float* g = ws + WS_GRAM + (((size_t)b * HEADS + h) * CH + (t % CH)) * CH;
    float tp = temp[h];
    float row[CH];
    float mx = -3.4e38f;
    #pragma unroll
    for (int d = 0; d < CH; ++d){
      row[d] = g[d] / (nq[t] * nk[h * CH + d]) * tp;
      mx = fmaxf(mx, row[d]);
    }
    float s = 0.f;
    #pragma unroll
    for (int d = 0; d < CH; ++d){ row[d] = expf(row[d] - mx); s += row[d]; }
    float inv = 1.f / s;
    #pragma unroll
    for (int d = 0; d < CH; ++d) attn[t * CH + d] = row[d] * inv;
  }
  __syncthreads();
  // M[o][dg] = sum_c ps_w[o][h*24+c] * attn[h*24+c][d]   (stored row-major [o][d])
  for (int idx = t; idx < C * C; idx += 256){
    int o = idx / C, dg = idx - o * C;
    int h = dg / CH, d = dg - h * CH;
    float s1 = 0.f, s2 = 0.f;
    #pragma unroll
    for (int c2 = 0; c2 < CH; ++c2){
      float a = attn[(h * CH + c2) * CH + d];
      s1 = fmaf(ps_w [(size_t)o * C + h * CH + c2], a, s1);
      s2 = fmaf(psh_w[(size_t)o * C + h * CH + c2], a, s2);
    }
    ws[WS_MS  + (size_t)b * C * C + idx] = s1;
    ws[WS_MSH + (size_t)b * C * C + idx] = s2;
  }
}

// out[o][px] = bias[o] + sum_d M[o][d] * v[d][px], in-place per 256-px block (MFMA)
__global__ __launch_bounds__(256, 2) void k3_gemm(
  const float* __restrict__ ps_b, const float* __restrict__ psh_b,
  float* out, const float* __restrict__ ws)
{
  __shared__ unsigned short vS[256*XP];
  const int t = threadIdx.x, lane = t & 63, w = t >> 6;
  const int b = blockIdx.z, which = blockIdx.y;
  const int px0 = blockIdx.x * 256;
  float* base = out + (size_t)which*NB*C*NPIX + (size_t)b*C*NPIX + px0;
  const float* M = ws + (which ? WS_MSH : WS_MS) + (size_t)b*C*C;
  const float* bias = which ? psh_b : ps_b;

  for (int i = 0; i < 24; ++i){
    int s = i*256 + t;
    int px = s & 255, chg = s >> 8;
    const float* p = base + (size_t)(chg*4)*NPIX + px;
    unsigned lo = ((unsigned)f2b(p[NPIX])   << 16) | (unsigned)f2b(p[0]);
    unsigned hi = ((unsigned)f2b(p[3*NPIX]) << 16) | (unsigned)f2b(p[2*NPIX]);
    *(uint2*)&vS[px*XP + chg*4] = make_uint2(lo, hi);
  }
  __syncthreads();

  #pragma unroll 1
  for (int mi = 0; mi < 6; ++mi){
    int m0 = mi*16;
    const float* mp = M + (size_t)(m0 + (lane&15))*C + (lane>>4)*8;
    short8 a0 = pack8(*(const float4*)(mp),    *(const float4*)(mp+4));
    short8 a1 = pack8(*(const float4*)(mp+32), *(const float4*)(mp+36));
    short8 a2 = pack8(*(const float4*)(mp+64), *(const float4*)(mp+68));
    float4 bv = *(const float4*)&bias[m0 + (lane>>4)*4];
    #pragma unroll
    for (int ni = 0; ni < 4; ++ni){
      int px = (w*4 + ni)*16 + (lane & 15);
      f32x4 acc = {bv.x, bv.y, bv.z, bv.w};
      const unsigned short* xb = &vS[px*XP + ((lane>>4)*8)];
      acc = __builtin_amdgcn_mfma_f32_16x16x32_bf16(a0, *(const short8*)(xb),    acc, 0,0,0);
      acc = __builtin_amdgcn_mfma_f32_16x16x32_bf16(a1, *(const short8*)(xb+32), acc, 0,0,0);
      acc = __builtin_amdgcn_mfma_f32_16x16x32_bf16(a2, *(const short8*)(xb+64), acc, 0,0,0);
      #pragma unroll
      for (int r = 0; r < 4; ++r)
        base[(size_t)(m0 + (lane>>4)*4 + r)*NPIX + px] = acc[r];
    }
  }
}

extern "C" void kernel_launch(void* const* d_in, const int* in_sizes, int n_in,
                              void* d_out, int out_size, void* d_ws, size_t ws_size,
                              hipStream_t stream)
{
  const float* content = (const float*)d_in[0];
  const float* style   = (const float*)d_in[1];
  const float* temp    = (const float*)d_in[2];
  const float* q_w   = (const float*)d_in[3];
  const float* q_b   = (const float*)d_in[4];
  const float* qd_w  = (const float*)d_in[5];
  const float* qd_b  = (const float*)d_in[6];
  const float* kv_w  = (const float*)d_in[7];
  const float* kv_b  = (const float*)d_in[8];
  const float* kvd_w = (const float*)d_in[9];
  const float* kvd_b = (const float*)d_in[10];
  const float* ps_w  = (const float*)d_in[11];
  const float* ps_b  = (const float*)d_in[12];
  const float* psh_w = (const float*)d_in[13];
  const float* psh_b = (const float*)d_in[14];
  float* out = (float*)d_out;
  float* ws  = (float*)d_ws;

  hipMemsetAsync(ws, 0, (size_t)WS_MS * sizeof(float), stream);

  dim3 g1(NT * NT, NB);
  k1_fused<<<g1, dim3(512), 0, stream>>>(content, style, q_w, q_b, qd_w, qd_b,
                                         kv_w, kv_b, kvd_w, kvd_b, out, ws);
  k2_attn<<<dim3(NB), dim3(256), 0, stream>>>(temp, ps_w, psh_w, ws);
  dim3 g3(NPIX / 256, 2, NB);
  k3_gemm<<<g3, dim3(256), 0, stream>>>(ps_b, psh_b, out, ws);
}

// Round 3
// 655.474 us; speedup vs baseline: 3.6913x; 1.1545x over previous
//
#include <hip/hip_runtime.h>

#define NB 4
#define C 96
#define HH 256
#define WW 256
#define NPIX (HH*WW)
#define HEADS 4
#define CH 24

// ---- fallback (round-2) tiling ----
#define TI 14
#define NT 19
#define XP 104
#define SP 264

// ---- new tiling: interior 16 wide x 14 tall, halo 18x16 ----
#define NTX2 16
#define NTY2 19
#define YP 296      // Ysh pitch (18*16=288 +8)
#define QP 264      // qS/kT pitch (16*16=256 +8)

#define WS_SUMSQ_Q 0
#define WS_SUMSQ_K (WS_SUMSQ_Q + NB*C)
#define WS_GRAM    (WS_SUMSQ_K + NB*C)
#define WS_MS      (WS_GRAM + NB*HEADS*CH*CH)
#define WS_MSH     (WS_MS + NB*C*C)

#define XT_OFF_BYTES ((size_t)335872)
#define XT_BYTES ((size_t)2*NB*NPIX*96*2)

typedef short short8 __attribute__((ext_vector_type(8)));
typedef float f32x4 __attribute__((ext_vector_type(4)));
typedef float f32x16 __attribute__((ext_vector_type(16)));

__device__ __forceinline__ unsigned short f2b(float f){
  unsigned u = __float_as_uint(f);
  unsigned r = u + 0x7FFFu + ((u >> 16) & 1u);
  return (unsigned short)(r >> 16);
}
__device__ __forceinline__ float b2f(unsigned short s){
  return __uint_as_float(((unsigned)s) << 16);
}
__device__ __forceinline__ short8 pack8(float4 a, float4 b){
  short8 r;
  r[0]=(short)f2b(a.x); r[1]=(short)f2b(a.y); r[2]=(short)f2b(a.z); r[3]=(short)f2b(a.w);
  r[4]=(short)f2b(b.x); r[5]=(short)f2b(b.y); r[6]=(short)f2b(b.z); r[7]=(short)f2b(b.w);
  return r;
}

// ============================ K0: fp32 [c][n] -> bf16 [n][c] ============================
__global__ __launch_bounds__(256) void k0t(
  const float* __restrict__ content, const float* __restrict__ style,
  unsigned short* __restrict__ xt)
{
  __shared__ unsigned short Xt[96*68];
  const int t = threadIdx.x;
  const int n0 = blockIdx.x * 64;
  const int b = blockIdx.y, src = blockIdx.z;
  const float* in = (src ? style : content) + (size_t)b*C*NPIX;
  #pragma unroll
  for (int i = 0; i < 6; ++i){
    int s = i*256 + t;
    int r = s >> 4, c4 = s & 15;
    float4 f = *(const float4*)(in + (size_t)r*NPIX + n0 + c4*4);
    unsigned lo = ((unsigned)f2b(f.y) << 16) | f2b(f.x);
    unsigned hi = ((unsigned)f2b(f.w) << 16) | f2b(f.z);
    *(uint2*)&Xt[r*68 + c4*4] = make_uint2(lo, hi);
  }
  __syncthreads();
  unsigned* dst = (unsigned*)(xt + (((size_t)src*NB + b)*NPIX + n0)*96);
  #pragma unroll
  for (int i = 0; i < 12; ++i){
    int s = i*256 + t;
    int j = s / 48, c2 = s - j*48;
    unsigned v = ((unsigned)Xt[(c2*2+1)*68 + j] << 16) | Xt[(c2*2)*68 + j];
    dst[(size_t)j*48 + c2] = v;
  }
}

// ============================ K_qk: q,k,Gram,sumsq ============================
__global__ __launch_bounds__(512, 4) void kqk(
  const unsigned short* __restrict__ xt,
  const float* __restrict__ q_w, const float* __restrict__ q_b,
  const float* __restrict__ qd_w, const float* __restrict__ qd_b,
  const float* __restrict__ kv_w, const float* __restrict__ kv_b,
  const float* __restrict__ kvd_w, const float* __restrict__ kvd_b,
  float* __restrict__ ws)
{
  __shared__ unsigned short Ysh[48*YP];
  __shared__ unsigned short qS[48*QP];
  __shared__ unsigned short kT[48*QP];
  __shared__ float redq[C], redk[C];

  const int t = threadIdx.x, lane = t & 63, w = t >> 6;
  const int b = blockIdx.y, tile = blockIdx.x;
  const int txx = tile & 15, tyy = tile >> 4;
  const int gx0 = txx*16, gy0 = tyy*14;
  if (t < C){ redq[t] = 0.f; redk[t] = 0.f; }
  __syncthreads();

  const unsigned short* xc = xt + ((size_t)(0*NB + b))*NPIX*96;
  const unsigned short* xs = xt + ((size_t)(1*NB + b))*NPIX*96;

  // conv1x1 (48 rows) over the 18x16 halo, MFMA, -> Ysh (column-major: [ch][hx*16+hy])
  auto conv = [&](const unsigned short* xbase, const float* wmat, const float* bias, int row0){
    const int hy = lane & 15, khalf = lane >> 4;
    const int gy = gy0 - 1 + hy;
    short8 xf[3][3]; bool imv[3]; int np = (w < 2) ? 3 : 2;
    #pragma unroll
    for (int i = 0; i < 3; ++i){
      if (i >= np) break;
      int pt = w + i*8;
      int gx = gx0 - 1 + pt;
      bool im = (gx>=0) && (gx<WW) && (gy>=0) && (gy<HH);
      imv[i] = im;
      int n = im ? (gy*WW + gx) : 0;
      const unsigned short* xp = xbase + (size_t)n*96 + khalf*8;
      short8 z = {};
      #pragma unroll
      for (int kk = 0; kk < 3; ++kk){
        short8 v = *(const short8*)(xp + kk*32);
        xf[i][kk] = im ? v : z;
      }
    }
    #pragma unroll 1
    for (int mi = 0; mi < 3; ++mi){
      int orow = row0 + mi*16 + hy;
      const float* wp = wmat + (size_t)orow*96 + khalf*8;
      short8 a0 = pack8(*(const float4*)(wp),    *(const float4*)(wp+4));
      short8 a1 = pack8(*(const float4*)(wp+32), *(const float4*)(wp+36));
      short8 a2 = pack8(*(const float4*)(wp+64), *(const float4*)(wp+68));
      float4 bv = *(const float4*)&bias[row0 + mi*16 + khalf*4];
      #pragma unroll
      for (int i = 0; i < 3; ++i){
        if (i >= np) break;
        int pt = w + i*8;
        f32x4 acc = {bv.x, bv.y, bv.z, bv.w};
        acc = __builtin_amdgcn_mfma_f32_16x16x32_bf16(a0, xf[i][0], acc, 0,0,0);
        acc = __builtin_amdgcn_mfma_f32_16x16x32_bf16(a1, xf[i][1], acc, 0,0,0);
        acc = __builtin_amdgcn_mfma_f32_16x16x32_bf16(a2, xf[i][2], acc, 0,0,0);
        #pragma unroll
        for (int r = 0; r < 4; ++r){
          int ch = mi*16 + khalf*4 + r;
          Ysh[ch*YP + pt*16 + hy] = imv[i] ? f2b(acc[r]) : (unsigned short)0;
        }
      }
    }
  };

  // dw 3x3 column-wise -> dst[c][j*16+py] (py 14,15 zero pad) + sumsq
  auto dwQK = [&](const float* dww, const float* dwb, int wrow0,
                  unsigned short* dst, float* red){
    for (int slot = t; slot < 48*16; slot += 512){
      int c = slot >> 4, j = slot & 15;
      const unsigned short* yb = &Ysh[c*YP + j*16];
      float u0[16], u1[16], u2[16];
      {
        short8 s0 = *(const short8*)(yb),    s1 = *(const short8*)(yb+8);
        short8 s2 = *(const short8*)(yb+16), s3 = *(const short8*)(yb+24);
        short8 s4 = *(const short8*)(yb+32), s5 = *(const short8*)(yb+40);
        #pragma unroll
        for (int u = 0; u < 8; ++u){
          u0[u]=b2f((unsigned short)s0[u]); u0[u+8]=b2f((unsigned short)s1[u]);
          u1[u]=b2f((unsigned short)s2[u]); u1[u+8]=b2f((unsigned short)s3[u]);
          u2[u]=b2f((unsigned short)s4[u]); u2[u+8]=b2f((unsigned short)s5[u]);
        }
      }
      const float* wd = dww + (size_t)(wrow0 + c)*9;
      float w00=wd[0],w01=wd[1],w02=wd[2],w10=wd[3],w11=wd[4],w12=wd[5],w20=wd[6],w21=wd[7],w22=wd[8];
      float bb = dwb[wrow0 + c];
      unsigned short vv[16];
      float sq = 0.f;
      #pragma unroll
      for (int py = 0; py < 14; ++py){
        float s = bb;
        s = fmaf(w00,u0[py],s); s = fmaf(w10,u0[py+1],s); s = fmaf(w20,u0[py+2],s);
        s = fmaf(w01,u1[py],s); s = fmaf(w11,u1[py+1],s); s = fmaf(w21,u1[py+2],s);
        s = fmaf(w02,u2[py],s); s = fmaf(w12,u2[py+1],s); s = fmaf(w22,u2[py+2],s);
        if (gy0 + py >= HH) s = 0.f;
        sq = fmaf(s, s, sq);
        vv[py] = f2b(s);
      }
      vv[14] = 0; vv[15] = 0;
      atomicAdd(&red[wrow0 + c], sq);
      *(short8*)&dst[c*QP + j*16]     = *(short8*)&vv[0];
      *(short8*)&dst[c*QP + j*16 + 8] = *(short8*)&vv[8];
    }
  };

  auto gram = [&](int cc){
    int hl = w & 1;
    int cl = lane & 31; bool cv = cl < CH;
    int row = hl*CH + (cv ? cl : 0);
    f32x16 g;
    #pragma unroll
    for (int r = 0; r < 16; ++r) g[r] = 0.f;
    short8 z = {};
    for (int ks = (w >> 1); ks < 16; ks += 4){
      int ko = ks*16 + (lane>>5)*8;
      short8 qa = *(const short8*)&qS[row*QP + ko];
      short8 kb = *(const short8*)&kT[row*QP + ko];
      if (!cv){ qa = z; kb = z; }
      g = __builtin_amdgcn_mfma_f32_32x32x16_bf16(qa, kb, g, 0,0,0);
    }
    float* gd = ws + WS_GRAM + (size_t)(b*HEADS + cc*2 + hl)*CH*CH;
    #pragma unroll
    for (int r = 0; r < 16; ++r){
      int row2 = (r&3) + 8*(r>>2) + 4*(lane>>5);
      int col = lane & 31;
      if (row2 < CH && col < CH) atomicAdd(&gd[row2*CH + col], g[r]);
    }
  };

  #pragma unroll 1
  for (int cc = 0; cc < 2; ++cc){
    conv(xc, q_w, q_b, cc*48);
    __syncthreads();
    dwQK(qd_w, qd_b, cc*48, qS, redq);
    __syncthreads();
    conv(xs, kv_w, kv_b, cc*48);
    __syncthreads();
    dwQK(kvd_w, kvd_b, cc*48, kT, redk);
    __syncthreads();
    gram(cc);
    __syncthreads();
  }
  if (t < C){
    atomicAdd(&ws[WS_SUMSQ_Q + b*C + t], redq[t]);
    atomicAdd(&ws[WS_SUMSQ_K + b*C + t], redk[t]);
  }
}

// ============================ K_v: v_scale/v_shift -> d_out (fp32) ============================
__global__ __launch_bounds__(512, 4) void kvker(
  const unsigned short* __restrict__ xs,   // style xt base
  const float* __restrict__ kv_w, const float* __restrict__ kv_b,
  const float* __restrict__ kvd_w, const float* __restrict__ kvd_b,
  float* __restrict__ out)
{
  __shared__ unsigned short Ysh[48*YP];
  const int t = threadIdx.x, lane = t & 63, w = t >> 6;
  const int b = blockIdx.y, tile = blockIdx.x;
  const int txx = tile & 15, tyy = tile >> 4;
  const int gx0 = txx*16, gy0 = tyy*14;
  const unsigned short* xb_ = xs + (size_t)b*NPIX*96;

  #pragma unroll 1
  for (int cv = 0; cv < 4; ++cv){
    int row0 = 96 + cv*48;
    { // conv (same structure as kqk)
      const int hy = lane & 15, khalf = lane >> 4;
      const int gy = gy0 - 1 + hy;
      short8 xf[3][3]; bool imv[3]; int np = (w < 2) ? 3 : 2;
      #pragma unroll
      for (int i = 0; i < 3; ++i){
        if (i >= np) break;
        int pt = w + i*8;
        int gx = gx0 - 1 + pt;
        bool im = (gx>=0) && (gx<WW) && (gy>=0) && (gy<HH);
        imv[i] = im;
        int n = im ? (gy*WW + gx) : 0;
        const unsigned short* xp = xb_ + (size_t)n*96 + khalf*8;
        short8 z = {};
        #pragma unroll
        for (int kk = 0; kk < 3; ++kk){
          short8 v = *(const short8*)(xp + kk*32);
          xf[i][kk] = im ? v : z;
        }
      }
      #pragma unroll 1
      for (int mi = 0; mi < 3; ++mi){
        int orow = row0 + mi*16 + hy;
        const float* wp = kv_w + (size_t)orow*96 + khalf*8;
        short8 a0 = pack8(*(const float4*)(wp),    *(const float4*)(wp+4));
        short8 a1 = pack8(*(const float4*)(wp+32), *(const float4*)(wp+36));
        short8 a2 = pack8(*(const float4*)(wp+64), *(const float4*)(wp+68));
        float4 bv = *(const float4*)&kv_b[row0 + mi*16 + khalf*4];
        #pragma unroll
        for (int i = 0; i < 3; ++i){
          if (i >= np) break;
          int pt = w + i*8;
          f32x4 acc = {bv.x, bv.y, bv.z, bv.w};
          acc = __builtin_amdgcn_mfma_f32_16x16x32_bf16(a0, xf[i][0], acc, 0,0,0);
          acc = __builtin_amdgcn_mfma_f32_16x16x32_bf16(a1, xf[i][1], acc, 0,0,0);
          acc = __builtin_amdgcn_mfma_f32_16x16x32_bf16(a2, xf[i][2], acc, 0,0,0);
          #pragma unroll
          for (int r = 0; r < 4; ++r){
            int ch = mi*16 + khalf*4 + r;
            Ysh[ch*YP + pt*16 + hy] = imv[i] ? f2b(acc[r]) : (unsigned short)0;
          }
        }
      }
    }
    __syncthreads();
    float* gout = out + (size_t)(cv>>1)*NB*C*NPIX + ((size_t)b*C + (cv&1)*48)*NPIX;
    for (int slot = t; slot < 48*16; slot += 512){
      int c = slot >> 4, j = slot & 15;
      const unsigned short* yb = &Ysh[c*YP + j*16];
      float u0[16], u1[16], u2[16];
      {
        short8 s0 = *(const short8*)(yb),    s1 = *(const short8*)(yb+8);
        short8 s2 = *(const short8*)(yb+16), s3 = *(const short8*)(yb+24);
        short8 s4 = *(const short8*)(yb+32), s5 = *(const short8*)(yb+40);
        #pragma unroll
        for (int u = 0; u < 8; ++u){
          u0[u]=b2f((unsigned short)s0[u]); u0[u+8]=b2f((unsigned short)s1[u]);
          u1[u]=b2f((unsigned short)s2[u]); u1[u+8]=b2f((unsigned short)s3[u]);
          u2[u]=b2f((unsigned short)s4[u]); u2[u+8]=b2f((unsigned short)s5[u]);
        }
      }
      const float* wd = kvd_w + (size_t)(row0 + c)*9;
      float w00=wd[0],w01=wd[1],w02=wd[2],w10=wd[3],w11=wd[4],w12=wd[5],w20=wd[6],w21=wd[7],w22=wd[8];
      float bb = kvd_b[row0 + c];
      float* op = gout + (size_t)c*NPIX + (size_t)gy0*WW + gx0 + j;
      #pragma unroll
      for (int py = 0; py < 14; ++py){
        float s = bb;
        s = fmaf(w00,u0[py],s); s = fmaf(w10,u0[py+1],s); s = fmaf(w20,u0[py+2],s);
        s = fmaf(w01,u1[py],s); s = fmaf(w11,u1[py+1],s); s = fmaf(w21,u1[py+2],s);
        s = fmaf(w02,u2[py],s); s = fmaf(w12,u2[py+1],s); s = fmaf(w22,u2[py+2],s);
        if (gy0 + py < HH) op[(size_t)py*WW] = s;
      }
    }
    __syncthreads();
  }
}

// ============================ fallback: round-2 fused kernel ============================
__global__ __launch_bounds__(512, 1) void k1_fused(
  const float* __restrict__ content, const float* __restrict__ style,
  const float* __restrict__ q_w, const float* __restrict__ q_b,
  const float* __restrict__ qd_w, const float* __restrict__ qd_b,
  const float* __restrict__ kv_w, const float* __restrict__ kv_b,
  const float* __restrict__ kvd_w, const float* __restrict__ kvd_b,
  float* __restrict__ out, float* __restrict__ ws)
{
  __shared__ unsigned short Xs[256*XP];
  __shared__ unsigned short qS[C*SP];
  __shared__ unsigned short Ysh[48*SP];
  __shared__ unsigned short kT[48*SP];
  __shared__ float redq[C], redk[C];

  const int t = threadIdx.x;
  const int lane = t & 63;
  const int w = t >> 6;
  const int b = blockIdx.y;
  const int tile = blockIdx.x;
  const int tx = tile % NT, ty = tile / NT;

  {
    unsigned* q32 = (unsigned*)qS;
    for (int i = t; i < C*SP/2; i += 512) q32[i] = 0u;
    unsigned* k32 = (unsigned*)kT;
    for (int i = t; i < 48*SP/2; i += 512) k32[i] = 0u;
    if (t < C){ redq[t] = 0.f; redk[t] = 0.f; }
  }
  __syncthreads();

  auto stageX = [&](const float* inb){
    for (int i = 0; i < 12; ++i){
      int s = i*512 + t;
      int px = s & 255, chg = s >> 8;
      int hx = px & 15, hy = px >> 4;
      int gx = tx*TI - 1 + hx, gy = ty*TI - 1 + hy;
      bool im = (gx>=0) && (gx<WW) && (gy>=0) && (gy<HH);
      const float* p = inb + (size_t)(chg*4)*NPIX + (im ? (gy*WW+gx) : 0);
      float v0 = im ? p[0] : 0.f;
      float v1 = im ? p[NPIX] : 0.f;
      float v2 = im ? p[2*NPIX] : 0.f;
      float v3 = im ? p[3*NPIX] : 0.f;
      unsigned lo = ((unsigned)f2b(v1) << 16) | (unsigned)f2b(v0);
      unsigned hi = ((unsigned)f2b(v3) << 16) | (unsigned)f2b(v2);
      *(uint2*)&Xs[px*XP + chg*4] = make_uint2(lo, hi);
    }
  };

  auto convChunk = [&](const float* wmat, const float* bias, int row0){
    for (int mi = 0; mi < 3; ++mi){
      int m0 = mi*16;
      int orow = row0 + m0 + (lane & 15);
      const float* wp = wmat + (size_t)orow*96 + ((lane>>4)*8);
      short8 a0 = pack8(*(const float4*)(wp),    *(const float4*)(wp+4));
      short8 a1 = pack8(*(const float4*)(wp+32), *(const float4*)(wp+36));
      short8 a2 = pack8(*(const float4*)(wp+64), *(const float4*)(wp+68));
      float4 bv = *(const float4*)&bias[row0 + m0 + (lane>>4)*4];
      for (int ni = 0; ni < 2; ++ni){
        int px = (w*2 + ni)*16 + (lane & 15);
        f32x4 acc = {bv.x, bv.y, bv.z, bv.w};
        const unsigned short* xb = &Xs[px*XP + ((lane>>4)*8)];
        acc = __builtin_amdgcn_mfma_f32_16x16x32_bf16(a0, *(const short8*)(xb),    acc, 0,0,0);
        acc = __builtin_amdgcn_mfma_f32_16x16x32_bf16(a1, *(const short8*)(xb+32), acc, 0,0,0);
        acc = __builtin_amdgcn_mfma_f32_16x16x32_bf16(a2, *(const short8*)(xb+64), acc, 0,0,0);
        int hx = px & 15, hy = px >> 4;
        int gx = tx*TI - 1 + hx, gy = ty*TI - 1 + hy;
        bool im = (gx>=0) && (gx<WW) && (gy>=0) && (gy<HH);
        int chb = m0 + (lane>>4)*4;
        #pragma unroll
        for (int r = 0; r < 4; ++r)
          Ysh[(chb + r)*SP + px] = im ? f2b(acc[r]) : (unsigned short)0;
      }
    }
  };

  auto dwChunk = [&](const float* dww, const float* dwb, int wrow0, int mode,
                     unsigned short* dst, int dstRow0, float* gout){
    for (int slot = t; slot < 48*16; slot += 512){
      int c = slot >> 4, py = slot & 15;
      if (py >= TI){
        if (mode < 2){
          int hr = (py == TI) ? 0 : 15;
          short8 z = {};
          *(short8*)&dst[(dstRow0 + c)*SP + hr*16]     = z;
          *(short8*)&dst[(dstRow0 + c)*SP + hr*16 + 8] = z;
        }
        continue;
      }
      const unsigned short* yb = &Ysh[c*SP + py*16];
      float u0[16], u1[16], u2[16];
      {
        short8 s0 = *(const short8*)(yb),    s1 = *(const short8*)(yb+8);
        short8 s2 = *(const short8*)(yb+16), s3 = *(const short8*)(yb+24);
        short8 s4 = *(const short8*)(yb+32), s5 = *(const short8*)(yb+40);
        #pragma unroll
        for (int j = 0; j < 8; ++j){
          u0[j]=b2f((unsigned short)s0[j]); u0[j+8]=b2f((unsigned short)s1[j]);
          u1[j]=b2f((unsigned short)s2[j]); u1[j+8]=b2f((unsigned short)s3[j]);
          u2[j]=b2f((unsigned short)s4[j]); u2[j+8]=b2f((unsigned short)s5[j]);
        }
      }
      const float* wd = dww + (size_t)(wrow0 + c)*9;
      float w00=wd[0],w01=wd[1],w02=wd[2],w10=wd[3],w11=wd[4],w12=wd[5],w20=wd[6],w21=wd[7],w22=wd[8];
      float bb = dwb[wrow0 + c];
      int gy = ty*TI + py;
      float o[TI];
      #pragma unroll
      for (int j = 0; j < TI; ++j){
        float s = bb;
        s = fmaf(w00,u0[j],s); s = fmaf(w01,u0[j+1],s); s = fmaf(w02,u0[j+2],s);
        s = fmaf(w10,u1[j],s); s = fmaf(w11,u1[j+1],s); s = fmaf(w12,u1[j+2],s);
        s = fmaf(w20,u2[j],s); s = fmaf(w21,u2[j+1],s); s = fmaf(w22,u2[j+2],s);
        int gx = tx*TI + j;
        bool ok = (gx < WW) && (gy < HH);
        o[j] = ok ? s : 0.f;
      }
      if (mode < 2){
        float sq = 0.f;
        #pragma unroll
        for (int j = 0; j < TI; ++j) sq = fmaf(o[j], o[j], sq);
        atomicAdd((mode==0 ? redq : redk) + wrow0 + c, sq);
        unsigned short vv[16];
        vv[0] = 0; vv[15] = 0;
        #pragma unroll
        for (int j = 0; j < TI; ++j) vv[j+1] = f2b(o[j]);
        *(short8*)&dst[(dstRow0 + c)*SP + (py+1)*16]     = *(short8*)&vv[0];
        *(short8*)&dst[(dstRow0 + c)*SP + (py+1)*16 + 8] = *(short8*)&vv[8];
      } else {
        if (gy < HH){
          float* op = gout + (size_t)c*NPIX + (size_t)gy*WW + tx*TI;
          #pragma unroll
          for (int j = 0; j < TI; ++j){
            if (tx*TI + j < WW) op[j] = o[j];
          }
        }
      }
    }
  };

  auto gram = [&](int cc){
    int h = cc*2 + (w & 1);
    int cl = lane & 31;
    bool cvld = cl < CH;
    int qrow = h*CH + (cvld ? cl : 0);
    int krow = (w & 1)*CH + (cvld ? cl : 0);
    f32x16 g;
    #pragma unroll
    for (int r = 0; r < 16; ++r) g[r] = 0.f;
    short8 z = {};
    #pragma unroll
    for (int ki = 0; ki < 4; ++ki){
      int k0 = ((w>>1)*4 + ki)*16 + (lane>>5)*8;
      short8 qa = *(const short8*)&qS[qrow*SP + k0];
      short8 kb = *(const short8*)&kT[krow*SP + k0];
      if (!cvld){ qa = z; kb = z; }
      g = __builtin_amdgcn_mfma_f32_32x32x16_bf16(qa, kb, g, 0,0,0);
    }
    float* gdst = ws + WS_GRAM + (size_t)(b*HEADS + h)*CH*CH;
    #pragma unroll
    for (int r = 0; r < 16; ++r){
      int row = (r&3) + 8*(r>>2) + 4*(lane>>5);
      int col = lane & 31;
      if (row < CH && col < CH) atomicAdd(&gdst[row*CH + col], g[r]);
    }
  };

  stageX(content + (size_t)b*C*NPIX);
  __syncthreads();
  for (int qc = 0; qc < 2; ++qc){
    convChunk(q_w, q_b, qc*48);
    __syncthreads();
    dwChunk(qd_w, qd_b, qc*48, 0, qS, qc*48, nullptr);
    __syncthreads();
  }
  if (t < C) atomicAdd(&ws[WS_SUMSQ_Q + b*C + t], redq[t]);

  stageX(style + (size_t)b*C*NPIX);
  __syncthreads();
  for (int cc = 0; cc < 2; ++cc){
    convChunk(kv_w, kv_b, cc*48);
    __syncthreads();
    dwChunk(kvd_w, kvd_b, cc*48, 1, kT, 0, nullptr);
    __syncthreads();
    gram(cc);
    __syncthreads();
  }
  if (t < C) atomicAdd(&ws[WS_SUMSQ_K + b*C + t], redk[t]);
  for (int cv = 0; cv < 4; ++cv){
    convChunk(kv_w, kv_b, 96 + cv*48);
    __syncthreads();
    float* gout = out + (size_t)(cv>>1)*NB*C*NPIX + ((size_t)b*C + (cv&1)*48)*NPIX;
    dwChunk(kvd_w, kvd_b, 96 + cv*48, 2, nullptr, 0, gout);
    __syncthreads();
  }
}

// ============================ k2 / k3 (unchanged) ============================
__global__ void k2_attn(
  const float* __restrict__ temp,
  const float* __restrict__ ps_w, const float* __restrict__ psh_w,
  float* __restrict__ ws)
{
  const int b = blockIdx.x;
  const int t = threadIdx.x;
  __shared__ float attn[C * CH];
  __shared__ float nq[C], nk[C];
  if (t < C){
    nq[t] = fmaxf(sqrtf(ws[WS_SUMSQ_Q + b * C + t]), 1e-12f);
    nk[t] = fmaxf(sqrtf(ws[WS_SUMSQ_K + b * C + t]), 1e-12f);
  }
  __syncthreads();
  if (t < C){
    int h = t / CH;
    const float* g = ws + WS_GRAM + (((size_t)b * HEADS + h) * CH + (t % CH)) * CH;
    float tp = temp[h];
    float row[CH];
    float mx = -3.4e38f;
    #pragma unroll
    for (int d = 0; d < CH; ++d){
      row[d] = g[d] / (nq[t] * nk[h * CH + d]) * tp;
      mx = fmaxf(mx, row[d]);
    }
    float s = 0.f;
    #pragma unroll
    for (int d = 0; d < CH; ++d){ row[d] = expf(row[d] - mx); s += row[d]; }
    float inv = 1.f / s;
    #pragma unroll
    for (int d = 0; d < CH; ++d) attn[t * CH + d] = row[d] * inv;
  }
  __syncthreads();
  for (int idx = t; idx < C * C; idx += 256){
    int o = idx / C, dg = idx - o * C;
    int h = dg / CH, d = dg - h * CH;
    float s1 = 0.f, s2 = 0.f;
    #pragma unroll
    for (int c2 = 0; c2 < CH; ++c2){
      float a = attn[(h * CH + c2) * CH + d];
      s1 = fmaf(ps_w [(size_t)o * C + h * CH + c2], a, s1);
      s2 = fmaf(psh_w[(size_t)o * C + h * CH + c2], a, s2);
    }
    ws[WS_MS  + (size_t)b * C * C + idx] = s1;
    ws[WS_MSH + (size_t)b * C * C + idx] = s2;
  }
}

__global__ __launch_bounds__(256, 2) void k3_gemm(
  const float* __restrict__ ps_b, const float* __restrict__ psh_b,
  float* out, const float* __restrict__ ws)
{
  __shared__ unsigned short vS[256*XP];
  const int t = threadIdx.x, lane = t & 63, w = t >> 6;
  const int b = blockIdx.z, which = blockIdx.y;
  const int px0 = blockIdx.x * 256;
  float* base = out + (size_t)which*NB*C*NPIX + (size_t)b*C*NPIX + px0;
  const float* M = ws + (which ? WS_MSH : WS_MS) + (size_t)b*C*C;
  const float* bias = which ? psh_b : ps_b;

  for (int i = 0; i < 24; ++i){
    int s = i*256 + t;
    int px = s & 255, chg = s >> 8;
    const float* p = base + (size_t)(chg*4)*NPIX + px;
    unsigned lo = ((unsigned)f2b(p[NPIX])   << 16) | (unsigned)f2b(p[0]);
    unsigned hi = ((unsigned)f2b(p[3*NPIX]) << 16) | (unsigned)f2b(p[2*NPIX]);
    *(uint2*)&vS[px*XP + chg*4] = make_uint2(lo, hi);
  }
  __syncthreads();

  #pragma unroll 1
  for (int mi = 0; mi < 6; ++mi){
    int m0 = mi*16;
    const float* mp = M + (size_t)(m0 + (lane&15))*C + (lane>>4)*8;
    short8 a0 = pack8(*(const float4*)(mp),    *(const float4*)(mp+4));
    short8 a1 = pack8(*(const float4*)(mp+32), *(const float4*)(mp+36));
    short8 a2 = pack8(*(const float4*)(mp+64), *(const float4*)(mp+68));
    float4 bv = *(const float4*)&bias[m0 + (lane>>4)*4];
    #pragma unroll
    for (int ni = 0; ni < 4; ++ni){
      int px = (w*4 + ni)*16 + (lane & 15);
      f32x4 acc = {bv.x, bv.y, bv.z, bv.w};
      const unsigned short* xb = &vS[px*XP + ((lane>>4)*8)];
      acc = __builtin_amdgcn_mfma_f32_16x16x32_bf16(a0, *(const short8*)(xb),    acc, 0,0,0);
      acc = __builtin_amdgcn_mfma_f32_16x16x32_bf16(a1, *(const short8*)(xb+32), acc, 0,0,0);
      acc = __builtin_amdgcn_mfma_f32_16x16x32_bf16(a2, *(const short8*)(xb+64), acc, 0,0,0);
      #pragma unroll
      for (int r = 0; r < 4; ++r)
        base[(size_t)(m0 + (lane>>4)*4 + r)*NPIX + px] = acc[r];
    }
  }
}

extern "C" void kernel_launch(void* const* d_in, const int* in_sizes, int n_in,
                              void* d_out, int out_size, void* d_ws, size_t ws_size,
                              hipStream_t stream)
{
  const float* content = (const float*)d_in[0];
  const float* style   = (const float*)d_in[1];
  const float* temp    = (const float*)d_in[2];
  const float* q_w   = (const float*)d_in[3];
  const float* q_b   = (const float*)d_in[4];
  const float* qd_w  = (const float*)d_in[5];
  const float* qd_b  = (const float*)d_in[6];
  const float* kv_w  = (const float*)d_in[7];
  const float* kv_b  = (const float*)d_in[8];
  const float* kvd_w = (const float*)d_in[9];
  const float* kvd_b = (const float*)d_in[10];
  const float* ps_w  = (const float*)d_in[11];
  const float* ps_b  = (const float*)d_in[12];
  const float* psh_w = (const float*)d_in[13];
  const float* psh_b = (const float*)d_in[14];
  float* out = (float*)d_out;
  float* ws  = (float*)d_ws;

  hipMemsetAsync(ws, 0, (size_t)WS_MS * sizeof(float), stream);

  if (ws_size >= XT_OFF_BYTES + XT_BYTES){
    unsigned short* xt = (unsigned short*)((char*)d_ws + XT_OFF_BYTES);
    k0t<<<dim3(NPIX/64, NB, 2), dim3(256), 0, stream>>>(content, style, xt);
    kqk<<<dim3(NTX2*NTY2, NB), dim3(512), 0, stream>>>(
        xt, q_w, q_b, qd_w, qd_b, kv_w, kv_b, kvd_w, kvd_b, ws);
    kvker<<<dim3(NTX2*NTY2, NB), dim3(512), 0, stream>>>(
        xt + (size_t)NB*NPIX*96, kv_w, kv_b, kvd_w, kvd_b, out);
  } else {
    dim3 g1(NT * NT, NB);
    k1_fused<<<g1, dim3(512), 0, stream>>>(content, style, q_w, q_b, qd_w, qd_b,
                                           kv_w, kv_b, kvd_w, kvd_b, out, ws);
  }
  k2_attn<<<dim3(NB), dim3(256), 0, stream>>>(temp, ps_w, psh_w, ws);
  dim3 g3(NPIX / 256, 2, NB);
  k3_gemm<<<g3, dim3(256), 0, stream>>>(ps_b, psh_b, out, ws);
}

// Round 4
// 583.741 us; speedup vs baseline: 4.1449x; 1.1229x over previous
//
#include <hip/hip_runtime.h>

#define NB 4
#define C 96
#define HH 256
#define WW 256
#define NPIX (HH*WW)
#define HEADS 4
#define CH 24

// ---- fallback (round-2) tiling ----
#define TI 14
#define NT 19
#define XP 104
#define SP 264

// ---- tiling: interior 16 wide x 14 tall, halo 18x16 ----
#define NTX2 16
#define NTY2 19
#define NTILES (NTX2*NTY2)
#define YP 296      // Ysh pitch
#define QP 264      // qS/kT pitch
#define VP 104      // vS pitch ([px][ch])

#define WS_SUMSQ_Q 0
#define WS_SUMSQ_K (WS_SUMSQ_Q + NB*C)
#define WS_GRAM    (WS_SUMSQ_K + NB*C)
#define WS_MS      (WS_GRAM + NB*HEADS*CH*CH)
#define WS_MSH     (WS_MS + NB*C*C)

#define XT_OFF_BYTES ((size_t)335872)
#define XT_BYTES   ((size_t)2*NB*NPIX*96*2)
#define PSQ_OFF    (XT_OFF_BYTES + XT_BYTES)
#define PSQ_BYTES  ((size_t)NTILES*NB*192*4)
#define PG_OFF     (PSQ_OFF + PSQ_BYTES)
#define PG_BYTES   ((size_t)NTILES*NB*HEADS*1024*4)
#define MB_OFF     (PG_OFF + PG_BYTES)
#define MB_BYTES   ((size_t)2*NB*96*96*2)
#define WS_NEED    (MB_OFF + MB_BYTES)

typedef short short8 __attribute__((ext_vector_type(8)));
typedef float f32x4 __attribute__((ext_vector_type(4)));
typedef float f32x16 __attribute__((ext_vector_type(16)));

__device__ __forceinline__ unsigned short f2b(float f){
  unsigned u = __float_as_uint(f);
  unsigned r = u + 0x7FFFu + ((u >> 16) & 1u);
  return (unsigned short)(r >> 16);
}
__device__ __forceinline__ float b2f(unsigned short s){
  return __uint_as_float(((unsigned)s) << 16);
}
__device__ __forceinline__ short8 pack8(float4 a, float4 b){
  short8 r;
  r[0]=(short)f2b(a.x); r[1]=(short)f2b(a.y); r[2]=(short)f2b(a.z); r[3]=(short)f2b(a.w);
  r[4]=(short)f2b(b.x); r[5]=(short)f2b(b.y); r[6]=(short)f2b(b.z); r[7]=(short)f2b(b.w);
  return r;
}

// conv1x1 (48 rows) over the 18x16 halo via MFMA -> Ysh column-major [ch][pt*16+hy]
__device__ __forceinline__ void conv48(
  const unsigned short* __restrict__ xbase, const float* __restrict__ wmat,
  const float* __restrict__ bias, int row0,
  int gx0, int gy0, int lane, int w, unsigned short* __restrict__ Ysh)
{
  const int hy = lane & 15, khalf = lane >> 4;
  const int gy = gy0 - 1 + hy;
  short8 xf[3][3]; bool imv[3]; int np = (w < 2) ? 3 : 2;
  #pragma unroll
  for (int i = 0; i < 3; ++i){
    if (i >= np) break;
    int pt = w + i*8;
    int gx = gx0 - 1 + pt;
    bool im = (gx>=0) && (gx<WW) && (gy>=0) && (gy<HH);
    imv[i] = im;
    int n = im ? (gy*WW + gx) : 0;
    const unsigned short* xp = xbase + (size_t)n*96 + khalf*8;
    short8 z = {};
    #pragma unroll
    for (int kk = 0; kk < 3; ++kk){
      short8 v = *(const short8*)(xp + kk*32);
      xf[i][kk] = im ? v : z;
    }
  }
  #pragma unroll 1
  for (int mi = 0; mi < 3; ++mi){
    int orow = row0 + mi*16 + hy;
    const float* wp = wmat + (size_t)orow*96 + khalf*8;
    short8 a0 = pack8(*(const float4*)(wp),    *(const float4*)(wp+4));
    short8 a1 = pack8(*(const float4*)(wp+32), *(const float4*)(wp+36));
    short8 a2 = pack8(*(const float4*)(wp+64), *(const float4*)(wp+68));
    float4 bv = *(const float4*)&bias[row0 + mi*16 + khalf*4];
    #pragma unroll
    for (int i = 0; i < 3; ++i){
      if (i >= np) break;
      int pt = w + i*8;
      f32x4 acc = {bv.x, bv.y, bv.z, bv.w};
      acc = __builtin_amdgcn_mfma_f32_16x16x32_bf16(a0, xf[i][0], acc, 0,0,0);
      acc = __builtin_amdgcn_mfma_f32_16x16x32_bf16(a1, xf[i][1], acc, 0,0,0);
      acc = __builtin_amdgcn_mfma_f32_16x16x32_bf16(a2, xf[i][2], acc, 0,0,0);
      #pragma unroll
      for (int r = 0; r < 4; ++r){
        int ch = mi*16 + khalf*4 + r;
        Ysh[ch*YP + pt*16 + hy] = imv[i] ? f2b(acc[r]) : (unsigned short)0;
      }
    }
  }
}

// ============================ K0: fp32 [c][n] -> bf16 [n][c] ============================
__global__ __launch_bounds__(256) void k0t(
  const float* __restrict__ content, const float* __restrict__ style,
  unsigned short* __restrict__ xt)
{
  __shared__ unsigned short Xt[96*68];
  const int t = threadIdx.x;
  const int n0 = blockIdx.x * 64;
  const int b = blockIdx.y, src = blockIdx.z;
  const float* in = (src ? style : content) + (size_t)b*C*NPIX;
  #pragma unroll
  for (int i = 0; i < 6; ++i){
    int s = i*256 + t;
    int r = s >> 4, c4 = s & 15;
    float4 f = *(const float4*)(in + (size_t)r*NPIX + n0 + c4*4);
    unsigned lo = ((unsigned)f2b(f.y) << 16) | f2b(f.x);
    unsigned hi = ((unsigned)f2b(f.w) << 16) | f2b(f.z);
    *(uint2*)&Xt[r*68 + c4*4] = make_uint2(lo, hi);
  }
  __syncthreads();
  unsigned* dst = (unsigned*)(xt + (((size_t)src*NB + b)*NPIX + n0)*96);
  #pragma unroll
  for (int i = 0; i < 12; ++i){
    int s = i*256 + t;
    int j = s / 48, c2 = s - j*48;
    unsigned v = ((unsigned)Xt[(c2*2+1)*68 + j] << 16) | Xt[(c2*2)*68 + j];
    dst[(size_t)j*48 + c2] = v;
  }
}

// ============================ K_qk: partial Gram + partial sumsq (no atomics) ============================
__global__ __launch_bounds__(512, 4) void kqk(
  const unsigned short* __restrict__ xt,
  const float* __restrict__ q_w, const float* __restrict__ q_b,
  const float* __restrict__ qd_w, const float* __restrict__ qd_b,
  const float* __restrict__ kv_w, const float* __restrict__ kv_b,
  const float* __restrict__ kvd_w, const float* __restrict__ kvd_b,
  float* __restrict__ pg, float* __restrict__ psq)
{
  __shared__ unsigned short Ysh[48*YP];
  __shared__ unsigned short qS[48*QP];
  __shared__ unsigned short kT[48*QP];
  __shared__ float redq[C], redk[C];

  const int t = threadIdx.x, lane = t & 63, w = t >> 6;
  const int b = blockIdx.y, tile = blockIdx.x;
  const int txx = tile & 15, tyy = tile >> 4;
  const int gx0 = txx*16, gy0 = tyy*14;
  if (t < C){ redq[t] = 0.f; redk[t] = 0.f; }
  __syncthreads();

  const unsigned short* xc = xt + ((size_t)(0*NB + b))*NPIX*96;
  const unsigned short* xs = xt + ((size_t)(1*NB + b))*NPIX*96;

  auto dwQK = [&](const float* dww, const float* dwb, int wrow0,
                  unsigned short* dst, float* red){
    for (int slot = t; slot < 48*16; slot += 512){
      int c = slot >> 4, j = slot & 15;
      const unsigned short* yb = &Ysh[c*YP + j*16];
      float u0[16], u1[16], u2[16];
      {
        short8 s0 = *(const short8*)(yb),    s1 = *(const short8*)(yb+8);
        short8 s2 = *(const short8*)(yb+16), s3 = *(const short8*)(yb+24);
        short8 s4 = *(const short8*)(yb+32), s5 = *(const short8*)(yb+40);
        #pragma unroll
        for (int u = 0; u < 8; ++u){
          u0[u]=b2f((unsigned short)s0[u]); u0[u+8]=b2f((unsigned short)s1[u]);
          u1[u]=b2f((unsigned short)s2[u]); u1[u+8]=b2f((unsigned short)s3[u]);
          u2[u]=b2f((unsigned short)s4[u]); u2[u+8]=b2f((unsigned short)s5[u]);
        }
      }
      const float* wd = dww + (size_t)(wrow0 + c)*9;
      float w00=wd[0],w01=wd[1],w02=wd[2],w10=wd[3],w11=wd[4],w12=wd[5],w20=wd[6],w21=wd[7],w22=wd[8];
      float bb = dwb[wrow0 + c];
      unsigned short vv[16];
      float sq = 0.f;
      #pragma unroll
      for (int py = 0; py < 14; ++py){
        float s = bb;
        s = fmaf(w00,u0[py],s); s = fmaf(w10,u0[py+1],s); s = fmaf(w20,u0[py+2],s);
        s = fmaf(w01,u1[py],s); s = fmaf(w11,u1[py+1],s); s = fmaf(w21,u1[py+2],s);
        s = fmaf(w02,u2[py],s); s = fmaf(w12,u2[py+1],s); s = fmaf(w22,u2[py+2],s);
        if (gy0 + py >= HH) s = 0.f;
        sq = fmaf(s, s, sq);
        vv[py] = f2b(s);
      }
      vv[14] = 0; vv[15] = 0;
      atomicAdd(&red[wrow0 + c], sq);
      *(short8*)&dst[c*QP + j*16]     = *(short8*)&vv[0];
      *(short8*)&dst[c*QP + j*16 + 8] = *(short8*)&vv[8];
    }
  };

  // Gram via 32x32x16 MFMA; cross-slice reduce through Ysh (dead here); stream partials.
  auto gram = [&](int cc){
    int hl = w & 1, slice = w >> 1;
    int cl = lane & 31; bool cv = cl < CH;
    int row = hl*CH + (cv ? cl : 0);
    f32x16 g;
    #pragma unroll
    for (int r = 0; r < 16; ++r) g[r] = 0.f;
    short8 z = {};
    for (int ks = slice; ks < 16; ks += 4){
      int ko = ks*16 + (lane>>5)*8;
      short8 qa = *(const short8*)&qS[row*QP + ko];
      short8 kb = *(const short8*)&kT[row*QP + ko];
      if (!cv){ qa = z; kb = z; }
      g = __builtin_amdgcn_mfma_f32_32x32x16_bf16(qa, kb, g, 0,0,0);
    }
    float* stg = (float*)Ysh;
    if (slice != 0){
      float* dst = stg + (size_t)(hl*3 + slice - 1)*1024;
      #pragma unroll
      for (int r = 0; r < 16; ++r) dst[r*64 + lane] = g[r];
    }
    __syncthreads();
    if (slice == 0){
      const float* s0 = stg + (size_t)(hl*3 + 0)*1024;
      const float* s1 = stg + (size_t)(hl*3 + 1)*1024;
      const float* s2 = stg + (size_t)(hl*3 + 2)*1024;
      float* dst = pg + ((size_t)(tile*NB + b)*HEADS + cc*2 + hl)*1024;
      #pragma unroll
      for (int r = 0; r < 16; ++r){
        int ix = r*64 + lane;
        dst[ix] = g[r] + s0[ix] + s1[ix] + s2[ix];
      }
    }
  };

  #pragma unroll 1
  for (int cc = 0; cc < 2; ++cc){
    conv48(xc, q_w, q_b, cc*48, gx0, gy0, lane, w, Ysh);
    __syncthreads();
    dwQK(qd_w, qd_b, cc*48, qS, redq);
    __syncthreads();
    conv48(xs, kv_w, kv_b, cc*48, gx0, gy0, lane, w, Ysh);
    __syncthreads();
    dwQK(kvd_w, kvd_b, cc*48, kT, redk);
    __syncthreads();
    gram(cc);
    __syncthreads();
  }
  if (t < 192){
    float v = (t < 96) ? redq[t] : redk[t - 96];
    psq[(size_t)(tile*NB + b)*192 + t] = v;
  }
}

// ============================ K_gred: reduce partials -> Gram + sumsq ============================
__global__ __launch_bounds__(256) void kgred(
  const float* __restrict__ pg, const float* __restrict__ psq, float* __restrict__ ws)
{
  const int bh = blockIdx.x;
  const int b = bh >> 2, h = bh & 3;
  const int t = threadIdx.x;
  float a0=0.f, a1=0.f, a2=0.f, a3=0.f, sq=0.f;
  for (int tile = 0; tile < NTILES; ++tile){
    const float* p = pg + ((size_t)(tile*NB + b)*HEADS + h)*1024;
    a0 += p[t]; a1 += p[t+256]; a2 += p[t+512]; a3 += p[t+768];
    if (t < 48){
      int ch = h*CH + (t % CH);
      sq += psq[(size_t)(tile*NB + b)*192 + (t < CH ? ch : 96 + ch)];
    }
  }
  if (t < 48){
    if (t < CH) ws[WS_SUMSQ_Q + b*C + h*CH + t] = sq;
    else        ws[WS_SUMSQ_K + b*C + h*CH + (t - CH)] = sq;
  }
  float accs[4] = {a0, a1, a2, a3};
  #pragma unroll
  for (int i = 0; i < 4; ++i){
    int idx = i*256 + t;
    int r = idx >> 6, ln = idx & 63;
    int row = (r&3) + 8*(r>>2) + 4*(ln>>5);
    int col = ln & 31;
    if (row < CH && col < CH)
      ws[WS_GRAM + ((size_t)(b*HEADS + h)*CH + row)*CH + col] = accs[i];
  }
}

// ============================ k2: softmax + M matrices (fp32 + bf16) ============================
__global__ void k2_attn(
  const float* __restrict__ temp,
  const float* __restrict__ ps_w, const float* __restrict__ psh_w,
  float* __restrict__ ws, unsigned short* __restrict__ mb)
{
  const int b = blockIdx.x;
  const int t = threadIdx.x;
  __shared__ float attn[C * CH];
  __shared__ float nq[C], nk[C];
  if (t < C){
    nq[t] = fmaxf(sqrtf(ws[WS_SUMSQ_Q + b * C + t]), 1e-12f);
    nk[t] = fmaxf(sqrtf(ws[WS_SUMSQ_K + b * C + t]), 1e-12f);
  }
  __syncthreads();
  if (t < C){
    int h = t / CH;
    const float* g = ws + WS_GRAM + (((size_t)b * HEADS + h) * CH + (t % CH)) * CH;
    float tp = temp[h];
    float row[CH];
    float mx = -3.4e38f;
    #pragma unroll
    for (int d = 0; d < CH; ++d){
      row[d] = g[d] / (nq[t] * nk[h * CH + d]) * tp;
      mx = fmaxf(mx, row[d]);
    }
    float s = 0.f;
    #pragma unroll
    for (int d = 0; d < CH; ++d){ row[d] = expf(row[d] - mx); s += row[d]; }
    float inv = 1.f / s;
    #pragma unroll
    for (int d = 0; d < CH; ++d) attn[t * CH + d] = row[d] * inv;
  }
  __syncthreads();
  for (int idx = t; idx < C * C; idx += 256){
    int o = idx / C, dg = idx - o * C;
    int h = dg / CH, d = dg - h * CH;
    float s1 = 0.f, s2 = 0.f;
    #pragma unroll
    for (int c2 = 0; c2 < CH; ++c2){
      float a = attn[(h * CH + c2) * CH + d];
      s1 = fmaf(ps_w [(size_t)o * C + h * CH + c2], a, s1);
      s2 = fmaf(psh_w[(size_t)o * C + h * CH + c2], a, s2);
    }
    ws[WS_MS  + (size_t)b * C * C + idx] = s1;
    ws[WS_MSH + (size_t)b * C * C + idx] = s2;
    if (mb){
      mb[((size_t)0*NB + b)*9216 + idx] = f2b(s1);
      mb[((size_t)1*NB + b)*9216 + idx] = f2b(s2);
    }
  }
}

// ============================ kv_out: v conv+dw then M-transform -> out ============================
__global__ __launch_bounds__(512, 4) void kv_out(
  const unsigned short* __restrict__ xs,
  const float* __restrict__ kv_w, const float* __restrict__ kv_b,
  const float* __restrict__ kvd_w, const float* __restrict__ kvd_b,
  const float* __restrict__ ps_b, const float* __restrict__ psh_b,
  const unsigned short* __restrict__ mb, float* __restrict__ out)
{
  __shared__ unsigned short Ysh[48*YP];
  __shared__ unsigned short vS[224*VP];
  const int t = threadIdx.x, lane = t & 63, w = t >> 6;
  const int b = blockIdx.y, tile = blockIdx.x;
  const int txx = tile & 15, tyy = tile >> 4;
  const int gx0 = txx*16, gy0 = tyy*14;
  const unsigned short* xb_ = xs + (size_t)b*NPIX*96;

  #pragma unroll 1
  for (int which = 0; which < 2; ++which){
    #pragma unroll 1
    for (int cv = 0; cv < 2; ++cv){
      int row0 = 96 + which*96 + cv*48;
      conv48(xb_, kv_w, kv_b, row0, gx0, gy0, lane, w, Ysh);
      __syncthreads();
      for (int slot = t; slot < 48*16; slot += 512){
        int c = slot >> 4, j = slot & 15;
        const unsigned short* yb = &Ysh[c*YP + j*16];
        float u0[16], u1[16], u2[16];
        {
          short8 s0 = *(const short8*)(yb),    s1 = *(const short8*)(yb+8);
          short8 s2 = *(const short8*)(yb+16), s3 = *(const short8*)(yb+24);
          short8 s4 = *(const short8*)(yb+32), s5 = *(const short8*)(yb+40);
          #pragma unroll
          for (int u = 0; u < 8; ++u){
            u0[u]=b2f((unsigned short)s0[u]); u0[u+8]=b2f((unsigned short)s1[u]);
            u1[u]=b2f((unsigned short)s2[u]); u1[u+8]=b2f((unsigned short)s3[u]);
            u2[u]=b2f((unsigned short)s4[u]); u2[u+8]=b2f((unsigned short)s5[u]);
          }
        }
        const float* wd = kvd_w + (size_t)(row0 + c)*9;
        float w00=wd[0],w01=wd[1],w02=wd[2],w10=wd[3],w11=wd[4],w12=wd[5],w20=wd[6],w21=wd[7],w22=wd[8];
        float bb = kvd_b[row0 + c];
        #pragma unroll
        for (int py = 0; py < 14; ++py){
          float s = bb;
          s = fmaf(w00,u0[py],s); s = fmaf(w10,u0[py+1],s); s = fmaf(w20,u0[py+2],s);
          s = fmaf(w01,u1[py],s); s = fmaf(w11,u1[py+1],s); s = fmaf(w21,u1[py+2],s);
          s = fmaf(w02,u2[py],s); s = fmaf(w12,u2[py+1],s); s = fmaf(w22,u2[py+2],s);
          vS[(py*16 + j)*VP + cv*48 + c] = f2b(s);
        }
      }
      __syncthreads();
    }
    // out[o][px] = bias[o] + sum_d M[o][d]*v[d][px]  (K=96, per 16x16 tile)
    const unsigned short* mbp = mb + ((size_t)which*NB + b)*9216;
    const float* bias = which ? psh_b : ps_b;
    float* ob = out + (size_t)which*NB*C*NPIX + (size_t)b*C*NPIX;
    for (int tl = w; tl < 84; tl += 8){
      int mi = tl / 14, n = tl - mi*14;
      const unsigned short* mp = mbp + (size_t)(mi*16 + (lane&15))*96 + (lane>>4)*8;
      short8 a0 = *(const short8*)(mp);
      short8 a1 = *(const short8*)(mp + 32);
      short8 a2 = *(const short8*)(mp + 64);
      float4 bv = *(const float4*)&bias[mi*16 + (lane>>4)*4];
      f32x4 acc = {bv.x, bv.y, bv.z, bv.w};
      const unsigned short* xb = &vS[(size_t)(n*16 + (lane&15))*VP + (lane>>4)*8];
      acc = __builtin_amdgcn_mfma_f32_16x16x32_bf16(a0, *(const short8*)(xb),    acc, 0,0,0);
      acc = __builtin_amdgcn_mfma_f32_16x16x32_bf16(a1, *(const short8*)(xb+32), acc, 0,0,0);
      acc = __builtin_amdgcn_mfma_f32_16x16x32_bf16(a2, *(const short8*)(xb+64), acc, 0,0,0);
      int gy = gy0 + n;
      if (gy < HH){
        #pragma unroll
        for (int r = 0; r < 4; ++r)
          ob[(size_t)(mi*16 + (lane>>4)*4 + r)*NPIX + gy*WW + gx0 + (lane&15)] = acc[r];
      }
    }
    __syncthreads();
  }
}

// ============================ fallback: round-2 fused kernel + k3 ============================
__global__ __launch_bounds__(512, 1) void k1_fused(
  const float* __restrict__ content, const float* __restrict__ style,
  const float* __restrict__ q_w, const float* __restrict__ q_b,
  const float* __restrict__ qd_w, const float* __restrict__ qd_b,
  const float* __restrict__ kv_w, const float* __restrict__ kv_b,
  const float* __restrict__ kvd_w, const float* __restrict__ kvd_b,
  float* __restrict__ out, float* __restrict__ ws)
{
  __shared__ unsigned short Xs[256*XP];
  __shared__ unsigned short qS[C*SP];
  __shared__ unsigned short Ysh[48*SP];
  __shared__ unsigned short kT[48*SP];
  __shared__ float redq[C], redk[C];

  const int t = threadIdx.x;
  const int lane = t & 63;
  const int w = t >> 6;
  const int b = blockIdx.y;
  const int tile = blockIdx.x;
  const int tx = tile % NT, ty = tile / NT;

  {
    unsigned* q32 = (unsigned*)qS;
    for (int i = t; i < C*SP/2; i += 512) q32[i] = 0u;
    unsigned* k32 = (unsigned*)kT;
    for (int i = t; i < 48*SP/2; i += 512) k32[i] = 0u;
    if (t < C){ redq[t] = 0.f; redk[t] = 0.f; }
  }
  __syncthreads();

  auto stageX = [&](const float* inb){
    for (int i = 0; i < 12; ++i){
      int s = i*512 + t;
      int px = s & 255, chg = s >> 8;
      int hx = px & 15, hy = px >> 4;
      int gx = tx*TI - 1 + hx, gy = ty*TI - 1 + hy;
      bool im = (gx>=0) && (gx<WW) && (gy>=0) && (gy<HH);
      const float* p = inb + (size_t)(chg*4)*NPIX + (im ? (gy*WW+gx) : 0);
      float v0 = im ? p[0] : 0.f;
      float v1 = im ? p[NPIX] : 0.f;
      float v2 = im ? p[2*NPIX] : 0.f;
      float v3 = im ? p[3*NPIX] : 0.f;
      unsigned lo = ((unsigned)f2b(v1) << 16) | (unsigned)f2b(v0);
      unsigned hi = ((unsigned)f2b(v3) << 16) | (unsigned)f2b(v2);
      *(uint2*)&Xs[px*XP + chg*4] = make_uint2(lo, hi);
    }
  };

  auto convChunk = [&](const float* wmat, const float* bias, int row0){
    for (int mi = 0; mi < 3; ++mi){
      int m0 = mi*16;
      int orow = row0 + m0 + (lane & 15);
      const float* wp = wmat + (size_t)orow*96 + ((lane>>4)*8);
      short8 a0 = pack8(*(const float4*)(wp),    *(const float4*)(wp+4));
      short8 a1 = pack8(*(const float4*)(wp+32), *(const float4*)(wp+36));
      short8 a2 = pack8(*(const float4*)(wp+64), *(const float4*)(wp+68));
      float4 bv = *(const float4*)&bias[row0 + m0 + (lane>>4)*4];
      for (int ni = 0; ni < 2; ++ni){
        int px = (w*2 + ni)*16 + (lane & 15);
        f32x4 acc = {bv.x, bv.y, bv.z, bv.w};
        const unsigned short* xb = &Xs[px*XP + ((lane>>4)*8)];
        acc = __builtin_amdgcn_mfma_f32_16x16x32_bf16(a0, *(const short8*)(xb),    acc, 0,0,0);
        acc = __builtin_amdgcn_mfma_f32_16x16x32_bf16(a1, *(const short8*)(xb+32), acc, 0,0,0);
        acc = __builtin_amdgcn_mfma_f32_16x16x32_bf16(a2, *(const short8*)(xb+64), acc, 0,0,0);
        int hx = px & 15, hy = px >> 4;
        int gx = tx*TI - 1 + hx, gy = ty*TI - 1 + hy;
        bool im = (gx>=0) && (gx<WW) && (gy>=0) && (gy<HH);
        int chb = m0 + (lane>>4)*4;
        #pragma unroll
        for (int r = 0; r < 4; ++r)
          Ysh[(chb + r)*SP + px] = im ? f2b(acc[r]) : (unsigned short)0;
      }
    }
  };

  auto dwChunk = [&](const float* dww, const float* dwb, int wrow0, int mode,
                     unsigned short* dst, int dstRow0, float* gout){
    for (int slot = t; slot < 48*16; slot += 512){
      int c = slot >> 4, py = slot & 15;
      if (py >= TI){
        if (mode < 2){
          int hr = (py == TI) ? 0 : 15;
          short8 z = {};
          *(short8*)&dst[(dstRow0 + c)*SP + hr*16]     = z;
          *(short8*)&dst[(dstRow0 + c)*SP + hr*16 + 8] = z;
        }
        continue;
      }
      const unsigned short* yb = &Ysh[c*SP + py*16];
      float u0[16], u1[16], u2[16];
      {
        short8 s0 = *(const short8*)(yb),    s1 = *(const short8*)(yb+8);
        short8 s2 = *(const short8*)(yb+16), s3 = *(const short8*)(yb+24);
        short8 s4 = *(const short8*)(yb+32), s5 = *(const short8*)(yb+40);
        #pragma unroll
        for (int j = 0; j < 8; ++j){
          u0[j]=b2f((unsigned short)s0[j]); u0[j+8]=b2f((unsigned short)s1[j]);
          u1[j]=b2f((unsigned short)s2[j]); u1[j+8]=b2f((unsigned short)s3[j]);
          u2[j]=b2f((unsigned short)s4[j]); u2[j+8]=b2f((unsigned short)s5[j]);
        }
      }
      const float* wd = dww + (size_t)(wrow0 + c)*9;
      float w00=wd[0],w01=wd[1],w02=wd[2],w10=wd[3],w11=wd[4],w12=wd[5],w20=wd[6],w21=wd[7],w22=wd[8];
      float bb = dwb[wrow0 + c];
      int gy = ty*TI + py;
      float o[TI];
      #pragma unroll
      for (int j = 0; j < TI; ++j){
        float s = bb;
        s = fmaf(w00,u0[j],s); s = fmaf(w01,u0[j+1],s); s = fmaf(w02,u0[j+2],s);
        s = fmaf(w10,u1[j],s); s = fmaf(w11,u1[j+1],s); s = fmaf(w12,u1[j+2],s);
        s = fmaf(w20,u2[j],s); s = fmaf(w21,u2[j+1],s); s = fmaf(w22,u2[j+2],s);
        int gx = tx*TI + j;
        bool ok = (gx < WW) && (gy < HH);
        o[j] = ok ? s : 0.f;
      }
      if (mode < 2){
        float sq = 0.f;
        #pragma unroll
        for (int j = 0; j < TI; ++j) sq = fmaf(o[j], o[j], sq);
        atomicAdd((mode==0 ? redq : redk) + wrow0 + c, sq);
        unsigned short vv[16];
        vv[0] = 0; vv[15] = 0;
        #pragma unroll
        for (int j = 0; j < TI; ++j) vv[j+1] = f2b(o[j]);
        *(short8*)&dst[(dstRow0 + c)*SP + (py+1)*16]     = *(short8*)&vv[0];
        *(short8*)&dst[(dstRow0 + c)*SP + (py+1)*16 + 8] = *(short8*)&vv[8];
      } else {
        if (gy < HH){
          float* op = gout + (size_t)c*NPIX + (size_t)gy*WW + tx*TI;
          #pragma unroll
          for (int j = 0; j < TI; ++j){
            if (tx*TI + j < WW) op[j] = o[j];
          }
        }
      }
    }
  };

  auto gram = [&](int cc){
    int h = cc*2 + (w & 1);
    int cl = lane & 31;
    bool cvld = cl < CH;
    int qrow = h*CH + (cvld ? cl : 0);
    int krow = (w & 1)*CH + (cvld ? cl : 0);
    f32x16 g;
    #pragma unroll
    for (int r = 0; r < 16; ++r) g[r] = 0.f;
    short8 z = {};
    #pragma unroll
    for (int ki = 0; ki < 4; ++ki){
      int k0 = ((w>>1)*4 + ki)*16 + (lane>>5)*8;
      short8 qa = *(const short8*)&qS[qrow*SP + k0];
      short8 kb = *(const short8*)&kT[krow*SP + k0];
      if (!cvld){ qa = z; kb = z; }
      g = __builtin_amdgcn_mfma_f32_32x32x16_bf16(qa, kb, g, 0,0,0);
    }
    float* gdst = ws + WS_GRAM + (size_t)(b*HEADS + h)*CH*CH;
    #pragma unroll
    for (int r = 0; r < 16; ++r){
      int row = (r&3) + 8*(r>>2) + 4*(lane>>5);
      int col = lane & 31;
      if (row < CH && col < CH) atomicAdd(&gdst[row*CH + col], g[r]);
    }
  };

  stageX(content + (size_t)b*C*NPIX);
  __syncthreads();
  for (int qc = 0; qc < 2; ++qc){
    convChunk(q_w, q_b, qc*48);
    __syncthreads();
    dwChunk(qd_w, qd_b, qc*48, 0, qS, qc*48, nullptr);
    __syncthreads();
  }
  if (t < C) atomicAdd(&ws[WS_SUMSQ_Q + b*C + t], redq[t]);

  stageX(style + (size_t)b*C*NPIX);
  __syncthreads();
  for (int cc = 0; cc < 2; ++cc){
    convChunk(kv_w, kv_b, cc*48);
    __syncthreads();
    dwChunk(kvd_w, kvd_b, cc*48, 1, kT, 0, nullptr);
    __syncthreads();
    gram(cc);
    __syncthreads();
  }
  if (t < C) atomicAdd(&ws[WS_SUMSQ_K + b*C + t], redk[t]);
  for (int cv = 0; cv < 4; ++cv){
    convChunk(kv_w, kv_b, 96 + cv*48);
    __syncthreads();
    float* gout = out + (size_t)(cv>>1)*NB*C*NPIX + ((size_t)b*C + (cv&1)*48)*NPIX;
    dwChunk(kvd_w, kvd_b, 96 + cv*48, 2, nullptr, 0, gout);
    __syncthreads();
  }
}

__global__ __launch_bounds__(256, 2) void k3_gemm(
  const float* __restrict__ ps_b, const float* __restrict__ psh_b,
  float* out, const float* __restrict__ ws)
{
  __shared__ unsigned short vS[256*XP];
  const int t = threadIdx.x, lane = t & 63, w = t >> 6;
  const int b = blockIdx.z, which = blockIdx.y;
  const int px0 = blockIdx.x * 256;
  float* base = out + (size_t)which*NB*C*NPIX + (size_t)b*C*NPIX + px0;
  const float* M = ws + (which ? WS_MSH : WS_MS) + (size_t)b*C*C;
  const float* bias = which ? psh_b : ps_b;

  for (int i = 0; i < 24; ++i){
    int s = i*256 + t;
    int px = s & 255, chg = s >> 8;
    const float* p = base + (size_t)(chg*4)*NPIX + px;
    unsigned lo = ((unsigned)f2b(p[NPIX])   << 16) | (unsigned)f2b(p[0]);
    unsigned hi = ((unsigned)f2b(p[3*NPIX]) << 16) | (unsigned)f2b(p[2*NPIX]);
    *(uint2*)&vS[px*XP + chg*4] = make_uint2(lo, hi);
  }
  __syncthreads();

  #pragma unroll 1
  for (int mi = 0; mi < 6; ++mi){
    int m0 = mi*16;
    const float* mp = M + (size_t)(m0 + (lane&15))*C + (lane>>4)*8;
    short8 a0 = pack8(*(const float4*)(mp),    *(const float4*)(mp+4));
    short8 a1 = pack8(*(const float4*)(mp+32), *(const float4*)(mp+36));
    short8 a2 = pack8(*(const float4*)(mp+64), *(const float4*)(mp+68));
    float4 bv = *(const float4*)&bias[m0 + (lane>>4)*4];
    #pragma unroll
    for (int ni = 0; ni < 4; ++ni){
      int px = (w*4 + ni)*16 + (lane & 15);
      f32x4 acc = {bv.x, bv.y, bv.z, bv.w};
      const unsigned short* xb = &vS[px*XP + ((lane>>4)*8)];
      acc = __builtin_amdgcn_mfma_f32_16x16x32_bf16(a0, *(const short8*)(xb),    acc, 0,0,0);
      acc = __builtin_amdgcn_mfma_f32_16x16x32_bf16(a1, *(const short8*)(xb+32), acc, 0,0,0);
      acc = __builtin_amdgcn_mfma_f32_16x16x32_bf16(a2, *(const short8*)(xb+64), acc, 0,0,0);
      #pragma unroll
      for (int r = 0; r < 4; ++r)
        base[(size_t)(m0 + (lane>>4)*4 + r)*NPIX + px] = acc[r];
    }
  }
}

extern "C" void kernel_launch(void* const* d_in, const int* in_sizes, int n_in,
                              void* d_out, int out_size, void* d_ws, size_t ws_size,
                              hipStream_t stream)
{
  const float* content = (const float*)d_in[0];
  const float* style   = (const float*)d_in[1];
  const float* temp    = (const float*)d_in[2];
  const float* q_w   = (const float*)d_in[3];
  const float* q_b   = (const float*)d_in[4];
  const float* qd_w  = (const float*)d_in[5];
  const float* qd_b  = (const float*)d_in[6];
  const float* kv_w  = (const float*)d_in[7];
  const float* kv_b  = (const float*)d_in[8];
  const float* kvd_w = (const float*)d_in[9];
  const float* kvd_b = (const float*)d_in[10];
  const float* ps_w  = (const float*)d_in[11];
  const float* ps_b  = (const float*)d_in[12];
  const float* psh_w = (const float*)d_in[13];
  const float* psh_b = (const float*)d_in[14];
  float* out = (float*)d_out;
  float* ws  = (float*)d_ws;

  if (ws_size >= WS_NEED){
    unsigned short* xt = (unsigned short*)((char*)d_ws + XT_OFF_BYTES);
    float* pg  = (float*)((char*)d_ws + PG_OFF);
    float* psq = (float*)((char*)d_ws + PSQ_OFF);
    unsigned short* mb = (unsigned short*)((char*)d_ws + MB_OFF);

    k0t<<<dim3(NPIX/64, NB, 2), dim3(256), 0, stream>>>(content, style, xt);
    kqk<<<dim3(NTILES, NB), dim3(512), 0, stream>>>(
        xt, q_w, q_b, qd_w, qd_b, kv_w, kv_b, kvd_w, kvd_b, pg, psq);
    kgred<<<dim3(NB*HEADS), dim3(256), 0, stream>>>(pg, psq, ws);
    k2_attn<<<dim3(NB), dim3(256), 0, stream>>>(temp, ps_w, psh_w, ws, mb);
    kv_out<<<dim3(NTILES, NB), dim3(512), 0, stream>>>(
        xt + (size_t)NB*NPIX*96, kv_w, kv_b, kvd_w, kvd_b, ps_b, psh_b, mb, out);
  } else {
    hipMemsetAsync(ws, 0, (size_t)WS_MS * sizeof(float), stream);
    dim3 g1(NT * NT, NB);
    k1_fused<<<g1, dim3(512), 0, stream>>>(content, style, q_w, q_b, qd_w, qd_b,
                                           kv_w, kv_b, kvd_w, kvd_b, out, ws);
    k2_attn<<<dim3(NB), dim3(256), 0, stream>>>(temp, ps_w, psh_w, ws, nullptr);
    dim3 g3(NPIX / 256, 2, NB);
    k3_gemm<<<g3, dim3(256), 0, stream>>>(ps_b, psh_b, out, ws);
  }
}

// Round 5
// 500.881 us; speedup vs baseline: 4.8306x; 1.1654x over previous
//
#include <hip/hip_runtime.h>

#define NB 4
#define C 96
#define HH 256
#define WW 256
#define NPIX (HH*WW)
#define HEADS 4
#define CH 24

// ---- tiling: interior 16 wide x 14 tall, halo 18x16 ----
#define NTX2 16
#define NTY2 19
#define NTILES (NTX2*NTY2)
#define YP 296      // col-major Ysh pitch (fallback kernels)
#define QP 264      // qS/kT pitch (fallback)
#define VP 104      // vS pitch (fallback)
#define KSPLIT 128

#define WS_SUMSQ_Q 0
#define WS_SUMSQ_K (WS_SUMSQ_Q + NB*C)
#define WS_GRAM    (WS_SUMSQ_K + NB*C)
#define WS_MS      (WS_GRAM + NB*HEADS*CH*CH)
#define WS_MSH     (WS_MS + NB*C*C)

// shared xt region
#define XT_OFF_BYTES ((size_t)335872)
#define XT_BYTES   ((size_t)2*NB*NPIX*96*2)

// ---- fallback (r4) layout ----
#define F_PSQ_OFF   (XT_OFF_BYTES + XT_BYTES)
#define F_PSQ_BYTES ((size_t)NTILES*NB*192*4)
#define F_PG_OFF    (F_PSQ_OFF + F_PSQ_BYTES)
#define F_PG_BYTES  ((size_t)NTILES*NB*HEADS*1024*4)
#define F_MB_OFF    (F_PG_OFF + F_PG_BYTES)
#define F_MB_BYTES  ((size_t)2*NB*96*96*2)
#define F_WS_NEED   (F_MB_OFF + F_MB_BYTES)

// ---- new layout ----
#define QK_OFF    (XT_OFF_BYTES + XT_BYTES)
#define QK_BYTES  ((size_t)2*NB*96*NPIX*2)
#define VB_OFF    (QK_OFF + QK_BYTES)              // v_shift only ([b][n][96] bf16)
#define VB_BYTES  ((size_t)NB*NPIX*96*2)
#define PG_OFF    (VB_OFF + VB_BYTES)
#define PG_BYTES  ((size_t)KSPLIT*NB*9216*4)
#define PSQ_OFF   (PG_OFF + PG_BYTES)
#define PSQ_BYTES ((size_t)2*NTILES*NB*96*4)
#define MB_OFF    (PSQ_OFF + PSQ_BYTES)
#define MB_BYTES  ((size_t)2*NB*96*96*2)
#define WB_OFF    (MB_OFF + MB_BYTES)
#define WB_BYTES  ((size_t)384*96*2)
#define WS_NEED2  (WB_OFF + WB_BYTES)

typedef short short8 __attribute__((ext_vector_type(8)));
typedef float f32x4 __attribute__((ext_vector_type(4)));
typedef float f32x16 __attribute__((ext_vector_type(16)));

__device__ __forceinline__ unsigned short f2b(float f){
  unsigned u = __float_as_uint(f);
  unsigned r = u + 0x7FFFu + ((u >> 16) & 1u);
  return (unsigned short)(r >> 16);
}
__device__ __forceinline__ float b2f(unsigned short s){
  return __uint_as_float(((unsigned)s) << 16);
}
__device__ __forceinline__ short8 pack8(float4 a, float4 b){
  short8 r;
  r[0]=(short)f2b(a.x); r[1]=(short)f2b(a.y); r[2]=(short)f2b(a.z); r[3]=(short)f2b(a.w);
  r[4]=(short)f2b(b.x); r[5]=(short)f2b(b.y); r[6]=(short)f2b(b.z); r[7]=(short)f2b(b.w);
  return r;
}

// ============================ K0: fp32 [c][n] -> bf16 [n][c] ============================
__global__ __launch_bounds__(256) void k0t(
  const float* __restrict__ content, const float* __restrict__ style,
  unsigned short* __restrict__ xt)
{
  __shared__ unsigned short Xt[96*68];
  const int t = threadIdx.x;
  const int n0 = blockIdx.x * 64;
  const int b = blockIdx.y, src = blockIdx.z;
  const float* in = (src ? style : content) + (size_t)b*C*NPIX;
  #pragma unroll
  for (int i = 0; i < 6; ++i){
    int s = i*256 + t;
    int r = s >> 4, c4 = s & 15;
    float4 f = *(const float4*)(in + (size_t)r*NPIX + n0 + c4*4);
    unsigned lo = ((unsigned)f2b(f.y) << 16) | f2b(f.x);
    unsigned hi = ((unsigned)f2b(f.w) << 16) | f2b(f.z);
    *(uint2*)&Xt[r*68 + c4*4] = make_uint2(lo, hi);
  }
  __syncthreads();
  unsigned* dst = (unsigned*)(xt + (((size_t)src*NB + b)*NPIX + n0)*96);
  #pragma unroll
  for (int i = 0; i < 12; ++i){
    int s = i*256 + t;
    int j = s / 48, c2 = s - j*48;
    unsigned v = ((unsigned)Xt[(c2*2+1)*68 + j] << 16) | Xt[(c2*2)*68 + j];
    dst[(size_t)j*48 + c2] = v;
  }
}

// ============================ kwpack: fp32 weights -> bf16 rows ============================
__global__ __launch_bounds__(256) void kwpack(
  const float* __restrict__ q_w, const float* __restrict__ kv_w,
  unsigned short* __restrict__ wb)
{
  int i = blockIdx.x*256 + threadIdx.x;
  if (i < 9216) wb[i] = f2b(q_w[i]);
  else if (i < 36864) wb[i] = f2b(kv_w[i - 9216]);
}

// ============================ kconv: fused conv1x1+dw3x3 per chunk ============================
// z=0: q (content), z=1: k (style), z=2: v (style, 4 chunks)
__global__ __launch_bounds__(512, 4) void kconv(
  const unsigned short* __restrict__ xt, const unsigned short* __restrict__ wb,
  const float* __restrict__ q_b, const float* __restrict__ qd_w, const float* __restrict__ qd_b,
  const float* __restrict__ kv_b, const float* __restrict__ kvd_w, const float* __restrict__ kvd_b,
  unsigned short* __restrict__ qk, unsigned short* __restrict__ vbs,
  unsigned short* __restrict__ vbh, float* __restrict__ psq)
{
  __shared__ unsigned short Ysh[48*384];   // row-major [ch][hy][pt], pitch 24
  __shared__ float red[96];
  const int t = threadIdx.x, lane = t & 63, w = t >> 6;
  const int tile = blockIdx.x, b = blockIdx.y, z = blockIdx.z;
  const int txx = tile & 15, tyy = tile >> 4;
  const int gx0 = txx*16, gy0 = tyy*14;
  const unsigned short* xsrc = xt + ((size_t)((z ? 1 : 0)*NB + b))*NPIX*96;
  const int nch = (z == 2) ? 4 : 2;
  const int wbbase = z*96;
  const float* cb  = (z==0) ? q_b  : (z==1 ? kv_b : kv_b + 96);
  const float* dww = (z==0) ? qd_w : (z==1 ? kvd_w : kvd_w + 96*9);
  const float* dwb = (z==0) ? qd_b : (z==1 ? kvd_b : kvd_b + 96);

  if (t < 96) red[t] = 0.f;

  // persistent halo fragments (loaded once, reused for all chunks)
  const int hy = lane & 15, khalf = lane >> 4;
  const int gyh = gy0 - 1 + hy;
  short8 xf[3][3]; bool imv[3];
  const int np = (w < 2) ? 3 : 2;
  #pragma unroll
  for (int i = 0; i < 3; ++i){
    if (i >= np) break;
    int pt = w + i*8;
    int gx = gx0 - 1 + pt;
    bool im = (gx>=0) && (gx<WW) && (gyh>=0) && (gyh<HH);
    imv[i] = im;
    const unsigned short* xp = xsrc + (size_t)(im ? (gyh*WW + gx) : 0)*96 + khalf*8;
    short8 zz = {};
    #pragma unroll
    for (int kk = 0; kk < 3; ++kk){
      short8 v = *(const short8*)(xp + kk*32);
      xf[i][kk] = im ? v : zz;
    }
  }

  #pragma unroll 1
  for (int chunk = 0; chunk < nch; ++chunk){
    // conv1x1: 48 output rows over halo
    #pragma unroll 1
    for (int mi = 0; mi < 3; ++mi){
      const unsigned short* wp = wb + (size_t)(wbbase + chunk*48 + mi*16 + hy)*96 + khalf*8;
      short8 a0 = *(const short8*)(wp);
      short8 a1 = *(const short8*)(wp + 32);
      short8 a2 = *(const short8*)(wp + 64);
      float4 bv = *(const float4*)&cb[chunk*48 + mi*16 + khalf*4];
      #pragma unroll
      for (int i = 0; i < 3; ++i){
        if (i >= np) break;
        int pt = w + i*8;
        f32x4 acc = {bv.x, bv.y, bv.z, bv.w};
        acc = __builtin_amdgcn_mfma_f32_16x16x32_bf16(a0, xf[i][0], acc, 0,0,0);
        acc = __builtin_amdgcn_mfma_f32_16x16x32_bf16(a1, xf[i][1], acc, 0,0,0);
        acc = __builtin_amdgcn_mfma_f32_16x16x32_bf16(a2, xf[i][2], acc, 0,0,0);
        #pragma unroll
        for (int r = 0; r < 4; ++r){
          int ch = mi*16 + khalf*4 + r;
          Ysh[ch*384 + hy*24 + pt] = imv[i] ? f2b(acc[r]) : (unsigned short)0;
        }
      }
    }
    __syncthreads();
    // dw 3x3 row-oriented: slot -> (c, py), 16 x-outputs
    for (int slot = t; slot < 672; slot += 512){
      int c = slot / 14, py = slot - (slot/14)*14;
      int gy = gy0 + py;
      if (gy < HH){
        const float* wd = dww + (size_t)(chunk*48 + c)*9;
        float w00=wd[0],w01=wd[1],w02=wd[2],w10=wd[3],w11=wd[4],w12=wd[5],w20=wd[6],w21=wd[7],w22=wd[8];
        float bb = dwb[chunk*48 + c];
        const unsigned short* yb = &Ysh[c*384 + py*24];
        float o[16];
        #pragma unroll
        for (int half = 0; half < 2; ++half){
          float u[3][10];
          #pragma unroll
          for (int uu = 0; uu < 3; ++uu){
            const unsigned short* rp = yb + uu*24 + half*8;
            short8 s = *(const short8*)rp;
            unsigned ex = *(const unsigned*)(rp + 8);
            #pragma unroll
            for (int j = 0; j < 8; ++j) u[uu][j] = b2f((unsigned short)s[j]);
            u[uu][8] = b2f((unsigned short)(ex & 0xffffu));
            u[uu][9] = b2f((unsigned short)(ex >> 16));
          }
          #pragma unroll
          for (int j = 0; j < 8; ++j){
            float s = bb;
            s = fmaf(w00,u[0][j],s); s = fmaf(w01,u[0][j+1],s); s = fmaf(w02,u[0][j+2],s);
            s = fmaf(w10,u[1][j],s); s = fmaf(w11,u[1][j+1],s); s = fmaf(w12,u[1][j+2],s);
            s = fmaf(w20,u[2][j],s); s = fmaf(w21,u[2][j+1],s); s = fmaf(w22,u[2][j+2],s);
            o[half*8 + j] = s;
          }
        }
        if (z < 2){
          float sq = 0.f;
          unsigned short vv[16];
          #pragma unroll
          for (int j = 0; j < 16; ++j){ sq = fmaf(o[j], o[j], sq); vv[j] = f2b(o[j]); }
          atomicAdd(&red[chunk*48 + c], sq);
          unsigned short* qp = qk + ((size_t)(z*NB + b)*96 + chunk*48 + c)*NPIX
                                  + (size_t)gy*WW + gx0;
          *(short8*)qp       = *(const short8*)&vv[0];
          *(short8*)(qp + 8) = *(const short8*)&vv[8];
        } else {
          int which = chunk >> 1;
          int vch = (chunk & 1)*48 + c;
          unsigned short* vp = (which ? vbh : vbs)
                             + ((size_t)b*NPIX + (size_t)gy*WW + gx0)*96 + vch;
          #pragma unroll
          for (int j = 0; j < 16; ++j) vp[(size_t)j*96] = f2b(o[j]);
        }
      }
    }
    __syncthreads();
  }
  if (z < 2 && t < 96)
    psq[((size_t)(z*NTILES + tile)*NB + b)*96 + t] = red[t];
}

// ============================ kgram: partial-K Gram (no LDS, no atomics) ============================
__global__ __launch_bounds__(384) void kgram(
  const unsigned short* __restrict__ qk, float* __restrict__ pg)
{
  const int t = threadIdx.x, lane = t & 63, wv = t >> 6;  // wv < 6 = di
  const int ks = blockIdx.x, b = blockIdx.y;
  const int n0 = ks * (NPIX / KSPLIT);
  const unsigned short* qb = qk + ((size_t)(0*NB + b)*96)*NPIX;
  const unsigned short* kb = qk + ((size_t)(1*NB + b)*96)*NPIX;
  f32x4 acc[6];
  #pragma unroll
  for (int i = 0; i < 6; ++i) acc[i] = (f32x4){0.f,0.f,0.f,0.f};
  #pragma unroll 1
  for (int st = 0; st < (NPIX/KSPLIT)/32; ++st){
    int off = n0 + st*32 + (lane>>4)*8;
    short8 bf = *(const short8*)(kb + (size_t)(wv*16 + (lane&15))*NPIX + off);
    #pragma unroll
    for (int ci = 0; ci < 6; ++ci){
      short8 af = *(const short8*)(qb + (size_t)(ci*16 + (lane&15))*NPIX + off);
      acc[ci] = __builtin_amdgcn_mfma_f32_16x16x32_bf16(af, bf, acc[ci], 0,0,0);
    }
  }
  float* dst = pg + ((size_t)ks*NB + b)*9216;
  #pragma unroll
  for (int ci = 0; ci < 6; ++ci){
    #pragma unroll
    for (int r = 0; r < 4; ++r)
      dst[(ci*6 + wv)*256 + ((lane>>4)*4 + r)*16 + (lane&15)] = acc[ci][r];
  }
}

// ============================ kgredN: reduce Gram + sumsq partials ============================
__global__ __launch_bounds__(256) void kgredN(
  const float* __restrict__ pg, const float* __restrict__ psq, float* __restrict__ ws)
{
  const int b = blockIdx.x, by = blockIdx.y, t = threadIdx.x;
  if (by < 36){
    int ci = by / 6, di = by - (by/6)*6;
    int qrow = ci*16 + (t >> 4), krow = di*16 + (t & 15);
    float s = 0.f;
    for (int ks = 0; ks < KSPLIT; ++ks)
      s += pg[((size_t)ks*NB + b)*9216 + by*256 + t];
    int h = qrow / CH;
    if (krow / CH == h)
      ws[WS_GRAM + ((size_t)(b*HEADS + h)*CH + (qrow % CH))*CH + (krow % CH)] = s;
  } else {
    if (t < 192){
      int src = t / 96, c = t - (t/96)*96;
      float s = 0.f;
      for (int tile = 0; tile < NTILES; ++tile)
        s += psq[((size_t)(src*NTILES + tile)*NB + b)*96 + c];
      ws[(src ? WS_SUMSQ_K : WS_SUMSQ_Q) + b*C + c] = s;
    }
  }
}

// ============================ k2: softmax + M matrices ============================
__global__ void k2_attn(
  const float* __restrict__ temp,
  const float* __restrict__ ps_w, const float* __restrict__ psh_w,
  float* __restrict__ ws, unsigned short* __restrict__ mb)
{
  const int b = blockIdx.x;
  const int t = threadIdx.x;
  __shared__ float attn[C * CH];
  __shared__ float nq[C], nk[C];
  if (t < C){
    nq[t] = fmaxf(sqrtf(ws[WS_SUMSQ_Q + b * C + t]), 1e-12f);
    nk[t] = fmaxf(sqrtf(ws[WS_SUMSQ_K + b * C + t]), 1e-12f);
  }
  __syncthreads();
  if (t < C){
    int h = t / CH;
    const float* g = ws + WS_GRAM + (((size_t)b * HEADS + h) * CH + (t % CH)) * CH;
    float tp = temp[h];
    float row[CH];
    float mx = -3.4e38f;
    #pragma unroll
    for (int d = 0; d < CH; ++d){
      row[d] = g[d] / (nq[t] * nk[h * CH + d]) * tp;
      mx = fmaxf(mx, row[d]);
    }
    float s = 0.f;
    #pragma unroll
    for (int d = 0; d < CH; ++d){ row[d] = expf(row[d] - mx); s += row[d]; }
    float inv = 1.f / s;
    #pragma unroll
    for (int d = 0; d < CH; ++d) attn[t * CH + d] = row[d] * inv;
  }
  __syncthreads();
  for (int idx = t; idx < C * C; idx += 256){
    int o = idx / C, dg = idx - o * C;
    int h = dg / CH, d = dg - h * CH;
    float s1 = 0.f, s2 = 0.f;
    #pragma unroll
    for (int c2 = 0; c2 < CH; ++c2){
      float a = attn[(h * CH + c2) * CH + d];
      s1 = fmaf(ps_w [(size_t)o * C + h * CH + c2], a, s1);
      s2 = fmaf(psh_w[(size_t)o * C + h * CH + c2], a, s2);
    }
    ws[WS_MS  + (size_t)b * C * C + idx] = s1;
    ws[WS_MSH + (size_t)b * C * C + idx] = s2;
    if (mb){
      mb[((size_t)0*NB + b)*9216 + idx] = f2b(s1);
      mb[((size_t)1*NB + b)*9216 + idx] = f2b(s2);
    }
  }
}

// ============================ kMv: out = M @ v  (no LDS, no barriers) ============================
__global__ __launch_bounds__(512, 4) void kMv(
  const unsigned short* __restrict__ vb, const unsigned short* __restrict__ mb,
  const float* __restrict__ bias, float* __restrict__ out)
{
  const int t = threadIdx.x, lane = t & 63, w = t >> 6;
  const int b = blockIdx.y;
  const int n0 = blockIdx.x * 256;
  const unsigned short* vbase = vb + (size_t)b*NPIX*96;
  const unsigned short* mbb = mb + (size_t)b*9216;
  float* ob = out + (size_t)b*C*NPIX;
  short8 bf[2][3];
  #pragma unroll
  for (int g = 0; g < 2; ++g){
    int px = n0 + (w*2 + g)*16 + (lane & 15);
    #pragma unroll
    for (int kk = 0; kk < 3; ++kk)
      bf[g][kk] = *(const short8*)(vbase + (size_t)px*96 + kk*32 + (lane>>4)*8);
  }
  #pragma unroll 1
  for (int mi = 0; mi < 6; ++mi){
    const unsigned short* mp = mbb + (size_t)(mi*16 + (lane & 15))*96 + (lane>>4)*8;
    short8 a0 = *(const short8*)(mp);
    short8 a1 = *(const short8*)(mp + 32);
    short8 a2 = *(const short8*)(mp + 64);
    float4 bv = *(const float4*)&bias[mi*16 + (lane>>4)*4];
    #pragma unroll
    for (int g = 0; g < 2; ++g){
      f32x4 acc = {bv.x, bv.y, bv.z, bv.w};
      acc = __builtin_amdgcn_mfma_f32_16x16x32_bf16(a0, bf[g][0], acc, 0,0,0);
      acc = __builtin_amdgcn_mfma_f32_16x16x32_bf16(a1, bf[g][1], acc, 0,0,0);
      acc = __builtin_amdgcn_mfma_f32_16x16x32_bf16(a2, bf[g][2], acc, 0,0,0);
      int px = n0 + (w*2 + g)*16 + (lane & 15);
      #pragma unroll
      for (int r = 0; r < 4; ++r)
        ob[(size_t)(mi*16 + (lane>>4)*4 + r)*NPIX + px] = acc[r];
    }
  }
}

// ============================ fallback (r4) kernels ============================
__device__ __forceinline__ void conv48c(
  const unsigned short* __restrict__ xbase, const float* __restrict__ wmat,
  const float* __restrict__ bias, int row0,
  int gx0, int gy0, int lane, int w, unsigned short* __restrict__ Ysh)
{
  const int hy = lane & 15, khalf = lane >> 4;
  const int gy = gy0 - 1 + hy;
  short8 xf[3][3]; bool imv[3]; int np = (w < 2) ? 3 : 2;
  #pragma unroll
  for (int i = 0; i < 3; ++i){
    if (i >= np) break;
    int pt = w + i*8;
    int gx = gx0 - 1 + pt;
    bool im = (gx>=0) && (gx<WW) && (gy>=0) && (gy<HH);
    imv[i] = im;
    int n = im ? (gy*WW + gx) : 0;
    const unsigned short* xp = xbase + (size_t)n*96 + khalf*8;
    short8 z = {};
    #pragma unroll
    for (int kk = 0; kk < 3; ++kk){
      short8 v = *(const short8*)(xp + kk*32);
      xf[i][kk] = im ? v : z;
    }
  }
  #pragma unroll 1
  for (int mi = 0; mi < 3; ++mi){
    int orow = row0 + mi*16 + hy;
    const float* wp = wmat + (size_t)orow*96 + khalf*8;
    short8 a0 = pack8(*(const float4*)(wp),    *(const float4*)(wp+4));
    short8 a1 = pack8(*(const float4*)(wp+32), *(const float4*)(wp+36));
    short8 a2 = pack8(*(const float4*)(wp+64), *(const float4*)(wp+68));
    float4 bv = *(const float4*)&bias[row0 + mi*16 + khalf*4];
    #pragma unroll
    for (int i = 0; i < 3; ++i){
      if (i >= np) break;
      int pt = w + i*8;
      f32x4 acc = {bv.x, bv.y, bv.z, bv.w};
      acc = __builtin_amdgcn_mfma_f32_16x16x32_bf16(a0, xf[i][0], acc, 0,0,0);
      acc = __builtin_amdgcn_mfma_f32_16x16x32_bf16(a1, xf[i][1], acc, 0,0,0);
      acc = __builtin_amdgcn_mfma_f32_16x16x32_bf16(a2, xf[i][2], acc, 0,0,0);
      #pragma unroll
      for (int r = 0; r < 4; ++r){
        int ch = mi*16 + khalf*4 + r;
        Ysh[ch*YP + pt*16 + hy] = imv[i] ? f2b(acc[r]) : (unsigned short)0;
      }
    }
  }
}

__global__ __launch_bounds__(512, 4) void kqk(
  const unsigned short* __restrict__ xt,
  const float* __restrict__ q_w, const float* __restrict__ q_b,
  const float* __restrict__ qd_w, const float* __restrict__ qd_b,
  const float* __restrict__ kv_w, const float* __restrict__ kv_b,
  const float* __restrict__ kvd_w, const float* __restrict__ kvd_b,
  float* __restrict__ pg, float* __restrict__ psq)
{
  __shared__ unsigned short Ysh[48*YP];
  __shared__ unsigned short qS[48*QP];
  __shared__ unsigned short kT[48*QP];
  __shared__ float redq[C], redk[C];

  const int t = threadIdx.x, lane = t & 63, w = t >> 6;
  const int b = blockIdx.y, tile = blockIdx.x;
  const int txx = tile & 15, tyy = tile >> 4;
  const int gx0 = txx*16, gy0 = tyy*14;
  if (t < C){ redq[t] = 0.f; redk[t] = 0.f; }
  __syncthreads();

  const unsigned short* xc = xt + ((size_t)(0*NB + b))*NPIX*96;
  const unsigned short* xs = xt + ((size_t)(1*NB + b))*NPIX*96;

  auto dwQK = [&](const float* dww, const float* dwb, int wrow0,
                  unsigned short* dst, float* red){
    for (int slot = t; slot < 48*16; slot += 512){
      int c = slot >> 4, j = slot & 15;
      const unsigned short* yb = &Ysh[c*YP + j*16];
      float u0[16], u1[16], u2[16];
      {
        short8 s0 = *(const short8*)(yb),    s1 = *(const short8*)(yb+8);
        short8 s2 = *(const short8*)(yb+16), s3 = *(const short8*)(yb+24);
        short8 s4 = *(const short8*)(yb+32), s5 = *(const short8*)(yb+40);
        #pragma unroll
        for (int u = 0; u < 8; ++u){
          u0[u]=b2f((unsigned short)s0[u]); u0[u+8]=b2f((unsigned short)s1[u]);
          u1[u]=b2f((unsigned short)s2[u]); u1[u+8]=b2f((unsigned short)s3[u]);
          u2[u]=b2f((unsigned short)s4[u]); u2[u+8]=b2f((unsigned short)s5[u]);
        }
      }
      const float* wd = dww + (size_t)(wrow0 + c)*9;
      float w00=wd[0],w01=wd[1],w02=wd[2],w10=wd[3],w11=wd[4],w12=wd[5],w20=wd[6],w21=wd[7],w22=wd[8];
      float bb = dwb[wrow0 + c];
      unsigned short vv[16];
      float sq = 0.f;
      #pragma unroll
      for (int py = 0; py < 14; ++py){
        float s = bb;
        s = fmaf(w00,u0[py],s); s = fmaf(w10,u0[py+1],s); s = fmaf(w20,u0[py+2],s);
        s = fmaf(w01,u1[py],s); s = fmaf(w11,u1[py+1],s); s = fmaf(w21,u1[py+2],s);
        s = fmaf(w02,u2[py],s); s = fmaf(w12,u2[py+1],s); s = fmaf(w22,u2[py+2],s);
        if (gy0 + py >= HH) s = 0.f;
        sq = fmaf(s, s, sq);
        vv[py] = f2b(s);
      }
      vv[14] = 0; vv[15] = 0;
      atomicAdd(&red[wrow0 + c], sq);
      *(short8*)&dst[c*QP + j*16]     = *(short8*)&vv[0];
      *(short8*)&dst[c*QP + j*16 + 8] = *(short8*)&vv[8];
    }
  };

  auto gram = [&](int cc){
    int hl = w & 1, slice = w >> 1;
    int cl = lane & 31; bool cv = cl < CH;
    int row = hl*CH + (cv ? cl : 0);
    f32x16 g;
    #pragma unroll
    for (int r = 0; r < 16; ++r) g[r] = 0.f;
    short8 z = {};
    for (int ks = slice; ks < 16; ks += 4){
      int ko = ks*16 + (lane>>5)*8;
      short8 qa = *(const short8*)&qS[row*QP + ko];
      short8 kb = *(const short8*)&kT[row*QP + ko];
      if (!cv){ qa = z; kb = z; }
      g = __builtin_amdgcn_mfma_f32_32x32x16_bf16(qa, kb, g, 0,0,0);
    }
    float* stg = (float*)Ysh;
    if (slice != 0){
      float* dst = stg + (size_t)(hl*3 + slice - 1)*1024;
      #pragma unroll
      for (int r = 0; r < 16; ++r) dst[r*64 + lane] = g[r];
    }
    __syncthreads();
    if (slice == 0){
      const float* s0 = stg + (size_t)(hl*3 + 0)*1024;
      const float* s1 = stg + (size_t)(hl*3 + 1)*1024;
      const float* s2 = stg + (size_t)(hl*3 + 2)*1024;
      float* dst = pg + ((size_t)(tile*NB + b)*HEADS + cc*2 + hl)*1024;
      #pragma unroll
      for (int r = 0; r < 16; ++r){
        int ix = r*64 + lane;
        dst[ix] = g[r] + s0[ix] + s1[ix] + s2[ix];
      }
    }
  };

  #pragma unroll 1
  for (int cc = 0; cc < 2; ++cc){
    conv48c(xc, q_w, q_b, cc*48, gx0, gy0, lane, w, Ysh);
    __syncthreads();
    dwQK(qd_w, qd_b, cc*48, qS, redq);
    __syncthreads();
    conv48c(xs, kv_w, kv_b, cc*48, gx0, gy0, lane, w, Ysh);
    __syncthreads();
    dwQK(kvd_w, kvd_b, cc*48, kT, redk);
    __syncthreads();
    gram(cc);
    __syncthreads();
  }
  if (t < 192){
    float v = (t < 96) ? redq[t] : redk[t - 96];
    psq[(size_t)(tile*NB + b)*192 + t] = v;
  }
}

__global__ __launch_bounds__(256) void kgredF(
  const float* __restrict__ pg, const float* __restrict__ psq, float* __restrict__ ws)
{
  const int bh = blockIdx.x;
  const int b = bh >> 2, h = bh & 3;
  const int t = threadIdx.x;
  float a0=0.f, a1=0.f, a2=0.f, a3=0.f, sq=0.f;
  for (int tile = 0; tile < NTILES; ++tile){
    const float* p = pg + ((size_t)(tile*NB + b)*HEADS + h)*1024;
    a0 += p[t]; a1 += p[t+256]; a2 += p[t+512]; a3 += p[t+768];
    if (t < 48){
      int ch = h*CH + (t % CH);
      sq += psq[(size_t)(tile*NB + b)*192 + (t < CH ? ch : 96 + ch)];
    }
  }
  if (t < 48){
    if (t < CH) ws[WS_SUMSQ_Q + b*C + h*CH + t] = sq;
    else        ws[WS_SUMSQ_K + b*C + h*CH + (t - CH)] = sq;
  }
  float accs[4] = {a0, a1, a2, a3};
  #pragma unroll
  for (int i = 0; i < 4; ++i){
    int idx = i*256 + t;
    int r = idx >> 6, ln = idx & 63;
    int row = (r&3) + 8*(r>>2) + 4*(ln>>5);
    int col = ln & 31;
    if (row < CH && col < CH)
      ws[WS_GRAM + ((size_t)(b*HEADS + h)*CH + row)*CH + col] = accs[i];
  }
}

__global__ __launch_bounds__(512, 4) void kv_out(
  const unsigned short* __restrict__ xs,
  const float* __restrict__ kv_w, const float* __restrict__ kv_b,
  const float* __restrict__ kvd_w, const float* __restrict__ kvd_b,
  const float* __restrict__ ps_b, const float* __restrict__ psh_b,
  const unsigned short* __restrict__ mb, float* __restrict__ out)
{
  __shared__ unsigned short Ysh[48*YP];
  __shared__ unsigned short vS[224*VP];
  const int t = threadIdx.x, lane = t & 63, w = t >> 6;
  const int b = blockIdx.y, tile = blockIdx.x;
  const int txx = tile & 15, tyy = tile >> 4;
  const int gx0 = txx*16, gy0 = tyy*14;
  const unsigned short* xb_ = xs + (size_t)b*NPIX*96;

  #pragma unroll 1
  for (int which = 0; which < 2; ++which){
    #pragma unroll 1
    for (int cv = 0; cv < 2; ++cv){
      int row0 = 96 + which*96 + cv*48;
      conv48c(xb_, kv_w, kv_b, row0, gx0, gy0, lane, w, Ysh);
      __syncthreads();
      for (int slot = t; slot < 48*16; slot += 512){
        int c = slot >> 4, j = slot & 15;
        const unsigned short* yb = &Ysh[c*YP + j*16];
        float u0[16], u1[16], u2[16];
        {
          short8 s0 = *(const short8*)(yb),    s1 = *(const short8*)(yb+8);
          short8 s2 = *(const short8*)(yb+16), s3 = *(const short8*)(yb+24);
          short8 s4 = *(const short8*)(yb+32), s5 = *(const short8*)(yb+40);
          #pragma unroll
          for (int u = 0; u < 8; ++u){
            u0[u]=b2f((unsigned short)s0[u]); u0[u+8]=b2f((unsigned short)s1[u]);
            u1[u]=b2f((unsigned short)s2[u]); u1[u+8]=b2f((unsigned short)s3[u]);
            u2[u]=b2f((unsigned short)s4[u]); u2[u+8]=b2f((unsigned short)s5[u]);
          }
        }
        const float* wd = kvd_w + (size_t)(row0 + c)*9;
        float w00=wd[0],w01=wd[1],w02=wd[2],w10=wd[3],w11=wd[4],w12=wd[5],w20=wd[6],w21=wd[7],w22=wd[8];
        float bb = kvd_b[row0 + c];
        #pragma unroll
        for (int py = 0; py < 14; ++py){
          float s = bb;
          s = fmaf(w00,u0[py],s); s = fmaf(w10,u0[py+1],s); s = fmaf(w20,u0[py+2],s);
          s = fmaf(w01,u1[py],s); s = fmaf(w11,u1[py+1],s); s = fmaf(w21,u1[py+2],s);
          s = fmaf(w02,u2[py],s); s = fmaf(w12,u2[py+1],s); s = fmaf(w22,u2[py+2],s);
          vS[(py*16 + j)*VP + cv*48 + c] = f2b(s);
        }
      }
      __syncthreads();
    }
    const unsigned short* mbp = mb + ((size_t)which*NB + b)*9216;
    const float* bias = which ? psh_b : ps_b;
    float* ob = out + (size_t)which*NB*C*NPIX + (size_t)b*C*NPIX;
    for (int tl = w; tl < 84; tl += 8){
      int mi = tl / 14, n = tl - mi*14;
      const unsigned short* mp = mbp + (size_t)(mi*16 + (lane&15))*96 + (lane>>4)*8;
      short8 a0 = *(const short8*)(mp);
      short8 a1 = *(const short8*)(mp + 32);
      short8 a2 = *(const short8*)(mp + 64);
      float4 bv = *(const float4*)&bias[mi*16 + (lane>>4)*4];
      f32x4 acc = {bv.x, bv.y, bv.z, bv.w};
      const unsigned short* xb = &vS[(size_t)(n*16 + (lane&15))*VP + (lane>>4)*8];
      acc = __builtin_amdgcn_mfma_f32_16x16x32_bf16(a0, *(const short8*)(xb),    acc, 0,0,0);
      acc = __builtin_amdgcn_mfma_f32_16x16x32_bf16(a1, *(const short8*)(xb+32), acc, 0,0,0);
      acc = __builtin_amdgcn_mfma_f32_16x16x32_bf16(a2, *(const short8*)(xb+64), acc, 0,0,0);
      int gy = gy0 + n;
      if (gy < HH){
        #pragma unroll
        for (int r = 0; r < 4; ++r)
          ob[(size_t)(mi*16 + (lane>>4)*4 + r)*NPIX + gy*WW + gx0 + (lane&15)] = acc[r];
      }
    }
    __syncthreads();
  }
}

extern "C" void kernel_launch(void* const* d_in, const int* in_sizes, int n_in,
                              void* d_out, int out_size, void* d_ws, size_t ws_size,
                              hipStream_t stream)
{
  const float* content = (const float*)d_in[0];
  const float* style   = (const float*)d_in[1];
  const float* temp    = (const float*)d_in[2];
  const float* q_w   = (const float*)d_in[3];
  const float* q_b   = (const float*)d_in[4];
  const float* qd_w  = (const float*)d_in[5];
  const float* qd_b  = (const float*)d_in[6];
  const float* kv_w  = (const float*)d_in[7];
  const float* kv_b  = (const float*)d_in[8];
  const float* kvd_w = (const float*)d_in[9];
  const float* kvd_b = (const float*)d_in[10];
  const float* ps_w  = (const float*)d_in[11];
  const float* ps_b  = (const float*)d_in[12];
  const float* psh_w = (const float*)d_in[13];
  const float* psh_b = (const float*)d_in[14];
  float* out = (float*)d_out;
  float* ws  = (float*)d_ws;

  unsigned short* xt = (unsigned short*)((char*)d_ws + XT_OFF_BYTES);

  if (ws_size >= WS_NEED2){
    unsigned short* qk  = (unsigned short*)((char*)d_ws + QK_OFF);
    unsigned short* vbh = (unsigned short*)((char*)d_ws + VB_OFF);
    unsigned short* vbs = (unsigned short*)(out + (size_t)NB*C*NPIX); // alias: shift half of d_out
    float* pg  = (float*)((char*)d_ws + PG_OFF);
    float* psq = (float*)((char*)d_ws + PSQ_OFF);
    unsigned short* mb = (unsigned short*)((char*)d_ws + MB_OFF);
    unsigned short* wb = (unsigned short*)((char*)d_ws + WB_OFF);

    k0t<<<dim3(NPIX/64, NB, 2), dim3(256), 0, stream>>>(content, style, xt);
    kwpack<<<dim3(144), dim3(256), 0, stream>>>(q_w, kv_w, wb);
    kconv<<<dim3(NTILES, NB, 3), dim3(512), 0, stream>>>(
        xt, wb, q_b, qd_w, qd_b, kv_b, kvd_w, kvd_b, qk, vbs, vbh, psq);
    kgram<<<dim3(KSPLIT, NB), dim3(384), 0, stream>>>(qk, pg);
    kgredN<<<dim3(NB, 37), dim3(256), 0, stream>>>(pg, psq, ws);
    k2_attn<<<dim3(NB), dim3(256), 0, stream>>>(temp, ps_w, psh_w, ws, mb);
    // which=0 (scale): reads vbs (shift half), writes scale half — must precede which=1
    kMv<<<dim3(NPIX/256, NB), dim3(512), 0, stream>>>(vbs, mb, ps_b, out);
    // which=1 (shift): reads vbh (ws), writes shift half
    kMv<<<dim3(NPIX/256, NB), dim3(512), 0, stream>>>(
        vbh, mb + (size_t)NB*9216, psh_b, out + (size_t)NB*C*NPIX);
  } else {
    float* pg  = (float*)((char*)d_ws + F_PG_OFF);
    float* psq = (float*)((char*)d_ws + F_PSQ_OFF);
    unsigned short* mb = (unsigned short*)((char*)d_ws + F_MB_OFF);
    k0t<<<dim3(NPIX/64, NB, 2), dim3(256), 0, stream>>>(content, style, xt);
    kqk<<<dim3(NTILES, NB), dim3(512), 0, stream>>>(
        xt, q_w, q_b, qd_w, qd_b, kv_w, kv_b, kvd_w, kvd_b, pg, psq);
    kgredF<<<dim3(NB*HEADS), dim3(256), 0, stream>>>(pg, psq, ws);
    k2_attn<<<dim3(NB), dim3(256), 0, stream>>>(temp, ps_w, psh_w, ws, mb);
    kv_out<<<dim3(NTILES, NB), dim3(512), 0, stream>>>(
        xt + (size_t)NB*NPIX*96, kv_w, kv_b, kvd_w, kvd_b, ps_b, psh_b, mb, out);
  }
}

// Round 6
// 485.768 us; speedup vs baseline: 4.9808x; 1.0311x over previous
//
#include <hip/hip_runtime.h>

#define NB 4
#define C 96
#define HH 256
#define WW 256
#define NPIX (HH*WW)
#define HEADS 4
#define CH 24

// ---- tiling: interior 16 wide x 14 tall, halo 18x16 ----
#define NTX2 16
#define NTY2 19
#define NTILES (NTX2*NTY2)
#define YP 296      // fallback Ysh pitch
#define QP 264      // fallback qS/kT pitch
#define VP 104      // vS pitch ([px][ch]) for kMv + fallback
#define KSPLIT 128
#define YR 24       // kconv Ysh row pitch (shorts)
#define YC 392      // kconv Ysh channel stride (shorts) — 784B = 196 dw (mod 32 = 4)

#define WS_SUMSQ_Q 0
#define WS_SUMSQ_K (WS_SUMSQ_Q + NB*C)
#define WS_GRAM    (WS_SUMSQ_K + NB*C)
#define WS_MS      (WS_GRAM + NB*HEADS*CH*CH)
#define WS_MSH     (WS_MS + NB*C*C)

// shared xt region
#define XT_OFF_BYTES ((size_t)335872)
#define XT_BYTES   ((size_t)2*NB*NPIX*96*2)

// ---- fallback (r4) layout ----
#define F_PSQ_OFF   (XT_OFF_BYTES + XT_BYTES)
#define F_PSQ_BYTES ((size_t)NTILES*NB*192*4)
#define F_PG_OFF    (F_PSQ_OFF + F_PSQ_BYTES)
#define F_PG_BYTES  ((size_t)NTILES*NB*HEADS*1024*4)
#define F_MB_OFF    (F_PG_OFF + F_PG_BYTES)
#define F_MB_BYTES  ((size_t)2*NB*96*96*2)
#define F_WS_NEED   (F_MB_OFF + F_MB_BYTES)

// ---- new layout (identical footprint to r5) ----
#define QK_OFF    (XT_OFF_BYTES + XT_BYTES)
#define QK_BYTES  ((size_t)2*NB*96*NPIX*2)
#define VB_OFF    (QK_OFF + QK_BYTES)              // v_shift ([b][96][n] bf16)
#define VB_BYTES  ((size_t)NB*NPIX*96*2)
#define PG_OFF    (VB_OFF + VB_BYTES)
#define PG_BYTES  ((size_t)KSPLIT*NB*9216*4)
#define PSQ_OFF   (PG_OFF + PG_BYTES)
#define PSQ_BYTES ((size_t)2*NTILES*NB*96*4)
#define MB_OFF    (PSQ_OFF + PSQ_BYTES)
#define MB_BYTES  ((size_t)2*NB*96*96*2)
#define WB_OFF    (MB_OFF + MB_BYTES)
#define WB_BYTES  ((size_t)384*96*2)
#define WS_NEED2  (WB_OFF + WB_BYTES)

typedef short short8 __attribute__((ext_vector_type(8)));
typedef float f32x4 __attribute__((ext_vector_type(4)));
typedef float f32x16 __attribute__((ext_vector_type(16)));

__device__ __forceinline__ unsigned short f2b(float f){
  unsigned u = __float_as_uint(f);
  unsigned r = u + 0x7FFFu + ((u >> 16) & 1u);
  return (unsigned short)(r >> 16);
}
__device__ __forceinline__ float b2f(unsigned short s){
  return __uint_as_float(((unsigned)s) << 16);
}
__device__ __forceinline__ short8 pack8(float4 a, float4 b){
  short8 r;
  r[0]=(short)f2b(a.x); r[1]=(short)f2b(a.y); r[2]=(short)f2b(a.z); r[3]=(short)f2b(a.w);
  r[4]=(short)f2b(b.x); r[5]=(short)f2b(b.y); r[6]=(short)f2b(b.z); r[7]=(short)f2b(b.w);
  return r;
}

// ============================ K0: fp32 [c][n] -> bf16 [n][c] ============================
__global__ __launch_bounds__(256) void k0t(
  const float* __restrict__ content, const float* __restrict__ style,
  unsigned short* __restrict__ xt)
{
  __shared__ unsigned short Xt[96*68];
  const int t = threadIdx.x;
  const int n0 = blockIdx.x * 64;
  const int b = blockIdx.y, src = blockIdx.z;
  const float* in = (src ? style : content) + (size_t)b*C*NPIX;
  #pragma unroll
  for (int i = 0; i < 6; ++i){
    int s = i*256 + t;
    int r = s >> 4, c4 = s & 15;
    float4 f = *(const float4*)(in + (size_t)r*NPIX + n0 + c4*4);
    unsigned lo = ((unsigned)f2b(f.y) << 16) | f2b(f.x);
    unsigned hi = ((unsigned)f2b(f.w) << 16) | f2b(f.z);
    *(uint2*)&Xt[r*68 + c4*4] = make_uint2(lo, hi);
  }
  __syncthreads();
  unsigned* dst = (unsigned*)(xt + (((size_t)src*NB + b)*NPIX + n0)*96);
  #pragma unroll
  for (int i = 0; i < 12; ++i){
    int s = i*256 + t;
    int j = s / 48, c2 = s - j*48;
    unsigned v = ((unsigned)Xt[(c2*2+1)*68 + j] << 16) | Xt[(c2*2)*68 + j];
    dst[(size_t)j*48 + c2] = v;
  }
}

// ============================ kwpack ============================
__global__ __launch_bounds__(256) void kwpack(
  const float* __restrict__ q_w, const float* __restrict__ kv_w,
  unsigned short* __restrict__ wb)
{
  int i = blockIdx.x*256 + threadIdx.x;
  if (i < 9216) wb[i] = f2b(q_w[i]);
  else if (i < 36864) wb[i] = f2b(kv_w[i - 9216]);
}

// ============================ kconv: z=0 q, z=1 k, z=2 v_scale, z=3 v_shift ============================
__global__ __launch_bounds__(512, 4) void kconv(
  const unsigned short* __restrict__ xt, const unsigned short* __restrict__ wb,
  const float* __restrict__ q_b, const float* __restrict__ qd_w, const float* __restrict__ qd_b,
  const float* __restrict__ kv_b, const float* __restrict__ kvd_w, const float* __restrict__ kvd_b,
  unsigned short* __restrict__ qk, unsigned short* __restrict__ vbs,
  unsigned short* __restrict__ vbh, float* __restrict__ psq)
{
  __shared__ unsigned short Ysh[48*YC];   // 37632 B
  __shared__ float red[96];
  const int t = threadIdx.x, lane = t & 63, w = t >> 6;
  const int tile = blockIdx.x, b = blockIdx.y, z = blockIdx.z;
  const int txx = tile & 15, tyy = tile >> 4;
  const int gx0 = txx*16, gy0 = tyy*14;
  const unsigned short* xsrc = xt + ((size_t)((z ? 1 : 0)*NB + b))*NPIX*96;
  const float* cb  = (z==0) ? q_b  : kv_b  + (z-1)*96;
  const float* dww = (z==0) ? qd_w : kvd_w + (size_t)(z-1)*96*9;
  const float* dwb = (z==0) ? qd_b : kvd_b + (z-1)*96;
  unsigned short* dst0 = (z < 2) ? qk + ((size_t)(z*NB + b))*96*NPIX
                                 : ((z==2) ? vbs : vbh) + (size_t)b*96*NPIX;

  if (t < 96) red[t] = 0.f;

  // persistent halo fragments
  const int hy = lane & 15, khalf = lane >> 4;
  const int gyh = gy0 - 1 + hy;
  short8 xf[3][3]; bool imv[3];
  const int np = (w < 2) ? 3 : 2;
  #pragma unroll
  for (int i = 0; i < 3; ++i){
    if (i >= np) break;
    int pt = w + i*8;
    int gx = gx0 - 1 + pt;
    bool im = (gx>=0) && (gx<WW) && (gyh>=0) && (gyh<HH);
    imv[i] = im;
    const unsigned short* xp = xsrc + (size_t)(im ? (gyh*WW + gx) : 0)*96 + khalf*8;
    short8 zz = {};
    #pragma unroll
    for (int kk = 0; kk < 3; ++kk){
      short8 v = *(const short8*)(xp + kk*32);
      xf[i][kk] = im ? v : zz;
    }
  }

  #pragma unroll 1
  for (int chunk = 0; chunk < 2; ++chunk){
    // conv1x1: 48 output rows over halo -> Ysh [ch][hy][pt]
    #pragma unroll 1
    for (int mi = 0; mi < 3; ++mi){
      const unsigned short* wp = wb + (size_t)(z*96 + chunk*48 + mi*16 + hy)*96 + khalf*8;
      short8 a0 = *(const short8*)(wp);
      short8 a1 = *(const short8*)(wp + 32);
      short8 a2 = *(const short8*)(wp + 64);
      float4 bv = *(const float4*)&cb[chunk*48 + mi*16 + khalf*4];
      #pragma unroll
      for (int i = 0; i < 3; ++i){
        if (i >= np) break;
        int pt = w + i*8;
        f32x4 acc = {bv.x, bv.y, bv.z, bv.w};
        acc = __builtin_amdgcn_mfma_f32_16x16x32_bf16(a0, xf[i][0], acc, 0,0,0);
        acc = __builtin_amdgcn_mfma_f32_16x16x32_bf16(a1, xf[i][1], acc, 0,0,0);
        acc = __builtin_amdgcn_mfma_f32_16x16x32_bf16(a2, xf[i][2], acc, 0,0,0);
        #pragma unroll
        for (int r = 0; r < 4; ++r){
          int ch = mi*16 + khalf*4 + r;
          Ysh[ch*YC + hy*YR + pt] = imv[i] ? f2b(acc[r]) : (unsigned short)0;
        }
      }
    }
    __syncthreads();
    // dw 3x3 row-oriented: slot -> (c, py), 16 x-outputs, coalesced short8 stores
    for (int slot = t; slot < 672; slot += 512){
      int c = slot / 14, py = slot - (slot/14)*14;
      int gy = gy0 + py;
      if (gy < HH){
        const float* wd = dww + (size_t)(chunk*48 + c)*9;
        float w00=wd[0],w01=wd[1],w02=wd[2],w10=wd[3],w11=wd[4],w12=wd[5],w20=wd[6],w21=wd[7],w22=wd[8];
        float bb = dwb[chunk*48 + c];
        const unsigned short* yb = &Ysh[c*YC + py*YR];
        float o[16];
        #pragma unroll
        for (int half = 0; half < 2; ++half){
          float u[3][10];
          #pragma unroll
          for (int uu = 0; uu < 3; ++uu){
            const unsigned short* rp = yb + uu*YR + half*8;
            short8 s = *(const short8*)rp;
            unsigned ex = *(const unsigned*)(rp + 8);
            #pragma unroll
            for (int j = 0; j < 8; ++j) u[uu][j] = b2f((unsigned short)s[j]);
            u[uu][8] = b2f((unsigned short)(ex & 0xffffu));
            u[uu][9] = b2f((unsigned short)(ex >> 16));
          }
          #pragma unroll
          for (int j = 0; j < 8; ++j){
            float s = bb;
            s = fmaf(w00,u[0][j],s); s = fmaf(w01,u[0][j+1],s); s = fmaf(w02,u[0][j+2],s);
            s = fmaf(w10,u[1][j],s); s = fmaf(w11,u[1][j+1],s); s = fmaf(w12,u[1][j+2],s);
            s = fmaf(w20,u[2][j],s); s = fmaf(w21,u[2][j+1],s); s = fmaf(w22,u[2][j+2],s);
            o[half*8 + j] = s;
          }
        }
        unsigned short vv[16];
        if (z < 2){
          float sq = 0.f;
          #pragma unroll
          for (int j = 0; j < 16; ++j){ sq = fmaf(o[j], o[j], sq); vv[j] = f2b(o[j]); }
          atomicAdd(&red[chunk*48 + c], sq);
        } else {
          #pragma unroll
          for (int j = 0; j < 16; ++j) vv[j] = f2b(o[j]);
        }
        unsigned short* qp = dst0 + (size_t)(chunk*48 + c)*NPIX + (size_t)gy*WW + gx0;
        *(short8*)qp       = *(const short8*)&vv[0];
        *(short8*)(qp + 8) = *(const short8*)&vv[8];
      }
    }
    __syncthreads();
  }
  if (z < 2 && t < 96)
    psq[((size_t)(z*NTILES + tile)*NB + b)*96 + t] = red[t];
}

// ============================ kgram: partial-K Gram ============================
__global__ __launch_bounds__(384) void kgram(
  const unsigned short* __restrict__ qk, float* __restrict__ pg)
{
  const int t = threadIdx.x, lane = t & 63, wv = t >> 6;
  const int ks = blockIdx.x, b = blockIdx.y;
  const int n0 = ks * (NPIX / KSPLIT);
  const unsigned short* qb = qk + ((size_t)(0*NB + b)*96)*NPIX;
  const unsigned short* kb = qk + ((size_t)(1*NB + b)*96)*NPIX;
  f32x4 acc[6];
  #pragma unroll
  for (int i = 0; i < 6; ++i) acc[i] = (f32x4){0.f,0.f,0.f,0.f};
  #pragma unroll 1
  for (int st = 0; st < (NPIX/KSPLIT)/32; ++st){
    int off = n0 + st*32 + (lane>>4)*8;
    short8 bf = *(const short8*)(kb + (size_t)(wv*16 + (lane&15))*NPIX + off);
    #pragma unroll
    for (int ci = 0; ci < 6; ++ci){
      short8 af = *(const short8*)(qb + (size_t)(ci*16 + (lane&15))*NPIX + off);
      acc[ci] = __builtin_amdgcn_mfma_f32_16x16x32_bf16(af, bf, acc[ci], 0,0,0);
    }
  }
  float* dst = pg + ((size_t)ks*NB + b)*9216;
  #pragma unroll
  for (int ci = 0; ci < 6; ++ci){
    #pragma unroll
    for (int r = 0; r < 4; ++r)
      dst[(ci*6 + wv)*256 + ((lane>>4)*4 + r)*16 + (lane&15)] = acc[ci][r];
  }
}

// ============================ kgredN ============================
__global__ __launch_bounds__(256) void kgredN(
  const float* __restrict__ pg, const float* __restrict__ psq, float* __restrict__ ws)
{
  const int b = blockIdx.x, by = blockIdx.y, t = threadIdx.x;
  if (by < 36){
    int ci = by / 6;
    int qrow = ci*16 + (t >> 4), krow = (by - ci*6)*16 + (t & 15);
    float s = 0.f;
    for (int ks = 0; ks < KSPLIT; ++ks)
      s += pg[((size_t)ks*NB + b)*9216 + by*256 + t];
    int h = qrow / CH;
    if (krow / CH == h)
      ws[WS_GRAM + ((size_t)(b*HEADS + h)*CH + (qrow % CH))*CH + (krow % CH)] = s;
  } else {
    if (t < 192){
      int src = t / 96, c = t - (t/96)*96;
      float s = 0.f;
      for (int tile = 0; tile < NTILES; ++tile)
        s += psq[((size_t)(src*NTILES + tile)*NB + b)*96 + c];
      ws[(src ? WS_SUMSQ_K : WS_SUMSQ_Q) + b*C + c] = s;
    }
  }
}

// ============================ k2: softmax + M matrices ============================
__global__ void k2_attn(
  const float* __restrict__ temp,
  const float* __restrict__ ps_w, const float* __restrict__ psh_w,
  float* __restrict__ ws, unsigned short* __restrict__ mb)
{
  const int b = blockIdx.x;
  const int t = threadIdx.x;
  __shared__ float attn[C * CH];
  __shared__ float nq[C], nk[C];
  if (t < C){
    nq[t] = fmaxf(sqrtf(ws[WS_SUMSQ_Q + b * C + t]), 1e-12f);
    nk[t] = fmaxf(sqrtf(ws[WS_SUMSQ_K + b * C + t]), 1e-12f);
  }
  __syncthreads();
  if (t < C){
    int h = t / CH;
    const float* g = ws + WS_GRAM + (((size_t)b * HEADS + h) * CH + (t % CH)) * CH;
    float tp = temp[h];
    float row[CH];
    float mx = -3.4e38f;
    #pragma unroll
    for (int d = 0; d < CH; ++d){
      row[d] = g[d] / (nq[t] * nk[h * CH + d]) * tp;
      mx = fmaxf(mx, row[d]);
    }
    float s = 0.f;
    #pragma unroll
    for (int d = 0; d < CH; ++d){ row[d] = expf(row[d] - mx); s += row[d]; }
    float inv = 1.f / s;
    #pragma unroll
    for (int d = 0; d < CH; ++d) attn[t * CH + d] = row[d] * inv;
  }
  __syncthreads();
  for (int idx = t; idx < C * C; idx += 256){
    int o = idx / C, dg = idx - o * C;
    int h = dg / CH, d = dg - h * CH;
    float s1 = 0.f, s2 = 0.f;
    #pragma unroll
    for (int c2 = 0; c2 < CH; ++c2){
      float a = attn[(h * CH + c2) * CH + d];
      s1 = fmaf(ps_w [(size_t)o * C + h * CH + c2], a, s1);
      s2 = fmaf(psh_w[(size_t)o * C + h * CH + c2], a, s2);
    }
    ws[WS_MS  + (size_t)b * C * C + idx] = s1;
    ws[WS_MSH + (size_t)b * C * C + idx] = s2;
    if (mb){
      mb[((size_t)0*NB + b)*9216 + idx] = f2b(s1);
      mb[((size_t)1*NB + b)*9216 + idx] = f2b(s2);
    }
  }
}

// ============================ kMv: out = M @ v, v bf16 [c][n], LDS transpose ============================
__global__ __launch_bounds__(512) void kMv(
  const unsigned short* __restrict__ vb, const unsigned short* __restrict__ mb,
  const float* __restrict__ bias, float* __restrict__ out)
{
  __shared__ unsigned short vS[256*VP];
  const int t = threadIdx.x, lane = t & 63, w = t >> 6;
  const int b = blockIdx.y;
  const int n0 = blockIdx.x * 256;
  const unsigned short* vbase = vb + (size_t)b*96*NPIX;
  #pragma unroll
  for (int i = 0; i < 6; ++i){
    int s = i*512 + t;
    int c = s >> 5, seg = s & 31;
    short8 v8 = *(const short8*)(vbase + (size_t)c*NPIX + n0 + seg*8);
    #pragma unroll
    for (int j = 0; j < 8; ++j)
      vS[(seg*8 + j)*VP + c] = (unsigned short)v8[j];
  }
  __syncthreads();
  const unsigned short* mbb = mb + (size_t)b*9216;
  float* ob = out + (size_t)b*C*NPIX;
  #pragma unroll 1
  for (int mi = 0; mi < 6; ++mi){
    const unsigned short* mp = mbb + (size_t)(mi*16 + (lane & 15))*96 + (lane>>4)*8;
    short8 a0 = *(const short8*)(mp);
    short8 a1 = *(const short8*)(mp + 32);
    short8 a2 = *(const short8*)(mp + 64);
    float4 bv = *(const float4*)&bias[mi*16 + (lane>>4)*4];
    #pragma unroll
    for (int g = 0; g < 2; ++g){
      int px = (w*2 + g)*16 + (lane & 15);
      const unsigned short* xb = &vS[px*VP + (lane>>4)*8];
      f32x4 acc = {bv.x, bv.y, bv.z, bv.w};
      acc = __builtin_amdgcn_mfma_f32_16x16x32_bf16(a0, *(const short8*)(xb),    acc, 0,0,0);
      acc = __builtin_amdgcn_mfma_f32_16x16x32_bf16(a1, *(const short8*)(xb+32), acc, 0,0,0);
      acc = __builtin_amdgcn_mfma_f32_16x16x32_bf16(a2, *(const short8*)(xb+64), acc, 0,0,0);
      #pragma unroll
      for (int r = 0; r < 4; ++r)
        ob[(size_t)(mi*16 + (lane>>4)*4 + r)*NPIX + n0 + px] = acc[r];
    }
  }
}

// ============================ fallback (r4) kernels ============================
__device__ __forceinline__ void conv48c(
  const unsigned short* __restrict__ xbase, const float* __restrict__ wmat,
  const float* __restrict__ bias, int row0,
  int gx0, int gy0, int lane, int w, unsigned short* __restrict__ Ysh)
{
  const int hy = lane & 15, khalf = lane >> 4;
  const int gy = gy0 - 1 + hy;
  short8 xf[3][3]; bool imv[3]; int np = (w < 2) ? 3 : 2;
  #pragma unroll
  for (int i = 0; i < 3; ++i){
    if (i >= np) break;
    int pt = w + i*8;
    int gx = gx0 - 1 + pt;
    bool im = (gx>=0) && (gx<WW) && (gy>=0) && (gy<HH);
    imv[i] = im;
    int n = im ? (gy*WW + gx) : 0;
    const unsigned short* xp = xbase + (size_t)n*96 + khalf*8;
    short8 z = {};
    #pragma unroll
    for (int kk = 0; kk < 3; ++kk){
      short8 v = *(const short8*)(xp + kk*32);
      xf[i][kk] = im ? v : z;
    }
  }
  #pragma unroll 1
  for (int mi = 0; mi < 3; ++mi){
    int orow = row0 + mi*16 + hy;
    const float* wp = wmat + (size_t)orow*96 + khalf*8;
    short8 a0 = pack8(*(const float4*)(wp),    *(const float4*)(wp+4));
    short8 a1 = pack8(*(const float4*)(wp+32), *(const float4*)(wp+36));
    short8 a2 = pack8(*(const float4*)(wp+64), *(const float4*)(wp+68));
    float4 bv = *(const float4*)&bias[row0 + mi*16 + khalf*4];
    #pragma unroll
    for (int i = 0; i < 3; ++i){
      if (i >= np) break;
      int pt = w + i*8;
      f32x4 acc = {bv.x, bv.y, bv.z, bv.w};
      acc = __builtin_amdgcn_mfma_f32_16x16x32_bf16(a0, xf[i][0], acc, 0,0,0);
      acc = __builtin_amdgcn_mfma_f32_16x16x32_bf16(a1, xf[i][1], acc, 0,0,0);
      acc = __builtin_amdgcn_mfma_f32_16x16x32_bf16(a2, xf[i][2], acc, 0,0,0);
      #pragma unroll
      for (int r = 0; r < 4; ++r){
        int ch = mi*16 + khalf*4 + r;
        Ysh[ch*YP + pt*16 + hy] = imv[i] ? f2b(acc[r]) : (unsigned short)0;
      }
    }
  }
}

__global__ __launch_bounds__(512, 4) void kqk(
  const unsigned short* __restrict__ xt,
  const float* __restrict__ q_w, const float* __restrict__ q_b,
  const float* __restrict__ qd_w, const float* __restrict__ qd_b,
  const float* __restrict__ kv_w, const float* __restrict__ kv_b,
  const float* __restrict__ kvd_w, const float* __restrict__ kvd_b,
  float* __restrict__ pg, float* __restrict__ psq)
{
  __shared__ unsigned short Ysh[48*YP];
  __shared__ unsigned short qS[48*QP];
  __shared__ unsigned short kT[48*QP];
  __shared__ float redq[C], redk[C];

  const int t = threadIdx.x, lane = t & 63, w = t >> 6;
  const int b = blockIdx.y, tile = blockIdx.x;
  const int txx = tile & 15, tyy = tile >> 4;
  const int gx0 = txx*16, gy0 = tyy*14;
  if (t < C){ redq[t] = 0.f; redk[t] = 0.f; }
  __syncthreads();

  const unsigned short* xc = xt + ((size_t)(0*NB + b))*NPIX*96;
  const unsigned short* xs = xt + ((size_t)(1*NB + b))*NPIX*96;

  auto dwQK = [&](const float* dww, const float* dwb, int wrow0,
                  unsigned short* dst, float* red){
    for (int slot = t; slot < 48*16; slot += 512){
      int c = slot >> 4, j = slot & 15;
      const unsigned short* yb = &Ysh[c*YP + j*16];
      float u0[16], u1[16], u2[16];
      {
        short8 s0 = *(const short8*)(yb),    s1 = *(const short8*)(yb+8);
        short8 s2 = *(const short8*)(yb+16), s3 = *(const short8*)(yb+24);
        short8 s4 = *(const short8*)(yb+32), s5 = *(const short8*)(yb+40);
        #pragma unroll
        for (int u = 0; u < 8; ++u){
          u0[u]=b2f((unsigned short)s0[u]); u0[u+8]=b2f((unsigned short)s1[u]);
          u1[u]=b2f((unsigned short)s2[u]); u1[u+8]=b2f((unsigned short)s3[u]);
          u2[u]=b2f((unsigned short)s4[u]); u2[u+8]=b2f((unsigned short)s5[u]);
        }
      }
      const float* wd = dww + (size_t)(wrow0 + c)*9;
      float w00=wd[0],w01=wd[1],w02=wd[2],w10=wd[3],w11=wd[4],w12=wd[5],w20=wd[6],w21=wd[7],w22=wd[8];
      float bb = dwb[wrow0 + c];
      unsigned short vv[16];
      float sq = 0.f;
      #pragma unroll
      for (int py = 0; py < 14; ++py){
        float s = bb;
        s = fmaf(w00,u0[py],s); s = fmaf(w10,u0[py+1],s); s = fmaf(w20,u0[py+2],s);
        s = fmaf(w01,u1[py],s); s = fmaf(w11,u1[py+1],s); s = fmaf(w21,u1[py+2],s);
        s = fmaf(w02,u2[py],s); s = fmaf(w12,u2[py+1],s); s = fmaf(w22,u2[py+2],s);
        if (gy0 + py >= HH) s = 0.f;
        sq = fmaf(s, s, sq);
        vv[py] = f2b(s);
      }
      vv[14] = 0; vv[15] = 0;
      atomicAdd(&red[wrow0 + c], sq);
      *(short8*)&dst[c*QP + j*16]     = *(short8*)&vv[0];
      *(short8*)&dst[c*QP + j*16 + 8] = *(short8*)&vv[8];
    }
  };

  auto gram = [&](int cc){
    int hl = w & 1, slice = w >> 1;
    int cl = lane & 31; bool cv = cl < CH;
    int row = hl*CH + (cv ? cl : 0);
    f32x16 g;
    #pragma unroll
    for (int r = 0; r < 16; ++r) g[r] = 0.f;
    short8 z = {};
    for (int ks = slice; ks < 16; ks += 4){
      int ko = ks*16 + (lane>>5)*8;
      short8 qa = *(const short8*)&qS[row*QP + ko];
      short8 kb = *(const short8*)&kT[row*QP + ko];
      if (!cv){ qa = z; kb = z; }
      g = __builtin_amdgcn_mfma_f32_32x32x16_bf16(qa, kb, g, 0,0,0);
    }
    float* stg = (float*)Ysh;
    if (slice != 0){
      float* dst = stg + (size_t)(hl*3 + slice - 1)*1024;
      #pragma unroll
      for (int r = 0; r < 16; ++r) dst[r*64 + lane] = g[r];
    }
    __syncthreads();
    if (slice == 0){
      const float* s0 = stg + (size_t)(hl*3 + 0)*1024;
      const float* s1 = stg + (size_t)(hl*3 + 1)*1024;
      const float* s2 = stg + (size_t)(hl*3 + 2)*1024;
      float* dst = pg + ((size_t)(tile*NB + b)*HEADS + cc*2 + hl)*1024;
      #pragma unroll
      for (int r = 0; r < 16; ++r){
        int ix = r*64 + lane;
        dst[ix] = g[r] + s0[ix] + s1[ix] + s2[ix];
      }
    }
  };

  #pragma unroll 1
  for (int cc = 0; cc < 2; ++cc){
    conv48c(xc, q_w, q_b, cc*48, gx0, gy0, lane, w, Ysh);
    __syncthreads();
    dwQK(qd_w, qd_b, cc*48, qS, redq);
    __syncthreads();
    conv48c(xs, kv_w, kv_b, cc*48, gx0, gy0, lane, w, Ysh);
    __syncthreads();
    dwQK(kvd_w, kvd_b, cc*48, kT, redk);
    __syncthreads();
    gram(cc);
    __syncthreads();
  }
  if (t < 192){
    float v = (t < 96) ? redq[t] : redk[t - 96];
    psq[(size_t)(tile*NB + b)*192 + t] = v;
  }
}

__global__ __launch_bounds__(256) void kgredF(
  const float* __restrict__ pg, const float* __restrict__ psq, float* __restrict__ ws)
{
  const int bh = blockIdx.x;
  const int b = bh >> 2, h = bh & 3;
  const int t = threadIdx.x;
  float a0=0.f, a1=0.f, a2=0.f, a3=0.f, sq=0.f;
  for (int tile = 0; tile < NTILES; ++tile){
    const float* p = pg + ((size_t)(tile*NB + b)*HEADS + h)*1024;
    a0 += p[t]; a1 += p[t+256]; a2 += p[t+512]; a3 += p[t+768];
    if (t < 48){
      int ch = h*CH + (t % CH);
      sq += psq[(size_t)(tile*NB + b)*192 + (t < CH ? ch : 96 + ch)];
    }
  }
  if (t < 48){
    if (t < CH) ws[WS_SUMSQ_Q + b*C + h*CH + t] = sq;
    else        ws[WS_SUMSQ_K + b*C + h*CH + (t - CH)] = sq;
  }
  float accs[4] = {a0, a1, a2, a3};
  #pragma unroll
  for (int i = 0; i < 4; ++i){
    int idx = i*256 + t;
    int r = idx >> 6, ln = idx & 63;
    int row = (r&3) + 8*(r>>2) + 4*(ln>>5);
    int col = ln & 31;
    if (row < CH && col < CH)
      ws[WS_GRAM + ((size_t)(b*HEADS + h)*CH + row)*CH + col] = accs[i];
  }
}

__global__ __launch_bounds__(512, 4) void kv_out(
  const unsigned short* __restrict__ xs,
  const float* __restrict__ kv_w, const float* __restrict__ kv_b,
  const float* __restrict__ kvd_w, const float* __restrict__ kvd_b,
  const float* __restrict__ ps_b, const float* __restrict__ psh_b,
  const unsigned short* __restrict__ mb, float* __restrict__ out)
{
  __shared__ unsigned short Ysh[48*YP];
  __shared__ unsigned short vS2[224*VP];
  const int t = threadIdx.x, lane = t & 63, w = t >> 6;
  const int b = blockIdx.y, tile = blockIdx.x;
  const int txx = tile & 15, tyy = tile >> 4;
  const int gx0 = txx*16, gy0 = tyy*14;
  const unsigned short* xb_ = xs + (size_t)b*NPIX*96;

  #pragma unroll 1
  for (int which = 0; which < 2; ++which){
    #pragma unroll 1
    for (int cv = 0; cv < 2; ++cv){
      int row0 = 96 + which*96 + cv*48;
      conv48c(xb_, kv_w, kv_b, row0, gx0, gy0, lane, w, Ysh);
      __syncthreads();
      for (int slot = t; slot < 48*16; slot += 512){
        int c = slot >> 4, j = slot & 15;
        const unsigned short* yb = &Ysh[c*YP + j*16];
        float u0[16], u1[16], u2[16];
        {
          short8 s0 = *(const short8*)(yb),    s1 = *(const short8*)(yb+8);
          short8 s2 = *(const short8*)(yb+16), s3 = *(const short8*)(yb+24);
          short8 s4 = *(const short8*)(yb+32), s5 = *(const short8*)(yb+40);
          #pragma unroll
          for (int u = 0; u < 8; ++u){
            u0[u]=b2f((unsigned short)s0[u]); u0[u+8]=b2f((unsigned short)s1[u]);
            u1[u]=b2f((unsigned short)s2[u]); u1[u+8]=b2f((unsigned short)s3[u]);
            u2[u]=b2f((unsigned short)s4[u]); u2[u+8]=b2f((unsigned short)s5[u]);
          }
        }
        const float* wd = kvd_w + (size_t)(row0 + c)*9;
        float w00=wd[0],w01=wd[1],w02=wd[2],w10=wd[3],w11=wd[4],w12=wd[5],w20=wd[6],w21=wd[7],w22=wd[8];
        float bb = kvd_b[row0 + c];
        #pragma unroll
        for (int py = 0; py < 14; ++py){
          float s = bb;
          s = fmaf(w00,u0[py],s); s = fmaf(w10,u0[py+1],s); s = fmaf(w20,u0[py+2],s);
          s = fmaf(w01,u1[py],s); s = fmaf(w11,u1[py+1],s); s = fmaf(w21,u1[py+2],s);
          s = fmaf(w02,u2[py],s); s = fmaf(w12,u2[py+1],s); s = fmaf(w22,u2[py+2],s);
          vS2[(py*16 + j)*VP + cv*48 + c] = f2b(s);
        }
      }
      __syncthreads();
    }
    const unsigned short* mbp = mb + ((size_t)which*NB + b)*9216;
    const float* bias = which ? psh_b : ps_b;
    float* ob = out + (size_t)which*NB*C*NPIX + (size_t)b*C*NPIX;
    for (int tl = w; tl < 84; tl += 8){
      int mi = tl / 14, n = tl - mi*14;
      const unsigned short* mp = mbp + (size_t)(mi*16 + (lane&15))*96 + (lane>>4)*8;
      short8 a0 = *(const short8*)(mp);
      short8 a1 = *(const short8*)(mp + 32);
      short8 a2 = *(const short8*)(mp + 64);
      float4 bv = *(const float4*)&bias[mi*16 + (lane>>4)*4];
      f32x4 acc = {bv.x, bv.y, bv.z, bv.w};
      const unsigned short* xb = &vS2[(size_t)(n*16 + (lane&15))*VP + (lane>>4)*8];
      acc = __builtin_amdgcn_mfma_f32_16x16x32_bf16(a0, *(const short8*)(xb),    acc, 0,0,0);
      acc = __builtin_amdgcn_mfma_f32_16x16x32_bf16(a1, *(const short8*)(xb+32), acc, 0,0,0);
      acc = __builtin_amdgcn_mfma_f32_16x16x32_bf16(a2, *(const short8*)(xb+64), acc, 0,0,0);
      int gy = gy0 + n;
      if (gy < HH){
        #pragma unroll
        for (int r = 0; r < 4; ++r)
          ob[(size_t)(mi*16 + (lane>>4)*4 + r)*NPIX + gy*WW + gx0 + (lane&15)] = acc[r];
      }
    }
    __syncthreads();
  }
}

extern "C" void kernel_launch(void* const* d_in, const int* in_sizes, int n_in,
                              void* d_out, int out_size, void* d_ws, size_t ws_size,
                              hipStream_t stream)
{
  const float* content = (const float*)d_in[0];
  const float* style   = (const float*)d_in[1];
  const float* temp    = (const float*)d_in[2];
  const float* q_w   = (const float*)d_in[3];
  const float* q_b   = (const float*)d_in[4];
  const float* qd_w  = (const float*)d_in[5];
  const float* qd_b  = (const float*)d_in[6];
  const float* kv_w  = (const float*)d_in[7];
  const float* kv_b  = (const float*)d_in[8];
  const float* kvd_w = (const float*)d_in[9];
  const float* kvd_b = (const float*)d_in[10];
  const float* ps_w  = (const float*)d_in[11];
  const float* ps_b  = (const float*)d_in[12];
  const float* psh_w = (const float*)d_in[13];
  const float* psh_b = (const float*)d_in[14];
  float* out = (float*)d_out;
  float* ws  = (float*)d_ws;

  unsigned short* xt = (unsigned short*)((char*)d_ws + XT_OFF_BYTES);

  if (ws_size >= WS_NEED2){
    unsigned short* qk  = (unsigned short*)((char*)d_ws + QK_OFF);
    unsigned short* vbh = (unsigned short*)((char*)d_ws + VB_OFF);
    unsigned short* vbs = (unsigned short*)(out + (size_t)NB*C*NPIX); // alias: shift half of d_out
    float* pg  = (float*)((char*)d_ws + PG_OFF);
    float* psq = (float*)((char*)d_ws + PSQ_OFF);
    unsigned short* mb = (unsigned short*)((char*)d_ws + MB_OFF);
    unsigned short* wb = (unsigned short*)((char*)d_ws + WB_OFF);

    k0t<<<dim3(NPIX/64, NB, 2), dim3(256), 0, stream>>>(content, style, xt);
    kwpack<<<dim3(144), dim3(256), 0, stream>>>(q_w, kv_w, wb);
    kconv<<<dim3(NTILES, NB, 4), dim3(512), 0, stream>>>(
        xt, wb, q_b, qd_w, qd_b, kv_b, kvd_w, kvd_b, qk, vbs, vbh, psq);
    kgram<<<dim3(KSPLIT, NB), dim3(384), 0, stream>>>(qk, pg);
    kgredN<<<dim3(NB, 37), dim3(256), 0, stream>>>(pg, psq, ws);
    k2_attn<<<dim3(NB), dim3(256), 0, stream>>>(temp, ps_w, psh_w, ws, mb);
    // scale: reads vbs (aliased in shift half), writes scale half — must precede shift
    kMv<<<dim3(NPIX/256, NB), dim3(512), 0, stream>>>(vbs, mb, ps_b, out);
    // shift: reads vbh (ws), writes shift half
    kMv<<<dim3(NPIX/256, NB), dim3(512), 0, stream>>>(
        vbh, mb + (size_t)NB*9216, psh_b, out + (size_t)NB*C*NPIX);
  } else {
    float* pg  = (float*)((char*)d_ws + F_PG_OFF);
    float* psq = (float*)((char*)d_ws + F_PSQ_OFF);
    unsigned short* mb = (unsigned short*)((char*)d_ws + F_MB_OFF);
    k0t<<<dim3(NPIX/64, NB, 2), dim3(256), 0, stream>>>(content, style, xt);
    kqk<<<dim3(NTILES, NB), dim3(512), 0, stream>>>(
        xt, q_w, q_b, qd_w, qd_b, kv_w, kv_b, kvd_w, kvd_b, pg, psq);
    kgredF<<<dim3(NB*HEADS), dim3(256), 0, stream>>>(pg, psq, ws);
    k2_attn<<<dim3(NB), dim3(256), 0, stream>>>(temp, ps_w, psh_w, ws, mb);
    kv_out<<<dim3(NTILES, NB), dim3(512), 0, stream>>>(
        xt + (size_t)NB*NPIX*96, kv_w, kv_b, kvd_w, kvd_b, ps_b, psh_b, mb, out);
  }
}

// Round 7
// 447.708 us; speedup vs baseline: 5.4043x; 1.0850x over previous
//
#include <hip/hip_runtime.h>

#define NB 4
#define C 96
#define HH 256
#define WW 256
#define NPIX (HH*WW)
#define HEADS 4
#define CH 24

// ---- tiling: interior 16 wide x 14 tall, halo 18x16 ----
#define NTX2 16
#define NTY2 19
#define NTILES (NTX2*NTY2)
#define YP 296      // fallback Ysh pitch
#define QP 264      // fallback qS/kT pitch
#define VP 104      // vS pitch ([px][ch]) for kMv + fallback
#define KSPLIT 128
#define YR 24       // kconv Ysh row pitch (shorts)
#define YC 392      // kconv Ysh channel stride (shorts)
#define XTP 76      // k0t LDS pitch (shorts): 152B, 8B-aligned, dword stride 38≡6 mod 32 -> 2-way

#define WS_SUMSQ_Q 0
#define WS_SUMSQ_K (WS_SUMSQ_Q + NB*C)
#define WS_GRAM    (WS_SUMSQ_K + NB*C)
#define WS_MS      (WS_GRAM + NB*HEADS*CH*CH)
#define WS_MSH     (WS_MS + NB*C*C)

// shared xt region
#define XT_OFF_BYTES ((size_t)335872)
#define XT_BYTES   ((size_t)2*NB*NPIX*96*2)

// ---- fallback (r4) layout ----
#define F_PSQ_OFF   (XT_OFF_BYTES + XT_BYTES)
#define F_PSQ_BYTES ((size_t)NTILES*NB*192*4)
#define F_PG_OFF    (F_PSQ_OFF + F_PSQ_BYTES)
#define F_PG_BYTES  ((size_t)NTILES*NB*HEADS*1024*4)
#define F_MB_OFF    (F_PG_OFF + F_PG_BYTES)
#define F_MB_BYTES  ((size_t)2*NB*96*96*2)
#define F_WS_NEED   (F_MB_OFF + F_MB_BYTES)

// ---- new layout (footprint same as r5/r6) ----
#define QK_OFF    (XT_OFF_BYTES + XT_BYTES)
#define QK_BYTES  ((size_t)2*NB*96*NPIX*2)
#define VB_OFF    (QK_OFF + QK_BYTES)              // v_shift ([b][96][n] bf16)
#define VB_BYTES  ((size_t)NB*NPIX*96*2)
#define PG_OFF    (VB_OFF + VB_BYTES)
#define PG_BYTES  ((size_t)KSPLIT*NB*9216*4)
#define PSQ_OFF   (PG_OFF + PG_BYTES)
#define PSQ_BYTES ((size_t)4*NTILES*NB*48*4)
#define MB_OFF    (PSQ_OFF + PSQ_BYTES)
#define MB_BYTES  ((size_t)2*NB*96*96*2)
#define WB_OFF    (MB_OFF + MB_BYTES)
#define WB_BYTES  ((size_t)384*96*2)
#define WS_NEED2  (WB_OFF + WB_BYTES)

typedef short short8 __attribute__((ext_vector_type(8)));
typedef float f32x4 __attribute__((ext_vector_type(4)));
typedef float f32x16 __attribute__((ext_vector_type(16)));

__device__ __forceinline__ unsigned short f2b(float f){
  unsigned u = __float_as_uint(f);
  unsigned r = u + 0x7FFFu + ((u >> 16) & 1u);
  return (unsigned short)(r >> 16);
}
__device__ __forceinline__ float b2f(unsigned short s){
  return __uint_as_float(((unsigned)s) << 16);
}
__device__ __forceinline__ short8 pack8(float4 a, float4 b){
  short8 r;
  r[0]=(short)f2b(a.x); r[1]=(short)f2b(a.y); r[2]=(short)f2b(a.z); r[3]=(short)f2b(a.w);
  r[4]=(short)f2b(b.x); r[5]=(short)f2b(b.y); r[6]=(short)f2b(b.z); r[7]=(short)f2b(b.w);
  return r;
}

// ============================ K0: fp32 [c][n] -> bf16 [n][c] ============================
__global__ __launch_bounds__(256) void k0t(
  const float* __restrict__ content, const float* __restrict__ style,
  unsigned short* __restrict__ xt)
{
  __shared__ unsigned short Xt[96*XTP];
  const int t = threadIdx.x;
  const int n0 = blockIdx.x * 64;
  const int b = blockIdx.y, src = blockIdx.z;
  const float* in = (src ? style : content) + (size_t)b*C*NPIX;
  #pragma unroll
  for (int i = 0; i < 6; ++i){
    int s = i*256 + t;
    int r = s >> 4, c4 = s & 15;
    float4 f = *(const float4*)(in + (size_t)r*NPIX + n0 + c4*4);
    unsigned lo = ((unsigned)f2b(f.y) << 16) | f2b(f.x);
    unsigned hi = ((unsigned)f2b(f.w) << 16) | f2b(f.z);
    *(uint2*)&Xt[r*XTP + c4*4] = make_uint2(lo, hi);
  }
  __syncthreads();
  unsigned* dst = (unsigned*)(xt + (((size_t)src*NB + b)*NPIX + n0)*96);
  #pragma unroll
  for (int i = 0; i < 12; ++i){
    int s = i*256 + t;
    int j = s / 48, c2 = s - j*48;
    unsigned v = ((unsigned)Xt[(c2*2+1)*XTP + j] << 16) | Xt[(c2*2)*XTP + j];
    dst[(size_t)j*48 + c2] = v;
  }
}

// ============================ kwpack ============================
__global__ __launch_bounds__(256) void kwpack(
  const float* __restrict__ q_w, const float* __restrict__ kv_w,
  unsigned short* __restrict__ wb)
{
  int i = blockIdx.x*256 + threadIdx.x;
  if (i < 9216) wb[i] = f2b(q_w[i]);
  else if (i < 36864) wb[i] = f2b(kv_w[i - 9216]);
}

// ============================ kconv: one 48-ch chunk per block ============================
// z: 0,1 = q chunks (content); 2,3 = k; 4,5 = v_scale; 6,7 = v_shift (style)
__global__ __launch_bounds__(512, 4) void kconv(
  const unsigned short* __restrict__ xt, const unsigned short* __restrict__ wb,
  const float* __restrict__ q_b, const float* __restrict__ qd_w, const float* __restrict__ qd_b,
  const float* __restrict__ kv_b, const float* __restrict__ kvd_w, const float* __restrict__ kvd_b,
  unsigned short* __restrict__ qk, unsigned short* __restrict__ vbs,
  unsigned short* __restrict__ vbh, float* __restrict__ psq)
{
  __shared__ unsigned short Ysh[48*YC];   // 37632 B
  __shared__ float red[48];
  const int t = threadIdx.x, lane = t & 63, w = t >> 6;
  const int tile = blockIdx.x, b = blockIdx.y, z = blockIdx.z;
  const int txx = tile & 15, tyy = tile >> 4;
  const int gx0 = txx*16, gy0 = tyy*14;
  const unsigned short* xsrc = xt + ((size_t)((z < 2 ? 0 : 1)*NB + b))*NPIX*96;
  const int wrow0 = (z < 2) ? z*48 : 96 + (z-2)*48;
  const float* cb  = (z<2) ? q_b  + z*48           : kv_b  + (size_t)(z-2)*48;
  const float* dww = (z<2) ? qd_w + (size_t)z*48*9 : kvd_w + (size_t)(z-2)*48*9;
  const float* dwb = (z<2) ? qd_b + z*48           : kvd_b + (size_t)(z-2)*48;
  unsigned short* dst0;
  if (z < 2)      dst0 = qk  + ((size_t)(0*NB + b)*96 + (size_t)z*48)*NPIX;
  else if (z < 4) dst0 = qk  + ((size_t)(1*NB + b)*96 + (size_t)(z-2)*48)*NPIX;
  else if (z < 6) dst0 = vbs + ((size_t)b*96 + (size_t)(z-4)*48)*NPIX;
  else            dst0 = vbh + ((size_t)b*96 + (size_t)(z-6)*48)*NPIX;

  if (t < 48) red[t] = 0.f;

  // persistent halo fragments
  const int hy = lane & 15, khalf = lane >> 4;
  const int gyh = gy0 - 1 + hy;
  short8 xf[3][3]; bool imv[3];
  const int np = (w < 2) ? 3 : 2;
  #pragma unroll
  for (int i = 0; i < 3; ++i){
    if (i >= np) break;
    int pt = w + i*8;
    int gx = gx0 - 1 + pt;
    bool im = (gx>=0) && (gx<WW) && (gyh>=0) && (gyh<HH);
    imv[i] = im;
    const unsigned short* xp = xsrc + (size_t)(im ? (gyh*WW + gx) : 0)*96 + khalf*8;
    short8 zz = {};
    #pragma unroll
    for (int kk = 0; kk < 3; ++kk){
      short8 v = *(const short8*)(xp + kk*32);
      xf[i][kk] = im ? v : zz;
    }
  }

  // conv1x1: 48 output rows over halo -> Ysh [ch][hy][pt]
  #pragma unroll 1
  for (int mi = 0; mi < 3; ++mi){
    const unsigned short* wp = wb + (size_t)(wrow0 + mi*16 + hy)*96 + khalf*8;
    short8 a0 = *(const short8*)(wp);
    short8 a1 = *(const short8*)(wp + 32);
    short8 a2 = *(const short8*)(wp + 64);
    float4 bv = *(const float4*)&cb[mi*16 + khalf*4];
    #pragma unroll
    for (int i = 0; i < 3; ++i){
      if (i >= np) break;
      int pt = w + i*8;
      f32x4 acc = {bv.x, bv.y, bv.z, bv.w};
      acc = __builtin_amdgcn_mfma_f32_16x16x32_bf16(a0, xf[i][0], acc, 0,0,0);
      acc = __builtin_amdgcn_mfma_f32_16x16x32_bf16(a1, xf[i][1], acc, 0,0,0);
      acc = __builtin_amdgcn_mfma_f32_16x16x32_bf16(a2, xf[i][2], acc, 0,0,0);
      #pragma unroll
      for (int r = 0; r < 4; ++r){
        int ch = mi*16 + khalf*4 + r;
        Ysh[ch*YC + hy*YR + pt] = imv[i] ? f2b(acc[r]) : (unsigned short)0;
      }
    }
  }
  __syncthreads();

  // dw 3x3, wave-balanced: wave w owns slots [w*84, (w+1)*84)
  for (int sl = lane; sl < 84; sl += 64){
    int slot = w*84 + sl;                 // 0..671
    int c = slot / 14, py = slot - (slot/14)*14;
    int gy = gy0 + py;
    if (gy < HH){
      const float* wd = dww + (size_t)c*9;
      float w00=wd[0],w01=wd[1],w02=wd[2],w10=wd[3],w11=wd[4],w12=wd[5],w20=wd[6],w21=wd[7],w22=wd[8];
      float bb = dwb[c];
      const unsigned short* yb = &Ysh[c*YC + py*YR];
      float o[16];
      #pragma unroll
      for (int half = 0; half < 2; ++half){
        float u[3][10];
        #pragma unroll
        for (int uu = 0; uu < 3; ++uu){
          const unsigned short* rp = yb + uu*YR + half*8;
          short8 s = *(const short8*)rp;
          unsigned ex = *(const unsigned*)(rp + 8);
          #pragma unroll
          for (int j = 0; j < 8; ++j) u[uu][j] = b2f((unsigned short)s[j]);
          u[uu][8] = b2f((unsigned short)(ex & 0xffffu));
          u[uu][9] = b2f((unsigned short)(ex >> 16));
        }
        #pragma unroll
        for (int j = 0; j < 8; ++j){
          float s = bb;
          s = fmaf(w00,u[0][j],s); s = fmaf(w01,u[0][j+1],s); s = fmaf(w02,u[0][j+2],s);
          s = fmaf(w10,u[1][j],s); s = fmaf(w11,u[1][j+1],s); s = fmaf(w12,u[1][j+2],s);
          s = fmaf(w20,u[2][j],s); s = fmaf(w21,u[2][j+1],s); s = fmaf(w22,u[2][j+2],s);
          o[half*8 + j] = s;
        }
      }
      unsigned short vv[16];
      if (z < 4){
        float sq = 0.f;
        #pragma unroll
        for (int j = 0; j < 16; ++j){ sq = fmaf(o[j], o[j], sq); vv[j] = f2b(o[j]); }
        atomicAdd(&red[c], sq);
      } else {
        #pragma unroll
        for (int j = 0; j < 16; ++j) vv[j] = f2b(o[j]);
      }
      unsigned short* qp = dst0 + (size_t)c*NPIX + (size_t)gy*WW + gx0;
      *(short8*)qp       = *(const short8*)&vv[0];
      *(short8*)(qp + 8) = *(const short8*)&vv[8];
    }
  }
  if (z < 4){
    __syncthreads();
    if (t < 48)
      psq[((size_t)(z*NTILES + tile)*NB + b)*48 + t] = red[t];
  }
}

// ============================ kgram: partial-K Gram ============================
__global__ __launch_bounds__(384) void kgram(
  const unsigned short* __restrict__ qk, float* __restrict__ pg)
{
  const int t = threadIdx.x, lane = t & 63, wv = t >> 6;
  const int ks = blockIdx.x, b = blockIdx.y;
  const int n0 = ks * (NPIX / KSPLIT);
  const unsigned short* qb = qk + ((size_t)(0*NB + b)*96)*NPIX;
  const unsigned short* kb = qk + ((size_t)(1*NB + b)*96)*NPIX;
  f32x4 acc[6];
  #pragma unroll
  for (int i = 0; i < 6; ++i) acc[i] = (f32x4){0.f,0.f,0.f,0.f};
  #pragma unroll 1
  for (int st = 0; st < (NPIX/KSPLIT)/32; ++st){
    int off = n0 + st*32 + (lane>>4)*8;
    short8 bf = *(const short8*)(kb + (size_t)(wv*16 + (lane&15))*NPIX + off);
    #pragma unroll
    for (int ci = 0; ci < 6; ++ci){
      short8 af = *(const short8*)(qb + (size_t)(ci*16 + (lane&15))*NPIX + off);
      acc[ci] = __builtin_amdgcn_mfma_f32_16x16x32_bf16(af, bf, acc[ci], 0,0,0);
    }
  }
  float* dst = pg + ((size_t)ks*NB + b)*9216;
  #pragma unroll
  for (int ci = 0; ci < 6; ++ci){
    #pragma unroll
    for (int r = 0; r < 4; ++r)
      dst[(ci*6 + wv)*256 + ((lane>>4)*4 + r)*16 + (lane&15)] = acc[ci][r];
  }
}

// ============================ kgredN ============================
__global__ __launch_bounds__(256) void kgredN(
  const float* __restrict__ pg, const float* __restrict__ psq, float* __restrict__ ws)
{
  const int b = blockIdx.x, by = blockIdx.y, t = threadIdx.x;
  if (by < 36){
    int ci = by / 6;
    int qrow = ci*16 + (t >> 4), krow = (by - ci*6)*16 + (t & 15);
    float s = 0.f;
    for (int ks = 0; ks < KSPLIT; ++ks)
      s += pg[((size_t)ks*NB + b)*9216 + by*256 + t];
    int h = qrow / CH;
    if (krow / CH == h)
      ws[WS_GRAM + ((size_t)(b*HEADS + h)*CH + (qrow % CH))*CH + (krow % CH)] = s;
  } else {
    if (t < 192){
      int src = t / 96, c = t - (t/96)*96;
      int zz = src*2 + (c/48), cc = c - (c/48)*48;
      float s = 0.f;
      for (int tile = 0; tile < NTILES; ++tile)
        s += psq[((size_t)(zz*NTILES + tile)*NB + b)*48 + cc];
      ws[(src ? WS_SUMSQ_K : WS_SUMSQ_Q) + b*C + c] = s;
    }
  }
}

// ============================ k2: softmax + M matrices ============================
__global__ void k2_attn(
  const float* __restrict__ temp,
  const float* __restrict__ ps_w, const float* __restrict__ psh_w,
  float* __restrict__ ws, unsigned short* __restrict__ mb)
{
  const int b = blockIdx.x;
  const int t = threadIdx.x;
  __shared__ float attn[C * CH];
  __shared__ float nq[C], nk[C];
  if (t < C){
    nq[t] = fmaxf(sqrtf(ws[WS_SUMSQ_Q + b * C + t]), 1e-12f);
    nk[t] = fmaxf(sqrtf(ws[WS_SUMSQ_K + b * C + t]), 1e-12f);
  }
  __syncthreads();
  if (t < C){
    int h = t / CH;
    const float* g = ws + WS_GRAM + (((size_t)b * HEADS + h) * CH + (t % CH)) * CH;
    float tp = temp[h];
    float row[CH];
    float mx = -3.4e38f;
    #pragma unroll
    for (int d = 0; d < CH; ++d){
      row[d] = g[d] / (nq[t] * nk[h * CH + d]) * tp;
      mx = fmaxf(mx, row[d]);
    }
    float s = 0.f;
    #pragma unroll
    for (int d = 0; d < CH; ++d){ row[d] = expf(row[d] - mx); s += row[d]; }
    float inv = 1.f / s;
    #pragma unroll
    for (int d = 0; d < CH; ++d) attn[t * CH + d] = row[d] * inv;
  }
  __syncthreads();
  for (int idx = t; idx < C * C; idx += 256){
    int o = idx / C, dg = idx - o * C;
    int h = dg / CH, d = dg - h * CH;
    float s1 = 0.f, s2 = 0.f;
    #pragma unroll
    for (int c2 = 0; c2 < CH; ++c2){
      float a = attn[(h * CH + c2) * CH + d];
      s1 = fmaf(ps_w [(size_t)o * C + h * CH + c2], a, s1);
      s2 = fmaf(psh_w[(size_t)o * C + h * CH + c2], a, s2);
    }
    ws[WS_MS  + (size_t)b * C * C + idx] = s1;
    ws[WS_MSH + (size_t)b * C * C + idx] = s2;
    if (mb){
      mb[((size_t)0*NB + b)*9216 + idx] = f2b(s1);
      mb[((size_t)1*NB + b)*9216 + idx] = f2b(s2);
    }
  }
}

// ============================ kMv: out = M @ v, v bf16 [c][n], paired-dword LDS transpose ============================
__global__ __launch_bounds__(512) void kMv(
  const unsigned short* __restrict__ vb, const unsigned short* __restrict__ mb,
  const float* __restrict__ bias, float* __restrict__ out)
{
  __shared__ unsigned short vS[256*VP];
  unsigned* vS32 = (unsigned*)vS;
  const int t = threadIdx.x, lane = t & 63, w = t >> 6;
  const int b = blockIdx.y;
  const int n0 = blockIdx.x * 256;
  const unsigned short* vbase = vb + (size_t)b*96*NPIX;
  #pragma unroll
  for (int i = 0; i < 3; ++i){
    int task = i*512 + t;            // 1536 = 48 ch-pairs x 32 segs
    int cp = task >> 5, seg = task & 31;
    const unsigned short* r0 = vbase + (size_t)(2*cp)*NPIX + n0 + seg*8;
    short8 a  = *(const short8*)r0;
    short8 bq = *(const short8*)(r0 + NPIX);
    #pragma unroll
    for (int j = 0; j < 8; ++j){
      unsigned d = ((unsigned)(unsigned short)bq[j] << 16) | (unsigned)(unsigned short)a[j];
      vS32[(seg*8 + j)*(VP/2) + cp] = d;
    }
  }
  __syncthreads();
  const unsigned short* mbb = mb + (size_t)b*9216;
  float* ob = out + (size_t)b*C*NPIX;
  #pragma unroll 1
  for (int mi = 0; mi < 6; ++mi){
    const unsigned short* mp = mbb + (size_t)(mi*16 + (lane & 15))*96 + (lane>>4)*8;
    short8 a0 = *(const short8*)(mp);
    short8 a1 = *(const short8*)(mp + 32);
    short8 a2 = *(const short8*)(mp + 64);
    float4 bv = *(const float4*)&bias[mi*16 + (lane>>4)*4];
    #pragma unroll
    for (int g = 0; g < 2; ++g){
      int px = (w*2 + g)*16 + (lane & 15);
      const unsigned short* xb = &vS[px*VP + (lane>>4)*8];
      f32x4 acc = {bv.x, bv.y, bv.z, bv.w};
      acc = __builtin_amdgcn_mfma_f32_16x16x32_bf16(a0, *(const short8*)(xb),    acc, 0,0,0);
      acc = __builtin_amdgcn_mfma_f32_16x16x32_bf16(a1, *(const short8*)(xb+32), acc, 0,0,0);
      acc = __builtin_amdgcn_mfma_f32_16x16x32_bf16(a2, *(const short8*)(xb+64), acc, 0,0,0);
      #pragma unroll
      for (int r = 0; r < 4; ++r)
        ob[(size_t)(mi*16 + (lane>>4)*4 + r)*NPIX + n0 + px] = acc[r];
    }
  }
}

// ============================ fallback (r4) kernels ============================
__device__ __forceinline__ void conv48c(
  const unsigned short* __restrict__ xbase, const float* __restrict__ wmat,
  const float* __restrict__ bias, int row0,
  int gx0, int gy0, int lane, int w, unsigned short* __restrict__ Ysh)
{
  const int hy = lane & 15, khalf = lane >> 4;
  const int gy = gy0 - 1 + hy;
  short8 xf[3][3]; bool imv[3]; int np = (w < 2) ? 3 : 2;
  #pragma unroll
  for (int i = 0; i < 3; ++i){
    if (i >= np) break;
    int pt = w + i*8;
    int gx = gx0 - 1 + pt;
    bool im = (gx>=0) && (gx<WW) && (gy>=0) && (gy<HH);
    imv[i] = im;
    int n = im ? (gy*WW + gx) : 0;
    const unsigned short* xp = xbase + (size_t)n*96 + khalf*8;
    short8 z = {};
    #pragma unroll
    for (int kk = 0; kk < 3; ++kk){
      short8 v = *(const short8*)(xp + kk*32);
      xf[i][kk] = im ? v : z;
    }
  }
  #pragma unroll 1
  for (int mi = 0; mi < 3; ++mi){
    int orow = row0 + mi*16 + hy;
    const float* wp = wmat + (size_t)orow*96 + khalf*8;
    short8 a0 = pack8(*(const float4*)(wp),    *(const float4*)(wp+4));
    short8 a1 = pack8(*(const float4*)(wp+32), *(const float4*)(wp+36));
    short8 a2 = pack8(*(const float4*)(wp+64), *(const float4*)(wp+68));
    float4 bv = *(const float4*)&bias[row0 + mi*16 + khalf*4];
    #pragma unroll
    for (int i = 0; i < 3; ++i){
      if (i >= np) break;
      int pt = w + i*8;
      f32x4 acc = {bv.x, bv.y, bv.z, bv.w};
      acc = __builtin_amdgcn_mfma_f32_16x16x32_bf16(a0, xf[i][0], acc, 0,0,0);
      acc = __builtin_amdgcn_mfma_f32_16x16x32_bf16(a1, xf[i][1], acc, 0,0,0);
      acc = __builtin_amdgcn_mfma_f32_16x16x32_bf16(a2, xf[i][2], acc, 0,0,0);
      #pragma unroll
      for (int r = 0; r < 4; ++r){
        int ch = mi*16 + khalf*4 + r;
        Ysh[ch*YP + pt*16 + hy] = imv[i] ? f2b(acc[r]) : (unsigned short)0;
      }
    }
  }
}

__global__ __launch_bounds__(512, 4) void kqk(
  const unsigned short* __restrict__ xt,
  const float* __restrict__ q_w, const float* __restrict__ q_b,
  const float* __restrict__ qd_w, const float* __restrict__ qd_b,
  const float* __restrict__ kv_w, const float* __restrict__ kv_b,
  const float* __restrict__ kvd_w, const float* __restrict__ kvd_b,
  float* __restrict__ pg, float* __restrict__ psq)
{
  __shared__ unsigned short Ysh[48*YP];
  __shared__ unsigned short qS[48*QP];
  __shared__ unsigned short kT[48*QP];
  __shared__ float redq[C], redk[C];

  const int t = threadIdx.x, lane = t & 63, w = t >> 6;
  const int b = blockIdx.y, tile = blockIdx.x;
  const int txx = tile & 15, tyy = tile >> 4;
  const int gx0 = txx*16, gy0 = tyy*14;
  if (t < C){ redq[t] = 0.f; redk[t] = 0.f; }
  __syncthreads();

  const unsigned short* xc = xt + ((size_t)(0*NB + b))*NPIX*96;
  const unsigned short* xs = xt + ((size_t)(1*NB + b))*NPIX*96;

  auto dwQK = [&](const float* dww, const float* dwb, int wrow0,
                  unsigned short* dst, float* red){
    for (int slot = t; slot < 48*16; slot += 512){
      int c = slot >> 4, j = slot & 15;
      const unsigned short* yb = &Ysh[c*YP + j*16];
      float u0[16], u1[16], u2[16];
      {
        short8 s0 = *(const short8*)(yb),    s1 = *(const short8*)(yb+8);
        short8 s2 = *(const short8*)(yb+16), s3 = *(const short8*)(yb+24);
        short8 s4 = *(const short8*)(yb+32), s5 = *(const short8*)(yb+40);
        #pragma unroll
        for (int u = 0; u < 8; ++u){
          u0[u]=b2f((unsigned short)s0[u]); u0[u+8]=b2f((unsigned short)s1[u]);
          u1[u]=b2f((unsigned short)s2[u]); u1[u+8]=b2f((unsigned short)s3[u]);
          u2[u]=b2f((unsigned short)s4[u]); u2[u+8]=b2f((unsigned short)s5[u]);
        }
      }
      const float* wd = dww + (size_t)(wrow0 + c)*9;
      float w00=wd[0],w01=wd[1],w02=wd[2],w10=wd[3],w11=wd[4],w12=wd[5],w20=wd[6],w21=wd[7],w22=wd[8];
      float bb = dwb[wrow0 + c];
      unsigned short vv[16];
      float sq = 0.f;
      #pragma unroll
      for (int py = 0; py < 14; ++py){
        float s = bb;
        s = fmaf(w00,u0[py],s); s = fmaf(w10,u0[py+1],s); s = fmaf(w20,u0[py+2],s);
        s = fmaf(w01,u1[py],s); s = fmaf(w11,u1[py+1],s); s = fmaf(w21,u1[py+2],s);
        s = fmaf(w02,u2[py],s); s = fmaf(w12,u2[py+1],s); s = fmaf(w22,u2[py+2],s);
        if (gy0 + py >= HH) s = 0.f;
        sq = fmaf(s, s, sq);
        vv[py] = f2b(s);
      }
      vv[14] = 0; vv[15] = 0;
      atomicAdd(&red[wrow0 + c], sq);
      *(short8*)&dst[c*QP + j*16]     = *(short8*)&vv[0];
      *(short8*)&dst[c*QP + j*16 + 8] = *(short8*)&vv[8];
    }
  };

  auto gram = [&](int cc){
    int hl = w & 1, slice = w >> 1;
    int cl = lane & 31; bool cv = cl < CH;
    int row = hl*CH + (cv ? cl : 0);
    f32x16 g;
    #pragma unroll
    for (int r = 0; r < 16; ++r) g[r] = 0.f;
    short8 z = {};
    for (int ks = slice; ks < 16; ks += 4){
      int ko = ks*16 + (lane>>5)*8;
      short8 qa = *(const short8*)&qS[row*QP + ko];
      short8 kb = *(const short8*)&kT[row*QP + ko];
      if (!cv){ qa = z; kb = z; }
      g = __builtin_amdgcn_mfma_f32_32x32x16_bf16(qa, kb, g, 0,0,0);
    }
    float* stg = (float*)Ysh;
    if (slice != 0){
      float* dst = stg + (size_t)(hl*3 + slice - 1)*1024;
      #pragma unroll
      for (int r = 0; r < 16; ++r) dst[r*64 + lane] = g[r];
    }
    __syncthreads();
    if (slice == 0){
      const float* s0 = stg + (size_t)(hl*3 + 0)*1024;
      const float* s1 = stg + (size_t)(hl*3 + 1)*1024;
      const float* s2 = stg + (size_t)(hl*3 + 2)*1024;
      float* dst = pg + ((size_t)(tile*NB + b)*HEADS + cc*2 + hl)*1024;
      #pragma unroll
      for (int r = 0; r < 16; ++r){
        int ix = r*64 + lane;
        dst[ix] = g[r] + s0[ix] + s1[ix] + s2[ix];
      }
    }
  };

  #pragma unroll 1
  for (int cc = 0; cc < 2; ++cc){
    conv48c(xc, q_w, q_b, cc*48, gx0, gy0, lane, w, Ysh);
    __syncthreads();
    dwQK(qd_w, qd_b, cc*48, qS, redq);
    __syncthreads();
    conv48c(xs, kv_w, kv_b, cc*48, gx0, gy0, lane, w, Ysh);
    __syncthreads();
    dwQK(kvd_w, kvd_b, cc*48, kT, redk);
    __syncthreads();
    gram(cc);
    __syncthreads();
  }
  if (t < 192){
    float v = (t < 96) ? redq[t] : redk[t - 96];
    psq[(size_t)(tile*NB + b)*192 + t] = v;
  }
}

__global__ __launch_bounds__(256) void kgredF(
  const float* __restrict__ pg, const float* __restrict__ psq, float* __restrict__ ws)
{
  const int bh = blockIdx.x;
  const int b = bh >> 2, h = bh & 3;
  const int t = threadIdx.x;
  float a0=0.f, a1=0.f, a2=0.f, a3=0.f, sq=0.f;
  for (int tile = 0; tile < NTILES; ++tile){
    const float* p = pg + ((size_t)(tile*NB + b)*HEADS + h)*1024;
    a0 += p[t]; a1 += p[t+256]; a2 += p[t+512]; a3 += p[t+768];
    if (t < 48){
      int ch = h*CH + (t % CH);
      sq += psq[(size_t)(tile*NB + b)*192 + (t < CH ? ch : 96 + ch)];
    }
  }
  if (t < 48){
    if (t < CH) ws[WS_SUMSQ_Q + b*C + h*CH + t] = sq;
    else        ws[WS_SUMSQ_K + b*C + h*CH + (t - CH)] = sq;
  }
  float accs[4] = {a0, a1, a2, a3};
  #pragma unroll
  for (int i = 0; i < 4; ++i){
    int idx = i*256 + t;
    int r = idx >> 6, ln = idx & 63;
    int row = (r&3) + 8*(r>>2) + 4*(ln>>5);
    int col = ln & 31;
    if (row < CH && col < CH)
      ws[WS_GRAM + ((size_t)(b*HEADS + h)*CH + row)*CH + col] = accs[i];
  }
}

__global__ __launch_bounds__(512, 4) void kv_out(
  const unsigned short* __restrict__ xs,
  const float* __restrict__ kv_w, const float* __restrict__ kv_b,
  const float* __restrict__ kvd_w, const float* __restrict__ kvd_b,
  const float* __restrict__ ps_b, const float* __restrict__ psh_b,
  const unsigned short* __restrict__ mb, float* __restrict__ out)
{
  __shared__ unsigned short Ysh[48*YP];
  __shared__ unsigned short vS2[224*VP];
  const int t = threadIdx.x, lane = t & 63, w = t >> 6;
  const int b = blockIdx.y, tile = blockIdx.x;
  const int txx = tile & 15, tyy = tile >> 4;
  const int gx0 = txx*16, gy0 = tyy*14;
  const unsigned short* xb_ = xs + (size_t)b*NPIX*96;

  #pragma unroll 1
  for (int which = 0; which < 2; ++which){
    #pragma unroll 1
    for (int cv = 0; cv < 2; ++cv){
      int row0 = 96 + which*96 + cv*48;
      conv48c(xb_, kv_w, kv_b, row0, gx0, gy0, lane, w, Ysh);
      __syncthreads();
      for (int slot = t; slot < 48*16; slot += 512){
        int c = slot >> 4, j = slot & 15;
        const unsigned short* yb = &Ysh[c*YP + j*16];
        float u0[16], u1[16], u2[16];
        {
          short8 s0 = *(const short8*)(yb),    s1 = *(const short8*)(yb+8);
          short8 s2 = *(const short8*)(yb+16), s3 = *(const short8*)(yb+24);
          short8 s4 = *(const short8*)(yb+32), s5 = *(const short8*)(yb+40);
          #pragma unroll
          for (int u = 0; u < 8; ++u){
            u0[u]=b2f((unsigned short)s0[u]); u0[u+8]=b2f((unsigned short)s1[u]);
            u1[u]=b2f((unsigned short)s2[u]); u1[u+8]=b2f((unsigned short)s3[u]);
            u2[u]=b2f((unsigned short)s4[u]); u2[u+8]=b2f((unsigned short)s5[u]);
          }
        }
        const float* wd = kvd_w + (size_t)(row0 + c)*9;
        float w00=wd[0],w01=wd[1],w02=wd[2],w10=wd[3],w11=wd[4],w12=wd[5],w20=wd[6],w21=wd[7],w22=wd[8];
        float bb = kvd_b[row0 + c];
        #pragma unroll
        for (int py = 0; py < 14; ++py){
          float s = bb;
          s = fmaf(w00,u0[py],s); s = fmaf(w10,u0[py+1],s); s = fmaf(w20,u0[py+2],s);
          s = fmaf(w01,u1[py],s); s = fmaf(w11,u1[py+1],s); s = fmaf(w21,u1[py+2],s);
          s = fmaf(w02,u2[py],s); s = fmaf(w12,u2[py+1],s); s = fmaf(w22,u2[py+2],s);
          vS2[(py*16 + j)*VP + cv*48 + c] = f2b(s);
        }
      }
      __syncthreads();
    }
    const unsigned short* mbp = mb + ((size_t)which*NB + b)*9216;
    const float* bias = which ? psh_b : ps_b;
    float* ob = out + (size_t)which*NB*C*NPIX + (size_t)b*C*NPIX;
    for (int tl = w; tl < 84; tl += 8){
      int mi = tl / 14, n = tl - mi*14;
      const unsigned short* mp = mbp + (size_t)(mi*16 + (lane&15))*96 + (lane>>4)*8;
      short8 a0 = *(const short8*)(mp);
      short8 a1 = *(const short8*)(mp + 32);
      short8 a2 = *(const short8*)(mp + 64);
      float4 bv = *(const float4*)&bias[mi*16 + (lane>>4)*4];
      f32x4 acc = {bv.x, bv.y, bv.z, bv.w};
      const unsigned short* xb = &vS2[(size_t)(n*16 + (lane&15))*VP + (lane>>4)*8];
      acc = __builtin_amdgcn_mfma_f32_16x16x32_bf16(a0, *(const short8*)(xb),    acc, 0,0,0);
      acc = __builtin_amdgcn_mfma_f32_16x16x32_bf16(a1, *(const short8*)(xb+32), acc, 0,0,0);
      acc = __builtin_amdgcn_mfma_f32_16x16x32_bf16(a2, *(const short8*)(xb+64), acc, 0,0,0);
      int gy = gy0 + n;
      if (gy < HH){
        #pragma unroll
        for (int r = 0; r < 4; ++r)
          ob[(size_t)(mi*16 + (lane>>4)*4 + r)*NPIX + gy*WW + gx0 + (lane&15)] = acc[r];
      }
    }
    __syncthreads();
  }
}

extern "C" void kernel_launch(void* const* d_in, const int* in_sizes, int n_in,
                              void* d_out, int out_size, void* d_ws, size_t ws_size,
                              hipStream_t stream)
{
  const float* content = (const float*)d_in[0];
  const float* style   = (const float*)d_in[1];
  const float* temp    = (const float*)d_in[2];
  const float* q_w   = (const float*)d_in[3];
  const float* q_b   = (const float*)d_in[4];
  const float* qd_w  = (const float*)d_in[5];
  const float* qd_b  = (const float*)d_in[6];
  const float* kv_w  = (const float*)d_in[7];
  const float* kv_b  = (const float*)d_in[8];
  const float* kvd_w = (const float*)d_in[9];
  const float* kvd_b = (const float*)d_in[10];
  const float* ps_w  = (const float*)d_in[11];
  const float* ps_b  = (const float*)d_in[12];
  const float* psh_w = (const float*)d_in[13];
  const float* psh_b = (const float*)d_in[14];
  float* out = (float*)d_out;
  float* ws  = (float*)d_ws;

  unsigned short* xt = (unsigned short*)((char*)d_ws + XT_OFF_BYTES);

  if (ws_size >= WS_NEED2){
    unsigned short* qk  = (unsigned short*)((char*)d_ws + QK_OFF);
    unsigned short* vbh = (unsigned short*)((char*)d_ws + VB_OFF);
    unsigned short* vbs = (unsigned short*)(out + (size_t)NB*C*NPIX); // alias: shift half of d_out
    float* pg  = (float*)((char*)d_ws + PG_OFF);
    float* psq = (float*)((char*)d_ws + PSQ_OFF);
    unsigned short* mb = (unsigned short*)((char*)d_ws + MB_OFF);
    unsigned short* wb = (unsigned short*)((char*)d_ws + WB_OFF);

    k0t<<<dim3(NPIX/64, NB, 2), dim3(256), 0, stream>>>(content, style, xt);
    kwpack<<<dim3(144), dim3(256), 0, stream>>>(q_w, kv_w, wb);
    kconv<<<dim3(NTILES, NB, 8), dim3(512), 0, stream>>>(
        xt, wb, q_b, qd_w, qd_b, kv_b, kvd_w, kvd_b, qk, vbs, vbh, psq);
    kgram<<<dim3(KSPLIT, NB), dim3(384), 0, stream>>>(qk, pg);
    kgredN<<<dim3(NB, 37), dim3(256), 0, stream>>>(pg, psq, ws);
    k2_attn<<<dim3(NB), dim3(256), 0, stream>>>(temp, ps_w, psh_w, ws, mb);
    // scale: reads vbs (aliased in shift half), writes scale half — must precede shift
    kMv<<<dim3(NPIX/256, NB), dim3(512), 0, stream>>>(vbs, mb, ps_b, out);
    // shift: reads vbh (ws), writes shift half
    kMv<<<dim3(NPIX/256, NB), dim3(512), 0, stream>>>(
        vbh, mb + (size_t)NB*9216, psh_b, out + (size_t)NB*C*NPIX);
  } else {
    float* pg  = (float*)((char*)d_ws + F_PG_OFF);
    float* psq = (float*)((char*)d_ws + F_PSQ_OFF);
    unsigned short* mb = (unsigned short*)((char*)d_ws + F_MB_OFF);
    k0t<<<dim3(NPIX/64, NB, 2), dim3(256), 0, stream>>>(content, style, xt);
    kqk<<<dim3(NTILES, NB), dim3(512), 0, stream>>>(
        xt, q_w, q_b, qd_w, qd_b, kv_w, kv_b, kvd_w, kvd_b, pg, psq);
    kgredF<<<dim3(NB*HEADS), dim3(256), 0, stream>>>(pg, psq, ws);
    k2_attn<<<dim3(NB), dim3(256), 0, stream>>>(temp, ps_w, psh_w, ws, mb);
    kv_out<<<dim3(NTILES, NB), dim3(512), 0, stream>>>(
        xt + (size_t)NB*NPIX*96, kv_w, kv_b, kvd_w, kvd_b, ps_b, psh_b, mb, out);
  }
}

// Round 8
// 436.828 us; speedup vs baseline: 5.5389x; 1.0249x over previous
//
#include <hip/hip_runtime.h>

#define NB 4
#define C 96
#define HH 256
#define WW 256
#define NPIX (HH*WW)
#define HEADS 4
#define CH 24

// ---- tiling: interior 16 wide x 14 tall, halo 18x16 ----
#define NTX2 16
#define NTY2 19
#define NTILES (NTX2*NTY2)
#define YP 296      // fallback Ysh pitch
#define QP 264      // fallback qS/kT pitch
#define VP 104      // vS pitch ([px][ch]) for kMv + fallback
#define KSPLIT 128
#define YR 24       // kconv Ysh row pitch (shorts)
#define YC 392      // kconv Ysh channel stride (shorts)
#define XTP 76      // k0t LDS pitch (shorts)

#define WS_SUMSQ_Q 0
#define WS_SUMSQ_K (WS_SUMSQ_Q + NB*C)
#define WS_GRAM    (WS_SUMSQ_K + NB*C)
#define WS_MS      (WS_GRAM + NB*HEADS*CH*CH)
#define WS_MSH     (WS_MS + NB*C*C)

// shared xt region
#define XT_OFF_BYTES ((size_t)335872)
#define XT_BYTES   ((size_t)2*NB*NPIX*96*2)

// ---- fallback (r4) layout ----
#define F_PSQ_OFF   (XT_OFF_BYTES + XT_BYTES)
#define F_PSQ_BYTES ((size_t)NTILES*NB*192*4)
#define F_PG_OFF    (F_PSQ_OFF + F_PSQ_BYTES)
#define F_PG_BYTES  ((size_t)NTILES*NB*HEADS*1024*4)
#define F_MB_OFF    (F_PG_OFF + F_PG_BYTES)
#define F_MB_BYTES  ((size_t)2*NB*96*96*2)
#define F_WS_NEED   (F_MB_OFF + F_MB_BYTES)

// ---- main layout ----
#define QK_OFF    (XT_OFF_BYTES + XT_BYTES)
#define QK_BYTES  ((size_t)2*NB*96*NPIX*2)
#define VB_OFF    (QK_OFF + QK_BYTES)              // v_shift ([b][96][n] bf16)
#define VB_BYTES  ((size_t)NB*NPIX*96*2)
#define PG_OFF    (VB_OFF + VB_BYTES)
#define PG_BYTES  ((size_t)KSPLIT*NB*9216*4)
#define PSQ_OFF   (PG_OFF + PG_BYTES)
#define PSQ_BYTES ((size_t)4*NTILES*NB*48*4)
#define MB_OFF    (PSQ_OFF + PSQ_BYTES)
#define MB_BYTES  ((size_t)2*NB*96*96*2)
#define WB_OFF    (MB_OFF + MB_BYTES)
#define WB_BYTES  ((size_t)384*96*2)
#define WS_NEED2  (WB_OFF + WB_BYTES)

typedef short short8 __attribute__((ext_vector_type(8)));
typedef float f32x4 __attribute__((ext_vector_type(4)));
typedef float f32x16 __attribute__((ext_vector_type(16)));

__device__ __forceinline__ unsigned short f2b(float f){
  unsigned u = __float_as_uint(f);
  unsigned r = u + 0x7FFFu + ((u >> 16) & 1u);
  return (unsigned short)(r >> 16);
}
__device__ __forceinline__ float b2f(unsigned short s){
  return __uint_as_float(((unsigned)s) << 16);
}
__device__ __forceinline__ short8 pack8(float4 a, float4 b){
  short8 r;
  r[0]=(short)f2b(a.x); r[1]=(short)f2b(a.y); r[2]=(short)f2b(a.z); r[3]=(short)f2b(a.w);
  r[4]=(short)f2b(b.x); r[5]=(short)f2b(b.y); r[6]=(short)f2b(b.z); r[7]=(short)f2b(b.w);
  return r;
}

// ============================ K0: fp32 [c][gy][gx] -> bf16 [px][c]; cm=1: px = gx*HH+gy ============================
__global__ __launch_bounds__(256) void k0t(
  const float* __restrict__ content, const float* __restrict__ style,
  unsigned short* __restrict__ xt, int cm)
{
  __shared__ unsigned short Xt[96*XTP];
  const int t = threadIdx.x;
  const int n0 = blockIdx.x * 64;
  const int b = blockIdx.y, src = blockIdx.z;
  const int gyr = n0 >> 8, gxb = n0 & 255;
  const float* in = (src ? style : content) + (size_t)b*C*NPIX;
  #pragma unroll
  for (int i = 0; i < 6; ++i){
    int s = i*256 + t;
    int r = s >> 4, c4 = s & 15;
    float4 f = *(const float4*)(in + (size_t)r*NPIX + n0 + c4*4);
    unsigned lo = ((unsigned)f2b(f.y) << 16) | f2b(f.x);
    unsigned hi = ((unsigned)f2b(f.w) << 16) | f2b(f.z);
    *(uint2*)&Xt[r*XTP + c4*4] = make_uint2(lo, hi);
  }
  __syncthreads();
  unsigned* dst = (unsigned*)(xt + ((size_t)src*NB + b)*NPIX*96);
  #pragma unroll
  for (int i = 0; i < 12; ++i){
    int s = i*256 + t;
    int j = s / 48, c2 = s - j*48;
    unsigned v = ((unsigned)Xt[(c2*2+1)*XTP + j] << 16) | Xt[(c2*2)*XTP + j];
    size_t np = cm ? ((size_t)(gxb + j)*HH + gyr) : (size_t)(n0 + j);
    dst[np*48 + c2] = v;
  }
}

// ============================ kwpack ============================
__global__ __launch_bounds__(256) void kwpack(
  const float* __restrict__ q_w, const float* __restrict__ kv_w,
  unsigned short* __restrict__ wb)
{
  int i = blockIdx.x*256 + threadIdx.x;
  if (i < 9216) wb[i] = f2b(q_w[i]);
  else if (i < 36864) wb[i] = f2b(kv_w[i - 9216]);
}

// ============================ kconv: one 48-ch chunk per block (xt column-major) ============================
// z: 0,1 = q chunks (content); 2,3 = k; 4,5 = v_scale; 6,7 = v_shift (style)
__global__ __launch_bounds__(512, 4) void kconv(
  const unsigned short* __restrict__ xt, const unsigned short* __restrict__ wb,
  const float* __restrict__ q_b, const float* __restrict__ qd_w, const float* __restrict__ qd_b,
  const float* __restrict__ kv_b, const float* __restrict__ kvd_w, const float* __restrict__ kvd_b,
  unsigned short* __restrict__ qk, unsigned short* __restrict__ vbs,
  unsigned short* __restrict__ vbh, float* __restrict__ psq)
{
  __shared__ unsigned short Ysh[48*YC];   // 37632 B
  __shared__ float red[48];
  const int t = threadIdx.x, lane = t & 63, w = t >> 6;
  const int tile = blockIdx.x, b = blockIdx.y, z = blockIdx.z;
  const int txx = tile & 15, tyy = tile >> 4;
  const int gx0 = txx*16, gy0 = tyy*14;
  const unsigned short* xsrc = xt + ((size_t)((z < 2 ? 0 : 1)*NB + b))*NPIX*96;
  const int wrow0 = (z < 2) ? z*48 : 96 + (z-2)*48;
  const float* cb  = (z<2) ? q_b  + z*48           : kv_b  + (size_t)(z-2)*48;
  const float* dww = (z<2) ? qd_w + (size_t)z*48*9 : kvd_w + (size_t)(z-2)*48*9;
  const float* dwb = (z<2) ? qd_b + z*48           : kvd_b + (size_t)(z-2)*48;
  unsigned short* dst0;
  if (z < 2)      dst0 = qk  + ((size_t)(0*NB + b)*96 + (size_t)z*48)*NPIX;
  else if (z < 4) dst0 = qk  + ((size_t)(1*NB + b)*96 + (size_t)(z-2)*48)*NPIX;
  else if (z < 6) dst0 = vbs + ((size_t)b*96 + (size_t)(z-4)*48)*NPIX;
  else            dst0 = vbh + ((size_t)b*96 + (size_t)(z-6)*48)*NPIX;

  if (t < 48) red[t] = 0.f;

  // persistent halo fragments — xt column-major: 16 hy-lanes hit contiguous pixels
  const int hy = lane & 15, khalf = lane >> 4;
  const int gyh = gy0 - 1 + hy;
  short8 xf[3][3]; bool imv[3];
  const int np = (w < 2) ? 3 : 2;
  #pragma unroll
  for (int i = 0; i < 3; ++i){
    if (i >= np) break;
    int pt = w + i*8;
    int gx = gx0 - 1 + pt;
    bool im = (gx>=0) && (gx<WW) && (gyh>=0) && (gyh<HH);
    imv[i] = im;
    const unsigned short* xp = xsrc + (size_t)(im ? (gx*HH + gyh) : 0)*96 + khalf*8;
    short8 zz = {};
    #pragma unroll
    for (int kk = 0; kk < 3; ++kk){
      short8 v = *(const short8*)(xp + kk*32);
      xf[i][kk] = im ? v : zz;
    }
  }

  // conv1x1: 48 output rows over halo -> Ysh [ch][hy][pt]
  #pragma unroll 1
  for (int mi = 0; mi < 3; ++mi){
    const unsigned short* wp = wb + (size_t)(wrow0 + mi*16 + hy)*96 + khalf*8;
    short8 a0 = *(const short8*)(wp);
    short8 a1 = *(const short8*)(wp + 32);
    short8 a2 = *(const short8*)(wp + 64);
    float4 bv = *(const float4*)&cb[mi*16 + khalf*4];
    #pragma unroll
    for (int i = 0; i < 3; ++i){
      if (i >= np) break;
      int pt = w + i*8;
      f32x4 acc = {bv.x, bv.y, bv.z, bv.w};
      acc = __builtin_amdgcn_mfma_f32_16x16x32_bf16(a0, xf[i][0], acc, 0,0,0);
      acc = __builtin_amdgcn_mfma_f32_16x16x32_bf16(a1, xf[i][1], acc, 0,0,0);
      acc = __builtin_amdgcn_mfma_f32_16x16x32_bf16(a2, xf[i][2], acc, 0,0,0);
      #pragma unroll
      for (int r = 0; r < 4; ++r){
        int ch = mi*16 + khalf*4 + r;
        Ysh[ch*YC + hy*YR + pt] = imv[i] ? f2b(acc[r]) : (unsigned short)0;
      }
    }
  }
  __syncthreads();

  // dw 3x3, wave-balanced
  for (int sl = lane; sl < 84; sl += 64){
    int slot = w*84 + sl;                 // 0..671
    int c = slot / 14, py = slot - (slot/14)*14;
    int gy = gy0 + py;
    if (gy < HH){
      const float* wd = dww + (size_t)c*9;
      float w00=wd[0],w01=wd[1],w02=wd[2],w10=wd[3],w11=wd[4],w12=wd[5],w20=wd[6],w21=wd[7],w22=wd[8];
      float bb = dwb[c];
      const unsigned short* yb = &Ysh[c*YC + py*YR];
      float o[16];
      #pragma unroll
      for (int half = 0; half < 2; ++half){
        float u[3][10];
        #pragma unroll
        for (int uu = 0; uu < 3; ++uu){
          const unsigned short* rp = yb + uu*YR + half*8;
          short8 s = *(const short8*)rp;
          unsigned ex = *(const unsigned*)(rp + 8);
          #pragma unroll
          for (int j = 0; j < 8; ++j) u[uu][j] = b2f((unsigned short)s[j]);
          u[uu][8] = b2f((unsigned short)(ex & 0xffffu));
          u[uu][9] = b2f((unsigned short)(ex >> 16));
        }
        #pragma unroll
        for (int j = 0; j < 8; ++j){
          float s = bb;
          s = fmaf(w00,u[0][j],s); s = fmaf(w01,u[0][j+1],s); s = fmaf(w02,u[0][j+2],s);
          s = fmaf(w10,u[1][j],s); s = fmaf(w11,u[1][j+1],s); s = fmaf(w12,u[1][j+2],s);
          s = fmaf(w20,u[2][j],s); s = fmaf(w21,u[2][j+1],s); s = fmaf(w22,u[2][j+2],s);
          o[half*8 + j] = s;
        }
      }
      unsigned short vv[16];
      if (z < 4){
        float sq = 0.f;
        #pragma unroll
        for (int j = 0; j < 16; ++j){ sq = fmaf(o[j], o[j], sq); vv[j] = f2b(o[j]); }
        atomicAdd(&red[c], sq);
      } else {
        #pragma unroll
        for (int j = 0; j < 16; ++j) vv[j] = f2b(o[j]);
      }
      unsigned short* qp = dst0 + (size_t)c*NPIX + (size_t)gy*WW + gx0;
      *(short8*)qp       = *(const short8*)&vv[0];
      *(short8*)(qp + 8) = *(const short8*)&vv[8];
    }
  }
  if (z < 4){
    __syncthreads();
    if (t < 48)
      psq[((size_t)(z*NTILES + tile)*NB + b)*48 + t] = red[t];
  }
}

// ============================ kgram: partial-K Gram ============================
__global__ __launch_bounds__(384) void kgram(
  const unsigned short* __restrict__ qk, float* __restrict__ pg)
{
  const int t = threadIdx.x, lane = t & 63, wv = t >> 6;
  const int ks = blockIdx.x, b = blockIdx.y;
  const int n0 = ks * (NPIX / KSPLIT);
  const unsigned short* qb = qk + ((size_t)(0*NB + b)*96)*NPIX;
  const unsigned short* kb = qk + ((size_t)(1*NB + b)*96)*NPIX;
  f32x4 acc[6];
  #pragma unroll
  for (int i = 0; i < 6; ++i) acc[i] = (f32x4){0.f,0.f,0.f,0.f};
  #pragma unroll 1
  for (int st = 0; st < (NPIX/KSPLIT)/32; ++st){
    int off = n0 + st*32 + (lane>>4)*8;
    short8 bf = *(const short8*)(kb + (size_t)(wv*16 + (lane&15))*NPIX + off);
    #pragma unroll
    for (int ci = 0; ci < 6; ++ci){
      short8 af = *(const short8*)(qb + (size_t)(ci*16 + (lane&15))*NPIX + off);
      acc[ci] = __builtin_amdgcn_mfma_f32_16x16x32_bf16(af, bf, acc[ci], 0,0,0);
    }
  }
  float* dst = pg + ((size_t)ks*NB + b)*9216;
  #pragma unroll
  for (int ci = 0; ci < 6; ++ci){
    #pragma unroll
    for (int r = 0; r < 4; ++r)
      dst[(ci*6 + wv)*256 + ((lane>>4)*4 + r)*16 + (lane&15)] = acc[ci][r];
  }
}

// ============================ kgredN ============================
__global__ __launch_bounds__(256) void kgredN(
  const float* __restrict__ pg, const float* __restrict__ psq, float* __restrict__ ws)
{
  const int b = blockIdx.x, by = blockIdx.y, t = threadIdx.x;
  if (by < 36){
    int ci = by / 6;
    int qrow = ci*16 + (t >> 4), krow = (by - ci*6)*16 + (t & 15);
    float s = 0.f;
    for (int ks = 0; ks < KSPLIT; ++ks)
      s += pg[((size_t)ks*NB + b)*9216 + by*256 + t];
    int h = qrow / CH;
    if (krow / CH == h)
      ws[WS_GRAM + ((size_t)(b*HEADS + h)*CH + (qrow % CH))*CH + (krow % CH)] = s;
  } else {
    if (t < 192){
      int src = t / 96, c = t - (t/96)*96;
      int zz = src*2 + (c/48), cc = c - (c/48)*48;
      float s = 0.f;
      for (int tile = 0; tile < NTILES; ++tile)
        s += psq[((size_t)(zz*NTILES + tile)*NB + b)*48 + cc];
      ws[(src ? WS_SUMSQ_K : WS_SUMSQ_Q) + b*C + c] = s;
    }
  }
}

// ============================ k2: softmax + M matrices ============================
__global__ void k2_attn(
  const float* __restrict__ temp,
  const float* __restrict__ ps_w, const float* __restrict__ psh_w,
  float* __restrict__ ws, unsigned short* __restrict__ mb)
{
  const int b = blockIdx.x;
  const int t = threadIdx.x;
  __shared__ float attn[C * CH];
  __shared__ float nq[C], nk[C];
  if (t < C){
    nq[t] = fmaxf(sqrtf(ws[WS_SUMSQ_Q + b * C + t]), 1e-12f);
    nk[t] = fmaxf(sqrtf(ws[WS_SUMSQ_K + b * C + t]), 1e-12f);
  }
  __syncthreads();
  if (t < C){
    int h = t / CH;
    const float* g = ws + WS_GRAM + (((size_t)b * HEADS + h) * CH + (t % CH)) * CH;
    float tp = temp[h];
    float row[CH];
    float mx = -3.4e38f;
    #pragma unroll
    for (int d = 0; d < CH; ++d){
      row[d] = g[d] / (nq[t] * nk[h * CH + d]) * tp;
      mx = fmaxf(mx, row[d]);
    }
    float s = 0.f;
    #pragma unroll
    for (int d = 0; d < CH; ++d){ row[d] = expf(row[d] - mx); s += row[d]; }
    float inv = 1.f / s;
    #pragma unroll
    for (int d = 0; d < CH; ++d) attn[t * CH + d] = row[d] * inv;
  }
  __syncthreads();
  for (int idx = t; idx < C * C; idx += 256){
    int o = idx / C, dg = idx - o * C;
    int h = dg / CH, d = dg - h * CH;
    float s1 = 0.f, s2 = 0.f;
    #pragma unroll
    for (int c2 = 0; c2 < CH; ++c2){
      float a = attn[(h * CH + c2) * CH + d];
      s1 = fmaf(ps_w [(size_t)o * C + h * CH + c2], a, s1);
      s2 = fmaf(psh_w[(size_t)o * C + h * CH + c2], a, s2);
    }
    ws[WS_MS  + (size_t)b * C * C + idx] = s1;
    ws[WS_MSH + (size_t)b * C * C + idx] = s2;
    if (mb){
      mb[((size_t)0*NB + b)*9216 + idx] = f2b(s1);
      mb[((size_t)1*NB + b)*9216 + idx] = f2b(s2);
    }
  }
}

// ============================ kMv: out = M @ v, diagonal-padded LDS transpose ============================
__global__ __launch_bounds__(512) void kMv(
  const unsigned short* __restrict__ vb, const unsigned short* __restrict__ mb,
  const float* __restrict__ bias, float* __restrict__ out)
{
  __shared__ unsigned short vS[256*VP + 32*8];   // +diagonal pad (px>>3)*8
  unsigned* vS32 = (unsigned*)vS;
  const int t = threadIdx.x, lane = t & 63, w = t >> 6;
  const int b = blockIdx.y;
  const int n0 = blockIdx.x * 256;
  const unsigned short* vbase = vb + (size_t)b*96*NPIX;
  #pragma unroll
  for (int i = 0; i < 3; ++i){
    int task = i*512 + t;            // 1536 = 48 ch-pairs x 32 segs
    int cp = task >> 5, seg = task & 31;
    const unsigned short* r0 = vbase + (size_t)(2*cp)*NPIX + n0 + seg*8;
    short8 a  = *(const short8*)r0;
    short8 bq = *(const short8*)(r0 + NPIX);
    #pragma unroll
    for (int j = 0; j < 8; ++j){
      int px = seg*8 + j;
      unsigned d = ((unsigned)(unsigned short)bq[j] << 16) | (unsigned)(unsigned short)a[j];
      vS32[px*(VP/2) + (px>>3)*4 + cp] = d;
    }
  }
  __syncthreads();
  const unsigned short* mbb = mb + (size_t)b*9216;
  float* ob = out + (size_t)b*C*NPIX;
  #pragma unroll 1
  for (int mi = 0; mi < 6; ++mi){
    const unsigned short* mp = mbb + (size_t)(mi*16 + (lane & 15))*96 + (lane>>4)*8;
    short8 a0 = *(const short8*)(mp);
    short8 a1 = *(const short8*)(mp + 32);
    short8 a2 = *(const short8*)(mp + 64);
    float4 bv = *(const float4*)&bias[mi*16 + (lane>>4)*4];
    #pragma unroll
    for (int g = 0; g < 2; ++g){
      int px = (w*2 + g)*16 + (lane & 15);
      const unsigned short* xb = &vS[px*VP + (px>>3)*8 + (lane>>4)*8];
      f32x4 acc = {bv.x, bv.y, bv.z, bv.w};
      acc = __builtin_amdgcn_mfma_f32_16x16x32_bf16(a0, *(const short8*)(xb),    acc, 0,0,0);
      acc = __builtin_amdgcn_mfma_f32_16x16x32_bf16(a1, *(const short8*)(xb+32), acc, 0,0,0);
      acc = __builtin_amdgcn_mfma_f32_16x16x32_bf16(a2, *(const short8*)(xb+64), acc, 0,0,0);
      #pragma unroll
      for (int r = 0; r < 4; ++r)
        ob[(size_t)(mi*16 + (lane>>4)*4 + r)*NPIX + n0 + px] = acc[r];
    }
  }
}

// ============================ fallback (r4) kernels (row-major xt) ============================
__device__ __forceinline__ void conv48c(
  const unsigned short* __restrict__ xbase, const float* __restrict__ wmat,
  const float* __restrict__ bias, int row0,
  int gx0, int gy0, int lane, int w, unsigned short* __restrict__ Ysh)
{
  const int hy = lane & 15, khalf = lane >> 4;
  const int gy = gy0 - 1 + hy;
  short8 xf[3][3]; bool imv[3]; int np = (w < 2) ? 3 : 2;
  #pragma unroll
  for (int i = 0; i < 3; ++i){
    if (i >= np) break;
    int pt = w + i*8;
    int gx = gx0 - 1 + pt;
    bool im = (gx>=0) && (gx<WW) && (gy>=0) && (gy<HH);
    imv[i] = im;
    int n = im ? (gy*WW + gx) : 0;
    const unsigned short* xp = xbase + (size_t)n*96 + khalf*8;
    short8 z = {};
    #pragma unroll
    for (int kk = 0; kk < 3; ++kk){
      short8 v = *(const short8*)(xp + kk*32);
      xf[i][kk] = im ? v : z;
    }
  }
  #pragma unroll 1
  for (int mi = 0; mi < 3; ++mi){
    int orow = row0 + mi*16 + hy;
    const float* wp = wmat + (size_t)orow*96 + khalf*8;
    short8 a0 = pack8(*(const float4*)(wp),    *(const float4*)(wp+4));
    short8 a1 = pack8(*(const float4*)(wp+32), *(const float4*)(wp+36));
    short8 a2 = pack8(*(const float4*)(wp+64), *(const float4*)(wp+68));
    float4 bv = *(const float4*)&bias[row0 + mi*16 + khalf*4];
    #pragma unroll
    for (int i = 0; i < 3; ++i){
      if (i >= np) break;
      int pt = w + i*8;
      f32x4 acc = {bv.x, bv.y, bv.z, bv.w};
      acc = __builtin_amdgcn_mfma_f32_16x16x32_bf16(a0, xf[i][0], acc, 0,0,0);
      acc = __builtin_amdgcn_mfma_f32_16x16x32_bf16(a1, xf[i][1], acc, 0,0,0);
      acc = __builtin_amdgcn_mfma_f32_16x16x32_bf16(a2, xf[i][2], acc, 0,0,0);
      #pragma unroll
      for (int r = 0; r < 4; ++r){
        int ch = mi*16 + khalf*4 + r;
        Ysh[ch*YP + pt*16 + hy] = imv[i] ? f2b(acc[r]) : (unsigned short)0;
      }
    }
  }
}

__global__ __launch_bounds__(512, 4) void kqk(
  const unsigned short* __restrict__ xt,
  const float* __restrict__ q_w, const float* __restrict__ q_b,
  const float* __restrict__ qd_w, const float* __restrict__ qd_b,
  const float* __restrict__ kv_w, const float* __restrict__ kv_b,
  const float* __restrict__ kvd_w, const float* __restrict__ kvd_b,
  float* __restrict__ pg, float* __restrict__ psq)
{
  __shared__ unsigned short Ysh[48*YP];
  __shared__ unsigned short qS[48*QP];
  __shared__ unsigned short kT[48*QP];
  __shared__ float redq[C], redk[C];

  const int t = threadIdx.x, lane = t & 63, w = t >> 6;
  const int b = blockIdx.y, tile = blockIdx.x;
  const int txx = tile & 15, tyy = tile >> 4;
  const int gx0 = txx*16, gy0 = tyy*14;
  if (t < C){ redq[t] = 0.f; redk[t] = 0.f; }
  __syncthreads();

  const unsigned short* xc = xt + ((size_t)(0*NB + b))*NPIX*96;
  const unsigned short* xs = xt + ((size_t)(1*NB + b))*NPIX*96;

  auto dwQK = [&](const float* dww, const float* dwb, int wrow0,
                  unsigned short* dst, float* red){
    for (int slot = t; slot < 48*16; slot += 512){
      int c = slot >> 4, j = slot & 15;
      const unsigned short* yb = &Ysh[c*YP + j*16];
      float u0[16], u1[16], u2[16];
      {
        short8 s0 = *(const short8*)(yb),    s1 = *(const short8*)(yb+8);
        short8 s2 = *(const short8*)(yb+16), s3 = *(const short8*)(yb+24);
        short8 s4 = *(const short8*)(yb+32), s5 = *(const short8*)(yb+40);
        #pragma unroll
        for (int u = 0; u < 8; ++u){
          u0[u]=b2f((unsigned short)s0[u]); u0[u+8]=b2f((unsigned short)s1[u]);
          u1[u]=b2f((unsigned short)s2[u]); u1[u+8]=b2f((unsigned short)s3[u]);
          u2[u]=b2f((unsigned short)s4[u]); u2[u+8]=b2f((unsigned short)s5[u]);
        }
      }
      const float* wd = dww + (size_t)(wrow0 + c)*9;
      float w00=wd[0],w01=wd[1],w02=wd[2],w10=wd[3],w11=wd[4],w12=wd[5],w20=wd[6],w21=wd[7],w22=wd[8];
      float bb = dwb[wrow0 + c];
      unsigned short vv[16];
      float sq = 0.f;
      #pragma unroll
      for (int py = 0; py < 14; ++py){
        float s = bb;
        s = fmaf(w00,u0[py],s); s = fmaf(w10,u0[py+1],s); s = fmaf(w20,u0[py+2],s);
        s = fmaf(w01,u1[py],s); s = fmaf(w11,u1[py+1],s); s = fmaf(w21,u1[py+2],s);
        s = fmaf(w02,u2[py],s); s = fmaf(w12,u2[py+1],s); s = fmaf(w22,u2[py+2],s);
        if (gy0 + py >= HH) s = 0.f;
        sq = fmaf(s, s, sq);
        vv[py] = f2b(s);
      }
      vv[14] = 0; vv[15] = 0;
      atomicAdd(&red[wrow0 + c], sq);
      *(short8*)&dst[c*QP + j*16]     = *(short8*)&vv[0];
      *(short8*)&dst[c*QP + j*16 + 8] = *(short8*)&vv[8];
    }
  };

  auto gram = [&](int cc){
    int hl = w & 1, slice = w >> 1;
    int cl = lane & 31; bool cv = cl < CH;
    int row = hl*CH + (cv ? cl : 0);
    f32x16 g;
    #pragma unroll
    for (int r = 0; r < 16; ++r) g[r] = 0.f;
    short8 z = {};
    for (int ks = slice; ks < 16; ks += 4){
      int ko = ks*16 + (lane>>5)*8;
      short8 qa = *(const short8*)&qS[row*QP + ko];
      short8 kb = *(const short8*)&kT[row*QP + ko];
      if (!cv){ qa = z; kb = z; }
      g = __builtin_amdgcn_mfma_f32_32x32x16_bf16(qa, kb, g, 0,0,0);
    }
    float* stg = (float*)Ysh;
    if (slice != 0){
      float* dst = stg + (size_t)(hl*3 + slice - 1)*1024;
      #pragma unroll
      for (int r = 0; r < 16; ++r) dst[r*64 + lane] = g[r];
    }
    __syncthreads();
    if (slice == 0){
      const float* s0 = stg + (size_t)(hl*3 + 0)*1024;
      const float* s1 = stg + (size_t)(hl*3 + 1)*1024;
      const float* s2 = stg + (size_t)(hl*3 + 2)*1024;
      float* dst = pg + ((size_t)(tile*NB + b)*HEADS + cc*2 + hl)*1024;
      #pragma unroll
      for (int r = 0; r < 16; ++r){
        int ix = r*64 + lane;
        dst[ix] = g[r] + s0[ix] + s1[ix] + s2[ix];
      }
    }
  };

  #pragma unroll 1
  for (int cc = 0; cc < 2; ++cc){
    conv48c(xc, q_w, q_b, cc*48, gx0, gy0, lane, w, Ysh);
    __syncthreads();
    dwQK(qd_w, qd_b, cc*48, qS, redq);
    __syncthreads();
    conv48c(xs, kv_w, kv_b, cc*48, gx0, gy0, lane, w, Ysh);
    __syncthreads();
    dwQK(kvd_w, kvd_b, cc*48, kT, redk);
    __syncthreads();
    gram(cc);
    __syncthreads();
  }
  if (t < 192){
    float v = (t < 96) ? redq[t] : redk[t - 96];
    psq[(size_t)(tile*NB + b)*192 + t] = v;
  }
}

__global__ __launch_bounds__(256) void kgredF(
  const float* __restrict__ pg, const float* __restrict__ psq, float* __restrict__ ws)
{
  const int bh = blockIdx.x;
  const int b = bh >> 2, h = bh & 3;
  const int t = threadIdx.x;
  float a0=0.f, a1=0.f, a2=0.f, a3=0.f, sq=0.f;
  for (int tile = 0; tile < NTILES; ++tile){
    const float* p = pg + ((size_t)(tile*NB + b)*HEADS + h)*1024;
    a0 += p[t]; a1 += p[t+256]; a2 += p[t+512]; a3 += p[t+768];
    if (t < 48){
      int ch = h*CH + (t % CH);
      sq += psq[(size_t)(tile*NB + b)*192 + (t < CH ? ch : 96 + ch)];
    }
  }
  if (t < 48){
    if (t < CH) ws[WS_SUMSQ_Q + b*C + h*CH + t] = sq;
    else        ws[WS_SUMSQ_K + b*C + h*CH + (t - CH)] = sq;
  }
  float accs[4] = {a0, a1, a2, a3};
  #pragma unroll
  for (int i = 0; i < 4; ++i){
    int idx = i*256 + t;
    int r = idx >> 6, ln = idx & 63;
    int row = (r&3) + 8*(r>>2) + 4*(ln>>5);
    int col = ln & 31;
    if (row < CH && col < CH)
      ws[WS_GRAM + ((size_t)(b*HEADS + h)*CH + row)*CH + col] = accs[i];
  }
}

__global__ __launch_bounds__(512, 4) void kv_out(
  const unsigned short* __restrict__ xs,
  const float* __restrict__ kv_w, const float* __restrict__ kv_b,
  const float* __restrict__ kvd_w, const float* __restrict__ kvd_b,
  const float* __restrict__ ps_b, const float* __restrict__ psh_b,
  const unsigned short* __restrict__ mb, float* __restrict__ out)
{
  __shared__ unsigned short Ysh[48*YP];
  __shared__ unsigned short vS2[224*VP];
  const int t = threadIdx.x, lane = t & 63, w = t >> 6;
  const int b = blockIdx.y, tile = blockIdx.x;
  const int txx = tile & 15, tyy = tile >> 4;
  const int gx0 = txx*16, gy0 = tyy*14;
  const unsigned short* xb_ = xs + (size_t)b*NPIX*96;

  #pragma unroll 1
  for (int which = 0; which < 2; ++which){
    #pragma unroll 1
    for (int cv = 0; cv < 2; ++cv){
      int row0 = 96 + which*96 + cv*48;
      conv48c(xb_, kv_w, kv_b, row0, gx0, gy0, lane, w, Ysh);
      __syncthreads();
      for (int slot = t; slot < 48*16; slot += 512){
        int c = slot >> 4, j = slot & 15;
        const unsigned short* yb = &Ysh[c*YP + j*16];
        float u0[16], u1[16], u2[16];
        {
          short8 s0 = *(const short8*)(yb),    s1 = *(const short8*)(yb+8);
          short8 s2 = *(const short8*)(yb+16), s3 = *(const short8*)(yb+24);
          short8 s4 = *(const short8*)(yb+32), s5 = *(const short8*)(yb+40);
          #pragma unroll
          for (int u = 0; u < 8; ++u){
            u0[u]=b2f((unsigned short)s0[u]); u0[u+8]=b2f((unsigned short)s1[u]);
            u1[u]=b2f((unsigned short)s2[u]); u1[u+8]=b2f((unsigned short)s3[u]);
            u2[u]=b2f((unsigned short)s4[u]); u2[u+8]=b2f((unsigned short)s5[u]);
          }
        }
        const float* wd = kvd_w + (size_t)(row0 + c)*9;
        float w00=wd[0],w01=wd[1],w02=wd[2],w10=wd[3],w11=wd[4],w12=wd[5],w20=wd[6],w21=wd[7],w22=wd[8];
        float bb = kvd_b[row0 + c];
        #pragma unroll
        for (int py = 0; py < 14; ++py){
          float s = bb;
          s = fmaf(w00,u0[py],s); s = fmaf(w10,u0[py+1],s); s = fmaf(w20,u0[py+2],s);
          s = fmaf(w01,u1[py],s); s = fmaf(w11,u1[py+1],s); s = fmaf(w21,u1[py+2],s);
          s = fmaf(w02,u2[py],s); s = fmaf(w12,u2[py+1],s); s = fmaf(w22,u2[py+2],s);
          vS2[(py*16 + j)*VP + cv*48 + c] = f2b(s);
        }
      }
      __syncthreads();
    }
    const unsigned short* mbp = mb + ((size_t)which*NB + b)*9216;
    const float* bias = which ? psh_b : ps_b;
    float* ob = out + (size_t)which*NB*C*NPIX + (size_t)b*C*NPIX;
    for (int tl = w; tl < 84; tl += 8){
      int mi = tl / 14, n = tl - mi*14;
      const unsigned short* mp = mbp + (size_t)(mi*16 + (lane&15))*96 + (lane>>4)*8;
      short8 a0 = *(const short8*)(mp);
      short8 a1 = *(const short8*)(mp + 32);
      short8 a2 = *(const short8*)(mp + 64);
      float4 bv = *(const float4*)&bias[mi*16 + (lane>>4)*4];
      f32x4 acc = {bv.x, bv.y, bv.z, bv.w};
      const unsigned short* xb = &vS2[(size_t)(n*16 + (lane&15))*VP + (lane>>4)*8];
      acc = __builtin_amdgcn_mfma_f32_16x16x32_bf16(a0, *(const short8*)(xb),    acc, 0,0,0);
      acc = __builtin_amdgcn_mfma_f32_16x16x32_bf16(a1, *(const short8*)(xb+32), acc, 0,0,0);
      acc = __builtin_amdgcn_mfma_f32_16x16x32_bf16(a2, *(const short8*)(xb+64), acc, 0,0,0);
      int gy = gy0 + n;
      if (gy < HH){
        #pragma unroll
        for (int r = 0; r < 4; ++r)
          ob[(size_t)(mi*16 + (lane>>4)*4 + r)*NPIX + gy*WW + gx0 + (lane&15)] = acc[r];
      }
    }
    __syncthreads();
  }
}

extern "C" void kernel_launch(void* const* d_in, const int* in_sizes, int n_in,
                              void* d_out, int out_size, void* d_ws, size_t ws_size,
                              hipStream_t stream)
{
  const float* content = (const float*)d_in[0];
  const float* style   = (const float*)d_in[1];
  const float* temp    = (const float*)d_in[2];
  const float* q_w   = (const float*)d_in[3];
  const float* q_b   = (const float*)d_in[4];
  const float* qd_w  = (const float*)d_in[5];
  const float* qd_b  = (const float*)d_in[6];
  const float* kv_w  = (const float*)d_in[7];
  const float* kv_b  = (const float*)d_in[8];
  const float* kvd_w = (const float*)d_in[9];
  const float* kvd_b = (const float*)d_in[10];
  const float* ps_w  = (const float*)d_in[11];
  const float* ps_b  = (const float*)d_in[12];
  const float* psh_w = (const float*)d_in[13];
  const float* psh_b = (const float*)d_in[14];
  float* out = (float*)d_out;
  float* ws  = (float*)d_ws;

  unsigned short* xt = (unsigned short*)((char*)d_ws + XT_OFF_BYTES);

  if (ws_size >= WS_NEED2){
    unsigned short* qk  = (unsigned short*)((char*)d_ws + QK_OFF);
    unsigned short* vbh = (unsigned short*)((char*)d_ws + VB_OFF);
    unsigned short* vbs = (unsigned short*)(out + (size_t)NB*C*NPIX); // alias: shift half of d_out
    float* pg  = (float*)((char*)d_ws + PG_OFF);
    float* psq = (float*)((char*)d_ws + PSQ_OFF);
    unsigned short* mb = (unsigned short*)((char*)d_ws + MB_OFF);
    unsigned short* wb = (unsigned short*)((char*)d_ws + WB_OFF);

    k0t<<<dim3(NPIX/64, NB, 2), dim3(256), 0, stream>>>(content, style, xt, 1);
    kwpack<<<dim3(144), dim3(256), 0, stream>>>(q_w, kv_w, wb);
    kconv<<<dim3(NTILES, NB, 8), dim3(512), 0, stream>>>(
        xt, wb, q_b, qd_w, qd_b, kv_b, kvd_w, kvd_b, qk, vbs, vbh, psq);
    kgram<<<dim3(KSPLIT, NB), dim3(384), 0, stream>>>(qk, pg);
    kgredN<<<dim3(NB, 37), dim3(256), 0, stream>>>(pg, psq, ws);
    k2_attn<<<dim3(NB), dim3(256), 0, stream>>>(temp, ps_w, psh_w, ws, mb);
    // scale: reads vbs (aliased in shift half), writes scale half — must precede shift
    kMv<<<dim3(NPIX/256, NB), dim3(512), 0, stream>>>(vbs, mb, ps_b, out);
    // shift: reads vbh (ws), writes shift half
    kMv<<<dim3(NPIX/256, NB), dim3(512), 0, stream>>>(
        vbh, mb + (size_t)NB*9216, psh_b, out + (size_t)NB*C*NPIX);
  } else {
    float* pg  = (float*)((char*)d_ws + F_PG_OFF);
    float* psq = (float*)((char*)d_ws + F_PSQ_OFF);
    unsigned short* mb = (unsigned short*)((char*)d_ws + F_MB_OFF);
    k0t<<<dim3(NPIX/64, NB, 2), dim3(256), 0, stream>>>(content, style, xt, 0);
    kqk<<<dim3(NTILES, NB), dim3(512), 0, stream>>>(
        xt, q_w, q_b, qd_w, qd_b, kv_w, kv_b, kvd_w, kvd_b, pg, psq);
    kgredF<<<dim3(NB*HEADS), dim3(256), 0, stream>>>(pg, psq, ws);
    k2_attn<<<dim3(NB), dim3(256), 0, stream>>>(temp, ps_w, psh_w, ws, mb);
    kv_out<<<dim3(NTILES, NB), dim3(512), 0, stream>>>(
        xt + (size_t)NB*NPIX*96, kv_w, kv_b, kvd_w, kvd_b, ps_b, psh_b, mb, out);
  }
}